// Round 2
// baseline (2357.119 us; speedup 1.0000x reference)
//
#include <hip/hip_runtime.h>
#include <math.h>

#ifndef M_PI
#define M_PI 3.14159265358979323846
#endif

static inline int cdiv(int a, int b){ return (a + b - 1) / b; }

// ---------------------------------------------------------------------------
// Shared per-edge geometry: vec, r, u, radial basis (8), SH l=1 (3), l=2 (5)
// ---------------------------------------------------------------------------
__device__ __forceinline__ void edge_geom(const float* __restrict__ pos, int row, int col,
    float& r, float& inv_r, float& ux, float& uy, float& uz,
    float* rad, float* sh1, float* sh2)
{
  float px = pos[row*3+0] - pos[col*3+0];
  float py = pos[row*3+1] - pos[col*3+1];
  float pz = pos[row*3+2] - pos[col*3+2];
  float r2 = px*px + py*py + pz*pz + 1e-12f;
  r = sqrtf(r2);
  inv_r = 1.0f / r;
  ux = px*inv_r; uy = py*inv_r; uz = pz*inv_r;
  const float K = 0.6324555320336759f;  // sqrt(2/R_MAX), R_MAX=5
  #pragma unroll
  for (int n = 0; n < 8; n++) {
    float cn = (float)(n+1) * (float)(M_PI / 5.0);
    rad[n] = K * sinf(cn * r) * inv_r;
  }
  const float s3  = 1.7320508075688772f;
  const float s5  = 2.23606797749979f;
  const float s15 = 3.872983346207417f;
  sh1[0] = s3*ux; sh1[1] = s3*uy; sh1[2] = s3*uz;
  sh2[0] = s15*ux*uy;
  sh2[1] = s15*uy*uz;
  sh2[2] = 0.5f*s5*(3.f*uz*uz - 1.f);
  sh2[3] = s15*ux*uz;
  sh2[4] = 0.5f*s15*(ux*ux - uy*uy);
}

// d rad[n]/dr = (K*cn*cos(cn r) - rad[n]) / r
__device__ __forceinline__ void edge_geom_bwd_extra(float r, float inv_r,
    const float* rad, float* draddr)
{
  const float K = 0.6324555320336759f;
  #pragma unroll
  for (int n = 0; n < 8; n++) {
    float cn = (float)(n+1) * (float)(M_PI / 5.0);
    draddr[n] = (K * cn * cosf(cn * r) - rad[n]) * inv_r;
  }
}

// sum over the 16-lane channel group (lanes differ in low 4 bits of lane id)
__device__ __forceinline__ float grp16_sum(float v){
  v += __shfl_xor(v, 1, 64);
  v += __shfl_xor(v, 2, 64);
  v += __shfl_xor(v, 4, 64);
  v += __shfl_xor(v, 8, 64);
  return v;
}

// ---------------------------------------------------------------------------
// h0_init[n,:] = emb[z[n],:] @ W_init
// ---------------------------------------------------------------------------
__global__ void k_node_init(const float* __restrict__ emb, const int* __restrict__ z,
                            const float* __restrict__ W_init, float* __restrict__ h0, int N)
{
  __shared__ float sW[256];
  if (threadIdx.x < 256) sW[threadIdx.x] = W_init[threadIdx.x];
  __syncthreads();
  int n = blockIdx.x * blockDim.x + threadIdx.x;
  if (n >= N) return;
  const float* e = emb + z[n]*16;
  float ev[16];
  #pragma unroll
  for (int k = 0; k < 16; k++) ev[k] = e[k];
  #pragma unroll
  for (int c = 0; c < 16; c++) {
    float s = 0.f;
    #pragma unroll
    for (int k = 0; k < 16; k++) s += ev[k] * sW[k*16+c];
    h0[n*16+c] = s;
  }
}

// ---------------------------------------------------------------------------
// Edge forward: 16 threads per edge (one per channel c).
// a0[row,c] += m0 ; if !last: a1[row,c,m] += m1, a2[row,c,m] += m2
// ---------------------------------------------------------------------------
__global__ void k_edge_fwd(const float* __restrict__ pos, const int* __restrict__ ei, int E,
                           const float* __restrict__ Wr, const float* __restrict__ br,
                           const float* __restrict__ h0_in, const float* __restrict__ h1_in,
                           const float* __restrict__ h2_in,
                           float* __restrict__ a0, float* __restrict__ a1, float* __restrict__ a2,
                           int last)
{
  __shared__ float sWr[8*80];
  __shared__ float sbr[80];
  for (int i = threadIdx.x; i < 8*80; i += blockDim.x) sWr[i] = Wr[i];
  for (int i = threadIdx.x; i < 80; i += blockDim.x) sbr[i] = br[i];
  __syncthreads();
  int e = blockIdx.x * (blockDim.x >> 4) + (threadIdx.x >> 4);
  int c = threadIdx.x & 15;
  if (e >= E) return;
  int row = ei[e], col = ei[E + e];

  float r, inv_r, ux, uy, uz, rad[8], sh1[3], sh2[5];
  edge_geom(pos, row, col, r, inv_r, ux, uy, uz, rad, sh1, sh2);

  float w[5];
  #pragma unroll
  for (int p = 0; p < 5; p++) {
    float s = sbr[p*16 + c];
    #pragma unroll
    for (int n = 0; n < 8; n++) s += rad[n] * sWr[n*80 + p*16 + c];
    w[p] = s;
  }

  float h0c = h0_in[col*16 + c];
  float S1 = 0.f, S2 = 0.f;
  if (h1_in) {
    #pragma unroll
    for (int m = 0; m < 3; m++) S1 += h1_in[col*48 + c*3 + m] * sh1[m];
    #pragma unroll
    for (int m = 0; m < 5; m++) S2 += h2_in[col*80 + c*5 + m] * sh2[m];
  }
  float m0 = w[0]*h0c + w[3]*S1 + w[4]*S2;
  atomicAdd(&a0[row*16 + c], m0);
  if (!last) {
    float wh1 = w[1]*h0c;
    #pragma unroll
    for (int m = 0; m < 3; m++) atomicAdd(&a1[row*48 + c*3 + m], wh1*sh1[m]);
    float wh2 = w[2]*h0c;
    #pragma unroll
    for (int m = 0; m < 5; m++) atomicAdd(&a2[row*80 + c*5 + m], wh2*sh2[m]);
  }
}

// ---------------------------------------------------------------------------
// Node update: h_out = h_in + a @ U  (one thread per (n,d))
// Note: when full=1 the incoming h1/h2 are identically zero (block 0 input),
// so v1/v2 start at 0 — no h1_in/h2_in reads needed.
// ---------------------------------------------------------------------------
__global__ void k_node_update(const float* __restrict__ h0_in,
                              const float* __restrict__ a0, const float* __restrict__ a1,
                              const float* __restrict__ a2,
                              const float* __restrict__ U,   // W_out[b]: 3*16*16
                              float* __restrict__ h0_out, float* __restrict__ h1_out,
                              float* __restrict__ h2_out, int N, int full)
{
  int idx = blockIdx.x * blockDim.x + threadIdx.x;
  int n = idx >> 4, d = idx & 15;
  if (n >= N) return;
  const float* U0 = U;
  const float* U1 = U + 256;
  const float* U2 = U + 512;
  float s = h0_in[n*16 + d];
  #pragma unroll
  for (int c = 0; c < 16; c++) s += a0[n*16 + c] * U0[c*16 + d];
  h0_out[n*16 + d] = s;
  if (full) {
    float v1[3] = {0.f, 0.f, 0.f};
    #pragma unroll
    for (int c = 0; c < 16; c++) {
      float u = U1[c*16 + d];
      #pragma unroll
      for (int m = 0; m < 3; m++) v1[m] += a1[n*48 + c*3 + m] * u;
    }
    #pragma unroll
    for (int m = 0; m < 3; m++) h1_out[n*48 + d*3 + m] = v1[m];
    float v2[5] = {0.f, 0.f, 0.f, 0.f, 0.f};
    #pragma unroll
    for (int c = 0; c < 16; c++) {
      float u = U2[c*16 + d];
      #pragma unroll
      for (int m = 0; m < 5; m++) v2[m] += a2[n*80 + c*5 + m] * u;
    }
    #pragma unroll
    for (int m = 0; m < 5; m++) h2_out[n*80 + d*5 + m] = v2[m];
  }
}

// ---------------------------------------------------------------------------
// Readout fwd + bwd fused: energy += site(n); g0[n,:] = dE/dh0_final[n,:]
// ---------------------------------------------------------------------------
__global__ void k_readout_bwd(const float* __restrict__ h0, const float* __restrict__ W_read,
                              const float* __restrict__ W1, const float* __restrict__ b1,
                              const float* __restrict__ W2, const float* __restrict__ b2,
                              float* __restrict__ g0, float* __restrict__ energy, int N)
{
  int n = blockIdx.x * blockDim.x + threadIdx.x;
  float site = 0.f;
  if (n < N) {
    float h[16], inv[16], dt[16];
    #pragma unroll
    for (int d = 0; d < 16; d++) h[d] = h0[n*16 + d];
    #pragma unroll
    for (int j = 0; j < 16; j++) {
      float s = 0.f;
      #pragma unroll
      for (int d = 0; d < 16; d++) s += h[d] * W_read[d*16 + j];
      inv[j] = s;
    }
    site = b2[0];
    #pragma unroll
    for (int c = 0; c < 16; c++) {
      float t = b1[c];
      #pragma unroll
      for (int j = 0; j < 16; j++) t += inv[j] * W1[j*16 + c];
      float sg = 1.f / (1.f + expf(-t));
      float w2v = W2[c];
      site += t * sg * w2v;
      dt[c] = w2v * sg * (1.f + t * (1.f - sg));   // W2 * silu'(t)
    }
    float dinv[16];
    #pragma unroll
    for (int j = 0; j < 16; j++) {
      float s = 0.f;
      #pragma unroll
      for (int c = 0; c < 16; c++) s += dt[c] * W1[j*16 + c];
      dinv[j] = s;
    }
    #pragma unroll
    for (int d = 0; d < 16; d++) {
      float s = 0.f;
      #pragma unroll
      for (int j = 0; j < 16; j++) s += dinv[j] * W_read[d*16 + j];
      g0[n*16 + d] = s;
    }
  }
  // wave-level reduction of site, one atomic per wave
  #pragma unroll
  for (int off = 32; off; off >>= 1) site += __shfl_down(site, off, 64);
  if ((threadIdx.x & 63) == 0) atomicAdd(energy, site);
}

// ---------------------------------------------------------------------------
// ga = g @ U^T  (dE/da from dE/dh_out). One thread per (n,c).
// ---------------------------------------------------------------------------
__global__ void k_ga(const float* __restrict__ g0, const float* __restrict__ g1,
                     const float* __restrict__ g2, const float* __restrict__ U,
                     float* __restrict__ ga0, float* __restrict__ ga1, float* __restrict__ ga2,
                     int N, int full)
{
  int idx = blockIdx.x * blockDim.x + threadIdx.x;
  int n = idx >> 4, c = idx & 15;
  if (n >= N) return;
  const float* U0 = U;
  const float* U1 = U + 256;
  const float* U2 = U + 512;
  float s = 0.f;
  #pragma unroll
  for (int d = 0; d < 16; d++) s += g0[n*16 + d] * U0[c*16 + d];
  ga0[n*16 + c] = s;
  if (full) {
    float v1[3] = {0.f, 0.f, 0.f};
    #pragma unroll
    for (int d = 0; d < 16; d++) {
      float u = U1[c*16 + d];
      #pragma unroll
      for (int m = 0; m < 3; m++) v1[m] += g1[n*48 + d*3 + m] * u;
    }
    #pragma unroll
    for (int m = 0; m < 3; m++) ga1[n*48 + c*3 + m] = v1[m];
    float v2[5] = {0.f, 0.f, 0.f, 0.f, 0.f};
    #pragma unroll
    for (int d = 0; d < 16; d++) {
      float u = U2[c*16 + d];
      #pragma unroll
      for (int m = 0; m < 5; m++) v2[m] += g2[n*80 + d*5 + m] * u;
    }
    #pragma unroll
    for (int m = 0; m < 5; m++) ga2[n*80 + c*5 + m] = v2[m];
  }
}

// ---------------------------------------------------------------------------
// Backward through block 1 edges: dm1=dm2=0 (h1/h2 final are dead).
// Scatters dh0/dh1/dh2 into g0/g1/g2[col]; dvec into forces.
// ---------------------------------------------------------------------------
__global__ void k_edge_bwd_b1(const float* __restrict__ pos, const int* __restrict__ ei, int E,
                              const float* __restrict__ Wr, const float* __restrict__ br,
                              const float* __restrict__ h0_in, const float* __restrict__ h1_in,
                              const float* __restrict__ h2_in,
                              const float* __restrict__ ga0,
                              float* __restrict__ g0, float* __restrict__ g1, float* __restrict__ g2,
                              float* __restrict__ force)
{
  __shared__ float sWr[8*80];
  __shared__ float sbr[80];
  for (int i = threadIdx.x; i < 8*80; i += blockDim.x) sWr[i] = Wr[i];
  for (int i = threadIdx.x; i < 80; i += blockDim.x) sbr[i] = br[i];
  __syncthreads();
  int e = blockIdx.x * (blockDim.x >> 4) + (threadIdx.x >> 4);
  int c = threadIdx.x & 15;
  if (e >= E) return;
  int row = ei[e], col = ei[E + e];

  float r, inv_r, ux, uy, uz, rad[8], sh1[3], sh2[5], draddr[8];
  edge_geom(pos, row, col, r, inv_r, ux, uy, uz, rad, sh1, sh2);
  edge_geom_bwd_extra(r, inv_r, rad, draddr);

  // w0, w3, w4 of block 1
  float w0 = sbr[c], w3 = sbr[48 + c], w4 = sbr[64 + c];
  #pragma unroll
  for (int n = 0; n < 8; n++) {
    w0 += rad[n] * sWr[n*80 + c];
    w3 += rad[n] * sWr[n*80 + 48 + c];
    w4 += rad[n] * sWr[n*80 + 64 + c];
  }

  float dm0 = ga0[row*16 + c];
  float h0c = h0_in[col*16 + c];
  float h1c[3], h2c[5];
  float S1 = 0.f, S2 = 0.f;
  #pragma unroll
  for (int m = 0; m < 3; m++) { h1c[m] = h1_in[col*48 + c*3 + m]; S1 += h1c[m]*sh1[m]; }
  #pragma unroll
  for (int m = 0; m < 5; m++) { h2c[m] = h2_in[col*80 + c*5 + m]; S2 += h2c[m]*sh2[m]; }

  float dw0 = dm0 * h0c;
  float dw3 = dm0 * S1;
  float dw4 = dm0 * S2;

  // node-gradient scatters
  atomicAdd(&g0[col*16 + c], dm0 * w0);
  float t3 = dm0 * w3;
  #pragma unroll
  for (int m = 0; m < 3; m++) atomicAdd(&g1[col*48 + c*3 + m], t3 * sh1[m]);
  float t4 = dm0 * w4;
  #pragma unroll
  for (int m = 0; m < 5; m++) atomicAdd(&g2[col*80 + c*5 + m], t4 * sh2[m]);

  // geometric gradients (per-channel partials)
  float gsh1[3], gsh2[5];
  #pragma unroll
  for (int m = 0; m < 3; m++) gsh1[m] = t3 * h1c[m];
  #pragma unroll
  for (int m = 0; m < 5; m++) gsh2[m] = t4 * h2c[m];
  float gr = 0.f;
  #pragma unroll
  for (int n = 0; n < 8; n++) {
    float gradial = dw0 * sWr[n*80 + c] + dw3 * sWr[n*80 + 48 + c] + dw4 * sWr[n*80 + 64 + c];
    gr += gradial * draddr[n];
  }

  gr = grp16_sum(gr);
  #pragma unroll
  for (int m = 0; m < 3; m++) gsh1[m] = grp16_sum(gsh1[m]);
  #pragma unroll
  for (int m = 0; m < 5; m++) gsh2[m] = grp16_sum(gsh2[m]);

  if (c == 0) {
    const float s3  = 1.7320508075688772f;
    const float s5  = 2.23606797749979f;
    const float s15 = 3.872983346207417f;
    float gux = s3*gsh1[0] + s15*(uy*gsh2[0] + uz*gsh2[3] + ux*gsh2[4]);
    float guy = s3*gsh1[1] + s15*(ux*gsh2[0] + uz*gsh2[1] - uy*gsh2[4]);
    float guz = s3*gsh1[2] + s15*uy*gsh2[1] + 3.f*s5*uz*gsh2[2] + s15*ux*gsh2[3];
    float gdotu = gux*ux + guy*uy + guz*uz;
    float dvx = gr*ux + (gux - gdotu*ux)*inv_r;
    float dvy = gr*uy + (guy - gdotu*uy)*inv_r;
    float dvz = gr*uz + (guz - gdotu*uz)*inv_r;
    // force = -dE/dpos; dE/dpos[row] += dv, dE/dpos[col] -= dv
    atomicAdd(&force[row*3+0], -dvx);
    atomicAdd(&force[row*3+1], -dvy);
    atomicAdd(&force[row*3+2], -dvz);
    atomicAdd(&force[col*3+0],  dvx);
    atomicAdd(&force[col*3+1],  dvy);
    atomicAdd(&force[col*3+2],  dvz);
  }
}

// ---------------------------------------------------------------------------
// Backward through block 0 edges: h1c=h2c=0 => only geometric gradients,
// no node scatters (h0_0 has no pos dependence).
// ---------------------------------------------------------------------------
__global__ void k_edge_bwd_b0(const float* __restrict__ pos, const int* __restrict__ ei, int E,
                              const float* __restrict__ Wr, const float* __restrict__ br,
                              const float* __restrict__ h0_in,
                              const float* __restrict__ ga0, const float* __restrict__ ga1,
                              const float* __restrict__ ga2,
                              float* __restrict__ force)
{
  __shared__ float sWr[8*80];
  __shared__ float sbr[80];
  for (int i = threadIdx.x; i < 8*80; i += blockDim.x) sWr[i] = Wr[i];
  for (int i = threadIdx.x; i < 80; i += blockDim.x) sbr[i] = br[i];
  __syncthreads();
  int e = blockIdx.x * (blockDim.x >> 4) + (threadIdx.x >> 4);
  int c = threadIdx.x & 15;
  if (e >= E) return;
  int row = ei[e], col = ei[E + e];

  float r, inv_r, ux, uy, uz, rad[8], sh1[3], sh2[5], draddr[8];
  edge_geom(pos, row, col, r, inv_r, ux, uy, uz, rad, sh1, sh2);
  edge_geom_bwd_extra(r, inv_r, rad, draddr);

  // w1, w2 of block 0
  float w1 = sbr[16 + c], w2v = sbr[32 + c];
  #pragma unroll
  for (int n = 0; n < 8; n++) {
    w1  += rad[n] * sWr[n*80 + 16 + c];
    w2v += rad[n] * sWr[n*80 + 32 + c];
  }

  float dm0 = ga0[row*16 + c];
  float dm1[3], dm2[5];
  #pragma unroll
  for (int m = 0; m < 3; m++) dm1[m] = ga1[row*48 + c*3 + m];
  #pragma unroll
  for (int m = 0; m < 5; m++) dm2[m] = ga2[row*80 + c*5 + m];

  float h0c = h0_in[col*16 + c];
  float T1 = 0.f, T2 = 0.f;
  #pragma unroll
  for (int m = 0; m < 3; m++) T1 += dm1[m] * sh1[m];
  #pragma unroll
  for (int m = 0; m < 5; m++) T2 += dm2[m] * sh2[m];

  float dw0 = dm0 * h0c;
  float dw1 = h0c * T1;
  float dw2 = h0c * T2;

  float gsh1[3], gsh2[5];
  float w1h = w1 * h0c, w2h = w2v * h0c;
  #pragma unroll
  for (int m = 0; m < 3; m++) gsh1[m] = dm1[m] * w1h;
  #pragma unroll
  for (int m = 0; m < 5; m++) gsh2[m] = dm2[m] * w2h;
  float gr = 0.f;
  #pragma unroll
  for (int n = 0; n < 8; n++) {
    float gradial = dw0 * sWr[n*80 + c] + dw1 * sWr[n*80 + 16 + c] + dw2 * sWr[n*80 + 32 + c];
    gr += gradial * draddr[n];
  }

  gr = grp16_sum(gr);
  #pragma unroll
  for (int m = 0; m < 3; m++) gsh1[m] = grp16_sum(gsh1[m]);
  #pragma unroll
  for (int m = 0; m < 5; m++) gsh2[m] = grp16_sum(gsh2[m]);

  if (c == 0) {
    const float s3  = 1.7320508075688772f;
    const float s5  = 2.23606797749979f;
    const float s15 = 3.872983346207417f;
    float gux = s3*gsh1[0] + s15*(uy*gsh2[0] + uz*gsh2[3] + ux*gsh2[4]);
    float guy = s3*gsh1[1] + s15*(ux*gsh2[0] + uz*gsh2[1] - uy*gsh2[4]);
    float guz = s3*gsh1[2] + s15*uy*gsh2[1] + 3.f*s5*uz*gsh2[2] + s15*ux*gsh2[3];
    float gdotu = gux*ux + guy*uy + guz*uz;
    float dvx = gr*ux + (gux - gdotu*ux)*inv_r;
    float dvy = gr*uy + (guy - gdotu*uy)*inv_r;
    float dvz = gr*uz + (guz - gdotu*uz)*inv_r;
    atomicAdd(&force[row*3+0], -dvx);
    atomicAdd(&force[row*3+1], -dvy);
    atomicAdd(&force[row*3+2], -dvz);
    atomicAdd(&force[col*3+0],  dvx);
    atomicAdd(&force[col*3+1],  dvy);
    atomicAdd(&force[col*3+2],  dvz);
  }
}

// ---------------------------------------------------------------------------
extern "C" void kernel_launch(void* const* d_in, const int* in_sizes, int n_in,
                              void* d_out, int out_size, void* d_ws, size_t ws_size,
                              hipStream_t stream)
{
  const float* pos    = (const float*)d_in[0];
  const int*   z      = (const int*)  d_in[1];
  const int*   ei     = (const int*)  d_in[2];
  const float* emb    = (const float*)d_in[3];
  const float* W_init = (const float*)d_in[4];
  const float* Wr     = (const float*)d_in[5];   // (2, 8, 80)
  const float* br     = (const float*)d_in[6];   // (2, 80)
  const float* W_out  = (const float*)d_in[7];   // (2, 3, 16, 16)
  const float* W_read = (const float*)d_in[8];
  const float* W1     = (const float*)d_in[9];
  const float* b1     = (const float*)d_in[10];
  const float* W2     = (const float*)d_in[11];
  const float* b2     = (const float*)d_in[12];

  const int N = in_sizes[0] / 3;
  const int E = in_sizes[2] / 2;

  float* ws = (float*)d_ws;
  float* h0_s0 = ws; ws += (size_t)N*16;
  float* h0_s1 = ws; ws += (size_t)N*16;
  float* h0_s2 = ws; ws += (size_t)N*16;
  float* h1_s1 = ws; ws += (size_t)N*48;
  float* h2_s1 = ws; ws += (size_t)N*80;
  float* a0    = ws; ws += (size_t)N*16;   // also ga0 in backward
  float* a1    = ws; ws += (size_t)N*48;   // also ga1
  float* a2    = ws; ws += (size_t)N*80;   // also ga2
  float* g0    = ws; ws += (size_t)N*16;
  float* g1    = ws; ws += (size_t)N*48;
  float* g2    = ws; ws += (size_t)N*80;

  float* out    = (float*)d_out;
  float* energy = out;
  float* force  = out + 1;

  const int BLK = 256;
  const int EPB = BLK / 16;  // edges per block

  (void)hipMemsetAsync(d_out, 0, (size_t)out_size * sizeof(float), stream);
  (void)hipMemsetAsync(a0, 0, (size_t)N * 144 * sizeof(float), stream);

  k_node_init<<<cdiv(N, BLK), BLK, 0, stream>>>(emb, z, W_init, h0_s0, N);

  // ---- forward block 0 ----
  k_edge_fwd<<<cdiv(E, EPB), BLK, 0, stream>>>(pos, ei, E, Wr, br,
                                               h0_s0, nullptr, nullptr, a0, a1, a2, 0);
  k_node_update<<<cdiv(N*16, BLK), BLK, 0, stream>>>(h0_s0, a0, a1, a2,
                                                     W_out, h0_s1, h1_s1, h2_s1, N, 1);

  // ---- forward block 1 (only h0 path is live) ----
  (void)hipMemsetAsync(a0, 0, (size_t)N * 16 * sizeof(float), stream);
  k_edge_fwd<<<cdiv(E, EPB), BLK, 0, stream>>>(pos, ei, E, Wr + 640, br + 80,
                                               h0_s1, h1_s1, h2_s1, a0, a1, a2, 1);
  k_node_update<<<cdiv(N*16, BLK), BLK, 0, stream>>>(h0_s1, a0, nullptr, nullptr,
                                                     W_out + 768, h0_s2, nullptr, nullptr, N, 0);

  // ---- readout fwd + bwd: energy, g0 = dE/dh0_final ----
  k_readout_bwd<<<cdiv(N, BLK), BLK, 0, stream>>>(h0_s2, W_read, W1, b1, W2, b2, g0, energy, N);

  // ---- backward block 1 ----
  k_ga<<<cdiv(N*16, BLK), BLK, 0, stream>>>(g0, nullptr, nullptr, W_out + 768,
                                            a0, nullptr, nullptr, N, 0);
  (void)hipMemsetAsync(g1, 0, (size_t)N * 128 * sizeof(float), stream);
  k_edge_bwd_b1<<<cdiv(E, EPB), BLK, 0, stream>>>(pos, ei, E, Wr + 640, br + 80,
                                                  h0_s1, h1_s1, h2_s1, a0, g0, g1, g2, force);

  // ---- backward block 0 ----
  k_ga<<<cdiv(N*16, BLK), BLK, 0, stream>>>(g0, g1, g2, W_out, a0, a1, a2, N, 1);
  k_edge_bwd_b0<<<cdiv(E, EPB), BLK, 0, stream>>>(pos, ei, E, Wr, br,
                                                  h0_s0, a0, a1, a2, force);
}

// Round 3
// 1260.524 us; speedup vs baseline: 1.8700x; 1.8700x over previous
//
#include <hip/hip_runtime.h>
#include <math.h>

#ifndef M_PI
#define M_PI 3.14159265358979323846
#endif

static inline int cdiv(int a, int b){ return (a + b - 1) / b; }

// ---------------------------------------------------------------------------
// Per-edge geometry
// ---------------------------------------------------------------------------
__device__ __forceinline__ void edge_geom_v(float px, float py, float pz,
    float& r, float& inv_r, float& ux, float& uy, float& uz,
    float* rad, float* sh1, float* sh2)
{
  float r2 = px*px + py*py + pz*pz + 1e-12f;
  r = sqrtf(r2);
  inv_r = 1.0f / r;
  ux = px*inv_r; uy = py*inv_r; uz = pz*inv_r;
  const float K = 0.6324555320336759f;  // sqrt(2/R_MAX), R_MAX=5
  #pragma unroll
  for (int n = 0; n < 8; n++) {
    float cn = (float)(n+1) * (float)(M_PI / 5.0);
    rad[n] = K * sinf(cn * r) * inv_r;
  }
  const float s3  = 1.7320508075688772f;
  const float s5  = 2.23606797749979f;
  const float s15 = 3.872983346207417f;
  sh1[0] = s3*ux; sh1[1] = s3*uy; sh1[2] = s3*uz;
  sh2[0] = s15*ux*uy;
  sh2[1] = s15*uy*uz;
  sh2[2] = 0.5f*s5*(3.f*uz*uz - 1.f);
  sh2[3] = s15*ux*uz;
  sh2[4] = 0.5f*s15*(ux*ux - uy*uy);
}

__device__ __forceinline__ void edge_geom_bwd_extra(float r, float inv_r,
    const float* rad, float* draddr)
{
  const float K = 0.6324555320336759f;
  #pragma unroll
  for (int n = 0; n < 8; n++) {
    float cn = (float)(n+1) * (float)(M_PI / 5.0);
    draddr[n] = (K * cn * cosf(cn * r) - rad[n]) * inv_r;
  }
}

__device__ __forceinline__ float grp16_sum(float v){
  v += __shfl_xor(v, 1, 64);
  v += __shfl_xor(v, 2, 64);
  v += __shfl_xor(v, 4, 64);
  v += __shfl_xor(v, 8, 64);
  return v;
}

// ---------------------------------------------------------------------------
// CSR build: histogram, scan (1 wave), scatter
// ---------------------------------------------------------------------------
__global__ void k_hist(const int* __restrict__ ei, int E,
                       int* __restrict__ deg_row, int* __restrict__ deg_col)
{
  int e = blockIdx.x * blockDim.x + threadIdx.x;
  if (e >= E) return;
  atomicAdd(&deg_row[ei[e]], 1);
  atomicAdd(&deg_col[ei[E + e]], 1);
}

__global__ void k_scan(const int* __restrict__ degA, const int* __restrict__ degB,
                       int* __restrict__ offA, int* __restrict__ offB,
                       int* __restrict__ curA, int* __restrict__ curB, int N)
{
  int lane = threadIdx.x;            // 64 threads, one wave
  for (int which = 0; which < 2; which++) {
    const int* deg = which ? degB : degA;
    int* off = which ? offB : offA;
    int* cur = which ? curB : curA;
    int chunk = (N + 63) / 64;
    int lo = lane * chunk;
    int hi = lo + chunk; if (hi > N) hi = N; if (lo > N) lo = N;
    int s = 0;
    for (int i = lo; i < hi; i++) s += deg[i];
    int incl = s;
    #pragma unroll
    for (int d = 1; d < 64; d <<= 1) {
      int y = __shfl_up(incl, d, 64);
      if (lane >= d) incl += y;
    }
    int running = incl - s;          // exclusive prefix of chunk sums
    for (int i = lo; i < hi; i++) {
      off[i] = running; cur[i] = running;
      running += deg[i];
    }
    int total = __shfl(incl, 63, 64);
    if (lane == 0) off[N] = total;
  }
}

__global__ void k_scatter(const int* __restrict__ ei, int E,
                          int* __restrict__ cur_row, int* __restrict__ cur_col,
                          int* __restrict__ eid_row, int* __restrict__ eid_col)
{
  int e = blockIdx.x * blockDim.x + threadIdx.x;
  if (e >= E) return;
  int pr = atomicAdd(&cur_row[ei[e]], 1);
  eid_row[pr] = e;
  int pc = atomicAdd(&cur_col[ei[E + e]], 1);
  eid_col[pc] = e;
}

// ---------------------------------------------------------------------------
// h0_init[n,:] = emb[z[n],:] @ W_init
// ---------------------------------------------------------------------------
__global__ void k_node_init(const float* __restrict__ emb, const int* __restrict__ z,
                            const float* __restrict__ W_init, float* __restrict__ h0, int N)
{
  __shared__ float sW[256];
  if (threadIdx.x < 256) sW[threadIdx.x] = W_init[threadIdx.x];
  __syncthreads();
  int n = blockIdx.x * blockDim.x + threadIdx.x;
  if (n >= N) return;
  const float* e = emb + z[n]*16;
  float ev[16];
  #pragma unroll
  for (int k = 0; k < 16; k++) ev[k] = e[k];
  #pragma unroll
  for (int c = 0; c < 16; c++) {
    float s = 0.f;
    #pragma unroll
    for (int k = 0; k < 16; k++) s += ev[k] * sW[k*16+c];
    h0[n*16+c] = s;
  }
}

// ---------------------------------------------------------------------------
// Forward, node-centric gather over row-incident edges. 16 lanes per node.
// last=0 (block 0): a0 += w0*h0c; a1 += (w1*h0c)*sh1; a2 += (w2*h0c)*sh2
// last=1 (block 1): a0 += w0*h0c + w3*S1 + w4*S2
// ---------------------------------------------------------------------------
__global__ void k_fwd_gather(const float* __restrict__ pos, const int* __restrict__ ei, int E,
                             const float* __restrict__ Wr, const float* __restrict__ br,
                             const float* __restrict__ h0_in, const float* __restrict__ h1_in,
                             const float* __restrict__ h2_in,
                             const int* __restrict__ off_row, const int* __restrict__ eid_row,
                             float* __restrict__ a0, float* __restrict__ a1, float* __restrict__ a2,
                             int N, int last)
{
  __shared__ float sWr[8*80];
  __shared__ float sbr[80];
  for (int i = threadIdx.x; i < 8*80; i += blockDim.x) sWr[i] = Wr[i];
  for (int i = threadIdx.x; i < 80; i += blockDim.x) sbr[i] = br[i];
  __syncthreads();
  int n = blockIdx.x * (blockDim.x >> 4) + (threadIdx.x >> 4);
  int c = threadIdx.x & 15;
  if (n >= N) return;
  float rx = pos[n*3+0], ry = pos[n*3+1], rz = pos[n*3+2];

  float acc0 = 0.f;
  float acc1[3] = {0.f,0.f,0.f};
  float acc2[5] = {0.f,0.f,0.f,0.f,0.f};

  int i0 = off_row[n], i1 = off_row[n+1];
  for (int i = i0; i < i1; i++) {
    int e = eid_row[i];
    int col = ei[E + e];
    float r, inv_r, ux, uy, uz, rad[8], sh1[3], sh2[5];
    edge_geom_v(rx - pos[col*3+0], ry - pos[col*3+1], rz - pos[col*3+2],
                r, inv_r, ux, uy, uz, rad, sh1, sh2);
    float h0c = h0_in[col*16 + c];
    if (last) {
      float w0 = sbr[c], w3 = sbr[48 + c], w4 = sbr[64 + c];
      #pragma unroll
      for (int k = 0; k < 8; k++) {
        w0 += rad[k] * sWr[k*80 + c];
        w3 += rad[k] * sWr[k*80 + 48 + c];
        w4 += rad[k] * sWr[k*80 + 64 + c];
      }
      float S1 = 0.f, S2 = 0.f;
      #pragma unroll
      for (int m = 0; m < 3; m++) S1 += h1_in[col*48 + c*3 + m] * sh1[m];
      #pragma unroll
      for (int m = 0; m < 5; m++) S2 += h2_in[col*80 + c*5 + m] * sh2[m];
      acc0 += w0*h0c + w3*S1 + w4*S2;
    } else {
      float w0 = sbr[c], w1 = sbr[16 + c], w2 = sbr[32 + c];
      #pragma unroll
      for (int k = 0; k < 8; k++) {
        w0 += rad[k] * sWr[k*80 + c];
        w1 += rad[k] * sWr[k*80 + 16 + c];
        w2 += rad[k] * sWr[k*80 + 32 + c];
      }
      acc0 += w0*h0c;
      float wh1 = w1*h0c, wh2 = w2*h0c;
      #pragma unroll
      for (int m = 0; m < 3; m++) acc1[m] += wh1*sh1[m];
      #pragma unroll
      for (int m = 0; m < 5; m++) acc2[m] += wh2*sh2[m];
    }
  }
  a0[n*16 + c] = acc0;
  if (!last) {
    #pragma unroll
    for (int m = 0; m < 3; m++) a1[n*48 + c*3 + m] = acc1[m];
    #pragma unroll
    for (int m = 0; m < 5; m++) a2[n*80 + c*5 + m] = acc2[m];
  }
}

// ---------------------------------------------------------------------------
// Node update: h_out = h_in + a @ U
// ---------------------------------------------------------------------------
__global__ void k_node_update(const float* __restrict__ h0_in,
                              const float* __restrict__ a0, const float* __restrict__ a1,
                              const float* __restrict__ a2,
                              const float* __restrict__ U,
                              float* __restrict__ h0_out, float* __restrict__ h1_out,
                              float* __restrict__ h2_out, int N, int full)
{
  int idx = blockIdx.x * blockDim.x + threadIdx.x;
  int n = idx >> 4, d = idx & 15;
  if (n >= N) return;
  const float* U0 = U;
  const float* U1 = U + 256;
  const float* U2 = U + 512;
  float s = h0_in[n*16 + d];
  #pragma unroll
  for (int c = 0; c < 16; c++) s += a0[n*16 + c] * U0[c*16 + d];
  h0_out[n*16 + d] = s;
  if (full) {
    float v1[3] = {0.f, 0.f, 0.f};
    #pragma unroll
    for (int c = 0; c < 16; c++) {
      float u = U1[c*16 + d];
      #pragma unroll
      for (int m = 0; m < 3; m++) v1[m] += a1[n*48 + c*3 + m] * u;
    }
    #pragma unroll
    for (int m = 0; m < 3; m++) h1_out[n*48 + d*3 + m] = v1[m];
    float v2[5] = {0.f, 0.f, 0.f, 0.f, 0.f};
    #pragma unroll
    for (int c = 0; c < 16; c++) {
      float u = U2[c*16 + d];
      #pragma unroll
      for (int m = 0; m < 5; m++) v2[m] += a2[n*80 + c*5 + m] * u;
    }
    #pragma unroll
    for (int m = 0; m < 5; m++) h2_out[n*80 + d*5 + m] = v2[m];
  }
}

// ---------------------------------------------------------------------------
// Readout fwd + bwd fused
// ---------------------------------------------------------------------------
__global__ void k_readout_bwd(const float* __restrict__ h0, const float* __restrict__ W_read,
                              const float* __restrict__ W1, const float* __restrict__ b1,
                              const float* __restrict__ W2, const float* __restrict__ b2,
                              float* __restrict__ g0, float* __restrict__ energy, int N)
{
  int n = blockIdx.x * blockDim.x + threadIdx.x;
  float site = 0.f;
  if (n < N) {
    float h[16], inv[16], dt[16];
    #pragma unroll
    for (int d = 0; d < 16; d++) h[d] = h0[n*16 + d];
    #pragma unroll
    for (int j = 0; j < 16; j++) {
      float s = 0.f;
      #pragma unroll
      for (int d = 0; d < 16; d++) s += h[d] * W_read[d*16 + j];
      inv[j] = s;
    }
    site = b2[0];
    #pragma unroll
    for (int c = 0; c < 16; c++) {
      float t = b1[c];
      #pragma unroll
      for (int j = 0; j < 16; j++) t += inv[j] * W1[j*16 + c];
      float sg = 1.f / (1.f + expf(-t));
      float w2v = W2[c];
      site += t * sg * w2v;
      dt[c] = w2v * sg * (1.f + t * (1.f - sg));
    }
    float dinv[16];
    #pragma unroll
    for (int j = 0; j < 16; j++) {
      float s = 0.f;
      #pragma unroll
      for (int c = 0; c < 16; c++) s += dt[c] * W1[j*16 + c];
      dinv[j] = s;
    }
    #pragma unroll
    for (int d = 0; d < 16; d++) {
      float s = 0.f;
      #pragma unroll
      for (int j = 0; j < 16; j++) s += dinv[j] * W_read[d*16 + j];
      g0[n*16 + d] = s;
    }
  }
  #pragma unroll
  for (int off = 32; off; off >>= 1) site += __shfl_down(site, off, 64);
  if ((threadIdx.x & 63) == 0) atomicAdd(energy, site);
}

// ---------------------------------------------------------------------------
// ga = g @ U^T
// ---------------------------------------------------------------------------
__global__ void k_ga(const float* __restrict__ g0, const float* __restrict__ g1,
                     const float* __restrict__ g2, const float* __restrict__ U,
                     float* __restrict__ ga0, float* __restrict__ ga1, float* __restrict__ ga2,
                     int N, int full)
{
  int idx = blockIdx.x * blockDim.x + threadIdx.x;
  int n = idx >> 4, c = idx & 15;
  if (n >= N) return;
  const float* U0 = U;
  const float* U1 = U + 256;
  const float* U2 = U + 512;
  float s = 0.f;
  #pragma unroll
  for (int d = 0; d < 16; d++) s += g0[n*16 + d] * U0[c*16 + d];
  ga0[n*16 + c] = s;
  if (full) {
    float v1[3] = {0.f, 0.f, 0.f};
    #pragma unroll
    for (int d = 0; d < 16; d++) {
      float u = U1[c*16 + d];
      #pragma unroll
      for (int m = 0; m < 3; m++) v1[m] += g1[n*48 + d*3 + m] * u;
    }
    #pragma unroll
    for (int m = 0; m < 3; m++) ga1[n*48 + c*3 + m] = v1[m];
    float v2[5] = {0.f, 0.f, 0.f, 0.f, 0.f};
    #pragma unroll
    for (int d = 0; d < 16; d++) {
      float u = U2[c*16 + d];
      #pragma unroll
      for (int m = 0; m < 5; m++) v2[m] += g2[n*80 + d*5 + m] * u;
    }
    #pragma unroll
    for (int m = 0; m < 5; m++) ga2[n*80 + c*5 + m] = v2[m];
  }
}

// ---------------------------------------------------------------------------
// Backward block 1, col-centric. For node n (as col), gather over incident
// edges: accumulate g0/g1/g2[n] in registers; write per-edge dv into dv_buf.
// ---------------------------------------------------------------------------
__global__ void k_bwd_b1_col(const float* __restrict__ pos, const int* __restrict__ ei, int E,
                             const float* __restrict__ Wr, const float* __restrict__ br,
                             const float* __restrict__ h0_in, const float* __restrict__ h1_in,
                             const float* __restrict__ h2_in,
                             const float* __restrict__ ga0,
                             const int* __restrict__ off_col, const int* __restrict__ eid_col,
                             float* __restrict__ g0, float* __restrict__ g1, float* __restrict__ g2,
                             float* __restrict__ dv_buf, int N)
{
  __shared__ float sWr[8*80];
  __shared__ float sbr[80];
  for (int i = threadIdx.x; i < 8*80; i += blockDim.x) sWr[i] = Wr[i];
  for (int i = threadIdx.x; i < 80; i += blockDim.x) sbr[i] = br[i];
  __syncthreads();
  int n = blockIdx.x * (blockDim.x >> 4) + (threadIdx.x >> 4);
  int c = threadIdx.x & 15;
  if (n >= N) return;
  float nx = pos[n*3+0], ny = pos[n*3+1], nz = pos[n*3+2];

  float h0c = h0_in[n*16 + c];
  float h1c[3], h2c[5];
  #pragma unroll
  for (int m = 0; m < 3; m++) h1c[m] = h1_in[n*48 + c*3 + m];
  #pragma unroll
  for (int m = 0; m < 5; m++) h2c[m] = h2_in[n*80 + c*5 + m];

  float accg0 = 0.f;
  float accg1[3] = {0.f,0.f,0.f};
  float accg2[5] = {0.f,0.f,0.f,0.f,0.f};

  const float s3  = 1.7320508075688772f;
  const float s5  = 2.23606797749979f;
  const float s15 = 3.872983346207417f;

  int i0 = off_col[n], i1 = off_col[n+1];
  for (int i = i0; i < i1; i++) {
    int e = eid_col[i];
    int row = ei[e];
    float r, inv_r, ux, uy, uz, rad[8], sh1[3], sh2[5], draddr[8];
    edge_geom_v(pos[row*3+0] - nx, pos[row*3+1] - ny, pos[row*3+2] - nz,
                r, inv_r, ux, uy, uz, rad, sh1, sh2);
    edge_geom_bwd_extra(r, inv_r, rad, draddr);

    float w0 = sbr[c], w3 = sbr[48 + c], w4 = sbr[64 + c];
    #pragma unroll
    for (int k = 0; k < 8; k++) {
      w0 += rad[k] * sWr[k*80 + c];
      w3 += rad[k] * sWr[k*80 + 48 + c];
      w4 += rad[k] * sWr[k*80 + 64 + c];
    }

    float dm0 = ga0[row*16 + c];
    float S1 = 0.f, S2 = 0.f;
    #pragma unroll
    for (int m = 0; m < 3; m++) S1 += h1c[m]*sh1[m];
    #pragma unroll
    for (int m = 0; m < 5; m++) S2 += h2c[m]*sh2[m];

    float dw0 = dm0 * h0c;
    float dw3 = dm0 * S1;
    float dw4 = dm0 * S2;

    float t3 = dm0 * w3, t4 = dm0 * w4;
    accg0 += dm0 * w0;
    #pragma unroll
    for (int m = 0; m < 3; m++) accg1[m] += t3 * sh1[m];
    #pragma unroll
    for (int m = 0; m < 5; m++) accg2[m] += t4 * sh2[m];

    float gsh1[3], gsh2[5];
    #pragma unroll
    for (int m = 0; m < 3; m++) gsh1[m] = t3 * h1c[m];
    #pragma unroll
    for (int m = 0; m < 5; m++) gsh2[m] = t4 * h2c[m];
    float gr = 0.f;
    #pragma unroll
    for (int k = 0; k < 8; k++) {
      float gradial = dw0 * sWr[k*80 + c] + dw3 * sWr[k*80 + 48 + c] + dw4 * sWr[k*80 + 64 + c];
      gr += gradial * draddr[k];
    }

    gr = grp16_sum(gr);
    #pragma unroll
    for (int m = 0; m < 3; m++) gsh1[m] = grp16_sum(gsh1[m]);
    #pragma unroll
    for (int m = 0; m < 5; m++) gsh2[m] = grp16_sum(gsh2[m]);

    if (c == 0) {
      float gux = s3*gsh1[0] + s15*(uy*gsh2[0] + uz*gsh2[3] + ux*gsh2[4]);
      float guy = s3*gsh1[1] + s15*(ux*gsh2[0] + uz*gsh2[1] - uy*gsh2[4]);
      float guz = s3*gsh1[2] + s15*uy*gsh2[1] + 3.f*s5*uz*gsh2[2] + s15*ux*gsh2[3];
      float gdotu = gux*ux + guy*uy + guz*uz;
      dv_buf[e*3+0] = gr*ux + (gux - gdotu*ux)*inv_r;
      dv_buf[e*3+1] = gr*uy + (guy - gdotu*uy)*inv_r;
      dv_buf[e*3+2] = gr*uz + (guz - gdotu*uz)*inv_r;
    }
  }
  g0[n*16 + c] += accg0;       // add to readout-gradient (residual identity path)
  #pragma unroll
  for (int m = 0; m < 3; m++) g1[n*48 + c*3 + m] = accg1[m];
  #pragma unroll
  for (int m = 0; m < 5; m++) g2[n*80 + c*5 + m] = accg2[m];
}

// ---------------------------------------------------------------------------
// Backward block 0, edge-parallel (pure gathers): dv_buf[e] += dv
// ---------------------------------------------------------------------------
__global__ void k_bwd_b0_edge(const float* __restrict__ pos, const int* __restrict__ ei, int E,
                              const float* __restrict__ Wr, const float* __restrict__ br,
                              const float* __restrict__ h0_in,
                              const float* __restrict__ ga0, const float* __restrict__ ga1,
                              const float* __restrict__ ga2,
                              float* __restrict__ dv_buf)
{
  __shared__ float sWr[8*80];
  __shared__ float sbr[80];
  for (int i = threadIdx.x; i < 8*80; i += blockDim.x) sWr[i] = Wr[i];
  for (int i = threadIdx.x; i < 80; i += blockDim.x) sbr[i] = br[i];
  __syncthreads();
  int e = blockIdx.x * (blockDim.x >> 4) + (threadIdx.x >> 4);
  int c = threadIdx.x & 15;
  if (e >= E) return;
  int row = ei[e], col = ei[E + e];

  float r, inv_r, ux, uy, uz, rad[8], sh1[3], sh2[5], draddr[8];
  edge_geom_v(pos[row*3+0]-pos[col*3+0], pos[row*3+1]-pos[col*3+1], pos[row*3+2]-pos[col*3+2],
              r, inv_r, ux, uy, uz, rad, sh1, sh2);
  edge_geom_bwd_extra(r, inv_r, rad, draddr);

  float w1 = sbr[16 + c], w2v = sbr[32 + c];
  #pragma unroll
  for (int k = 0; k < 8; k++) {
    w1  += rad[k] * sWr[k*80 + 16 + c];
    w2v += rad[k] * sWr[k*80 + 32 + c];
  }

  float dm0 = ga0[row*16 + c];
  float dm1[3], dm2[5];
  #pragma unroll
  for (int m = 0; m < 3; m++) dm1[m] = ga1[row*48 + c*3 + m];
  #pragma unroll
  for (int m = 0; m < 5; m++) dm2[m] = ga2[row*80 + c*5 + m];

  float h0c = h0_in[col*16 + c];
  float T1 = 0.f, T2 = 0.f;
  #pragma unroll
  for (int m = 0; m < 3; m++) T1 += dm1[m] * sh1[m];
  #pragma unroll
  for (int m = 0; m < 5; m++) T2 += dm2[m] * sh2[m];

  float dw0 = dm0 * h0c;
  float dw1 = h0c * T1;
  float dw2 = h0c * T2;

  float gsh1[3], gsh2[5];
  float w1h = w1 * h0c, w2h = w2v * h0c;
  #pragma unroll
  for (int m = 0; m < 3; m++) gsh1[m] = dm1[m] * w1h;
  #pragma unroll
  for (int m = 0; m < 5; m++) gsh2[m] = dm2[m] * w2h;
  float gr = 0.f;
  #pragma unroll
  for (int k = 0; k < 8; k++) {
    float gradial = dw0 * sWr[k*80 + c] + dw1 * sWr[k*80 + 16 + c] + dw2 * sWr[k*80 + 32 + c];
    gr += gradial * draddr[k];
  }

  gr = grp16_sum(gr);
  #pragma unroll
  for (int m = 0; m < 3; m++) gsh1[m] = grp16_sum(gsh1[m]);
  #pragma unroll
  for (int m = 0; m < 5; m++) gsh2[m] = grp16_sum(gsh2[m]);

  if (c == 0) {
    const float s3  = 1.7320508075688772f;
    const float s5  = 2.23606797749979f;
    const float s15 = 3.872983346207417f;
    float gux = s3*gsh1[0] + s15*(uy*gsh2[0] + uz*gsh2[3] + ux*gsh2[4]);
    float guy = s3*gsh1[1] + s15*(ux*gsh2[0] + uz*gsh2[1] - uy*gsh2[4]);
    float guz = s3*gsh1[2] + s15*uy*gsh2[1] + 3.f*s5*uz*gsh2[2] + s15*ux*gsh2[3];
    float gdotu = gux*ux + guy*uy + guz*uz;
    dv_buf[e*3+0] += gr*ux + (gux - gdotu*ux)*inv_r;
    dv_buf[e*3+1] += gr*uy + (guy - gdotu*uy)*inv_r;
    dv_buf[e*3+2] += gr*uz + (guz - gdotu*uz)*inv_r;
  }
}

// ---------------------------------------------------------------------------
// Force assembly: force[n] = sum_{col==n} dv - sum_{row==n} dv
// (dE/dpos[row] += dv, dE/dpos[col] -= dv; force = -dE/dpos)
// ---------------------------------------------------------------------------
__global__ void k_force(const int* __restrict__ off_row, const int* __restrict__ eid_row,
                        const int* __restrict__ off_col, const int* __restrict__ eid_col,
                        const float* __restrict__ dv, float* __restrict__ force, int N)
{
  int n = blockIdx.x * blockDim.x + threadIdx.x;
  if (n >= N) return;
  float fx = 0.f, fy = 0.f, fz = 0.f;
  for (int i = off_col[n]; i < off_col[n+1]; i++) {
    int e = eid_col[i];
    fx += dv[e*3+0]; fy += dv[e*3+1]; fz += dv[e*3+2];
  }
  for (int i = off_row[n]; i < off_row[n+1]; i++) {
    int e = eid_row[i];
    fx -= dv[e*3+0]; fy -= dv[e*3+1]; fz -= dv[e*3+2];
  }
  force[n*3+0] = fx; force[n*3+1] = fy; force[n*3+2] = fz;
}

// ---------------------------------------------------------------------------
extern "C" void kernel_launch(void* const* d_in, const int* in_sizes, int n_in,
                              void* d_out, int out_size, void* d_ws, size_t ws_size,
                              hipStream_t stream)
{
  const float* pos    = (const float*)d_in[0];
  const int*   z      = (const int*)  d_in[1];
  const int*   ei     = (const int*)  d_in[2];
  const float* emb    = (const float*)d_in[3];
  const float* W_init = (const float*)d_in[4];
  const float* Wr     = (const float*)d_in[5];   // (2, 8, 80)
  const float* br     = (const float*)d_in[6];   // (2, 80)
  const float* W_out  = (const float*)d_in[7];   // (2, 3, 16, 16)
  const float* W_read = (const float*)d_in[8];
  const float* W1     = (const float*)d_in[9];
  const float* b1     = (const float*)d_in[10];
  const float* W2     = (const float*)d_in[11];
  const float* b2     = (const float*)d_in[12];

  const int N = in_sizes[0] / 3;
  const int E = in_sizes[2] / 2;

  float* f = (float*)d_ws;
  float* h0_s0 = f; f += (size_t)N*16;
  float* h0_s1 = f; f += (size_t)N*16;
  float* h0_s2 = f; f += (size_t)N*16;
  float* h1_s1 = f; f += (size_t)N*48;
  float* h2_s1 = f; f += (size_t)N*80;
  float* a0    = f; f += (size_t)N*16;   // also ga0
  float* a1    = f; f += (size_t)N*48;   // also ga1
  float* a2    = f; f += (size_t)N*80;   // also ga2
  float* g0    = f; f += (size_t)N*16;
  float* g1    = f; f += (size_t)N*48;
  float* g2    = f; f += (size_t)N*80;
  float* dv    = f; f += (size_t)E*3;
  int* ip = (int*)f;
  int* deg_row = ip; ip += N;            // deg_row+deg_col contiguous -> one memset
  int* deg_col = ip; ip += N;
  int* off_row = ip; ip += N+1;
  int* off_col = ip; ip += N+1;
  int* cur_row = ip; ip += N;
  int* cur_col = ip; ip += N;
  int* eid_row = ip; ip += E;
  int* eid_col = ip; ip += E;

  float* out    = (float*)d_out;
  float* energy = out;
  float* force  = out + 1;

  const int BLK = 256;
  const int GPB = BLK / 16;  // 16-lane groups per block

  (void)hipMemsetAsync(energy, 0, sizeof(float), stream);
  (void)hipMemsetAsync(deg_row, 0, (size_t)2 * N * sizeof(int), stream);

  // ---- CSR build ----
  k_hist<<<cdiv(E, BLK), BLK, 0, stream>>>(ei, E, deg_row, deg_col);
  k_scan<<<1, 64, 0, stream>>>(deg_row, deg_col, off_row, off_col, cur_row, cur_col, N);
  k_scatter<<<cdiv(E, BLK), BLK, 0, stream>>>(ei, E, cur_row, cur_col, eid_row, eid_col);

  k_node_init<<<cdiv(N, BLK), BLK, 0, stream>>>(emb, z, W_init, h0_s0, N);

  // ---- forward block 0 ----
  k_fwd_gather<<<cdiv(N, GPB), BLK, 0, stream>>>(pos, ei, E, Wr, br,
                                                 h0_s0, nullptr, nullptr,
                                                 off_row, eid_row, a0, a1, a2, N, 0);
  k_node_update<<<cdiv(N*16, BLK), BLK, 0, stream>>>(h0_s0, a0, a1, a2,
                                                     W_out, h0_s1, h1_s1, h2_s1, N, 1);

  // ---- forward block 1 (only h0 path live) ----
  k_fwd_gather<<<cdiv(N, GPB), BLK, 0, stream>>>(pos, ei, E, Wr + 640, br + 80,
                                                 h0_s1, h1_s1, h2_s1,
                                                 off_row, eid_row, a0, nullptr, nullptr, N, 1);
  k_node_update<<<cdiv(N*16, BLK), BLK, 0, stream>>>(h0_s1, a0, nullptr, nullptr,
                                                     W_out + 768, h0_s2, nullptr, nullptr, N, 0);

  // ---- readout fwd + bwd ----
  k_readout_bwd<<<cdiv(N, BLK), BLK, 0, stream>>>(h0_s2, W_read, W1, b1, W2, b2, g0, energy, N);

  // ---- backward block 1 ----
  k_ga<<<cdiv(N*16, BLK), BLK, 0, stream>>>(g0, nullptr, nullptr, W_out + 768,
                                            a0, nullptr, nullptr, N, 0);
  k_bwd_b1_col<<<cdiv(N, GPB), BLK, 0, stream>>>(pos, ei, E, Wr + 640, br + 80,
                                                 h0_s1, h1_s1, h2_s1, a0,
                                                 off_col, eid_col, g0, g1, g2, dv, N);

  // ---- backward block 0 ----
  k_ga<<<cdiv(N*16, BLK), BLK, 0, stream>>>(g0, g1, g2, W_out, a0, a1, a2, N, 1);
  k_bwd_b0_edge<<<cdiv(E, GPB), BLK, 0, stream>>>(pos, ei, E, Wr, br,
                                                  h0_s0, a0, a1, a2, dv);

  // ---- force assembly ----
  k_force<<<cdiv(N, BLK), BLK, 0, stream>>>(off_row, eid_row, off_col, eid_col, dv, force, N);
}

// Round 4
// 898.399 us; speedup vs baseline: 2.6237x; 1.4031x over previous
//
#include <hip/hip_runtime.h>
#include <math.h>

#ifndef M_PI
#define M_PI 3.14159265358979323846
#endif

static inline int cdiv(int a, int b){ return (a + b - 1) / b; }

#define SQRT3f  1.7320508075688772f
#define SQRT5f  2.23606797749979f
#define SQRT15f 3.872983346207417f
#define KRADf   0.6324555320336759f      /* sqrt(2/R_MAX), R_MAX=5 */
#define PI5f    0.6283185307179586f      /* pi/5 */

// ---------------------------------------------------------------------------
// Geometry via Chebyshev recurrence: one sincosf for all 8 radial terms.
// ck may be nullptr (forward: no cos needed).
// ---------------------------------------------------------------------------
__device__ __forceinline__ void geom_core(float px, float py, float pz,
    float& r, float& inv_r, float& ux, float& uy, float& uz,
    float* rad, float* ck, float* sh1, float* sh2)
{
  float r2 = px*px + py*py + pz*pz + 1e-12f;
  r = sqrtf(r2);
  inv_r = 1.0f / r;
  ux = px*inv_r; uy = py*inv_r; uz = pz*inv_r;
  float x = r * PI5f;
  float s1, c1;
  sincosf(x, &s1, &c1);
  float tc = 2.f * c1;
  float sprev = 0.f, s = s1, cprev = 1.f, cc = c1;
  float Ki = KRADf * inv_r;
  #pragma unroll
  for (int k = 0; k < 8; k++) {
    rad[k] = Ki * s;
    if (ck) ck[k] = cc;
    float sn = tc*s - sprev; sprev = s; s = sn;
    float cn = tc*cc - cprev; cprev = cc; cc = cn;
  }
  sh1[0] = SQRT3f*ux; sh1[1] = SQRT3f*uy; sh1[2] = SQRT3f*uz;
  sh2[0] = SQRT15f*ux*uy;
  sh2[1] = SQRT15f*uy*uz;
  sh2[2] = 0.5f*SQRT5f*(3.f*uz*uz - 1.f);
  sh2[3] = SQRT15f*ux*uz;
  sh2[4] = 0.5f*SQRT15f*(ux*ux - uy*uy);
}

// draddr[k] = (K*c_k*cos(c_k r) - rad[k]) / r,  c_k = (k+1)*pi/5
__device__ __forceinline__ void geom_drad(float inv_r, const float* rad, const float* ck,
                                          float* draddr)
{
  const float KPI5 = KRADf * PI5f;
  #pragma unroll
  for (int k = 0; k < 8; k++)
    draddr[k] = (KPI5 * (float)(k+1) * ck[k] - rad[k]) * inv_r;
}

__device__ __forceinline__ float grp16_sum(float v){
  v += __shfl_xor(v, 1, 64);
  v += __shfl_xor(v, 2, 64);
  v += __shfl_xor(v, 4, 64);
  v += __shfl_xor(v, 8, 64);
  return v;
}

// ---------------------------------------------------------------------------
// CSR build: histogram, scan (1 wave), scatter
// ---------------------------------------------------------------------------
__global__ void k_hist(const int* __restrict__ ei, int E,
                       int* __restrict__ deg_row, int* __restrict__ deg_col)
{
  int e = blockIdx.x * blockDim.x + threadIdx.x;
  if (e >= E) return;
  atomicAdd(&deg_row[ei[e]], 1);
  atomicAdd(&deg_col[ei[E + e]], 1);
}

__global__ void k_scan(const int* __restrict__ degA, const int* __restrict__ degB,
                       int* __restrict__ offA, int* __restrict__ offB,
                       int* __restrict__ curA, int* __restrict__ curB, int N)
{
  int lane = threadIdx.x;            // 64 threads, one wave
  for (int which = 0; which < 2; which++) {
    const int* deg = which ? degB : degA;
    int* off = which ? offB : offA;
    int* cur = which ? curB : curA;
    int chunk = (N + 63) / 64;
    int lo = lane * chunk;
    int hi = lo + chunk; if (hi > N) hi = N; if (lo > N) lo = N;
    int s = 0;
    for (int i = lo; i < hi; i++) s += deg[i];
    int incl = s;
    #pragma unroll
    for (int d = 1; d < 64; d <<= 1) {
      int y = __shfl_up(incl, d, 64);
      if (lane >= d) incl += y;
    }
    int running = incl - s;          // exclusive prefix of chunk sums
    for (int i = lo; i < hi; i++) {
      off[i] = running; cur[i] = running;
      running += deg[i];
    }
    int total = __shfl(incl, 63, 64);
    if (lane == 0) off[N] = total;
  }
}

__global__ void k_scatter(const int* __restrict__ ei, int E,
                          int* __restrict__ cur_row, int* __restrict__ cur_col,
                          int* __restrict__ eid_row, int* __restrict__ eid_col)
{
  int e = blockIdx.x * blockDim.x + threadIdx.x;
  if (e >= E) return;
  int pr = atomicAdd(&cur_row[ei[e]], 1);
  eid_row[pr] = e;
  int pc = atomicAdd(&cur_col[ei[E + e]], 1);
  eid_col[pc] = e;
}

// ---------------------------------------------------------------------------
// h0_init[n,:] = emb[z[n],:] @ W_init
// ---------------------------------------------------------------------------
__global__ void k_node_init(const float* __restrict__ emb, const int* __restrict__ z,
                            const float* __restrict__ W_init, float* __restrict__ h0, int N)
{
  __shared__ float sW[256];
  if (threadIdx.x < 256) sW[threadIdx.x] = W_init[threadIdx.x];
  __syncthreads();
  int n = blockIdx.x * blockDim.x + threadIdx.x;
  if (n >= N) return;
  const float* e = emb + z[n]*16;
  float ev[16];
  #pragma unroll
  for (int k = 0; k < 16; k++) ev[k] = e[k];
  #pragma unroll
  for (int c = 0; c < 16; c++) {
    float s = 0.f;
    #pragma unroll
    for (int k = 0; k < 16; k++) s += ev[k] * sW[k*16+c];
    h0[n*16+c] = s;
  }
}

// ---------------------------------------------------------------------------
// Forward block 0, row-centric gather. 16 lanes per node (one per channel).
// a0 += w0*h0c; a1 += (w1*h0c)*sh1; a2 += (w2*h0c)*sh2
// ---------------------------------------------------------------------------
__global__ void k_fwd_b0(const float* __restrict__ pos, const int* __restrict__ ei, int E,
                         const float* __restrict__ Wr, const float* __restrict__ br,
                         const float* __restrict__ h0_in,
                         const int* __restrict__ off_row, const int* __restrict__ eid_row,
                         float* __restrict__ a0, float* __restrict__ a1, float* __restrict__ a2,
                         int N)
{
  int n = blockIdx.x * (blockDim.x >> 4) + (threadIdx.x >> 4);
  int c = threadIdx.x & 15;
  if (n >= N) return;
  float wr0[8], wr1[8], wr2[8];
  #pragma unroll
  for (int k = 0; k < 8; k++) {
    wr0[k] = Wr[k*80 + c];
    wr1[k] = Wr[k*80 + 16 + c];
    wr2[k] = Wr[k*80 + 32 + c];
  }
  float b0v = br[c], b1v = br[16 + c], b2v = br[32 + c];
  float rx = pos[n*3+0], ry = pos[n*3+1], rz = pos[n*3+2];

  float acc0 = 0.f, acc1[3] = {0.f,0.f,0.f}, acc2[5] = {0.f,0.f,0.f,0.f,0.f};

  int i0 = off_row[n], i1 = off_row[n+1];
  float pxn=0.f, pyn=0.f, pzn=0.f, h0n=0.f;
  if (i0 < i1) {
    int e = eid_row[i0]; int col = ei[E + e];
    pxn = rx - pos[col*3+0]; pyn = ry - pos[col*3+1]; pzn = rz - pos[col*3+2];
    h0n = h0_in[col*16 + c];
  }
  for (int i = i0; i < i1; i++) {
    float px = pxn, py = pyn, pz = pzn, h0c = h0n;
    if (i+1 < i1) {
      int e = eid_row[i+1]; int col = ei[E + e];
      pxn = rx - pos[col*3+0]; pyn = ry - pos[col*3+1]; pzn = rz - pos[col*3+2];
      h0n = h0_in[col*16 + c];
    }
    float r, inv_r, ux, uy, uz, rad[8], sh1[3], sh2[5];
    geom_core(px, py, pz, r, inv_r, ux, uy, uz, rad, nullptr, sh1, sh2);
    float w0 = b0v, w1 = b1v, w2 = b2v;
    #pragma unroll
    for (int k = 0; k < 8; k++) {
      w0 += rad[k]*wr0[k]; w1 += rad[k]*wr1[k]; w2 += rad[k]*wr2[k];
    }
    acc0 += w0*h0c;
    float wh1 = w1*h0c, wh2 = w2*h0c;
    #pragma unroll
    for (int m = 0; m < 3; m++) acc1[m] += wh1*sh1[m];
    #pragma unroll
    for (int m = 0; m < 5; m++) acc2[m] += wh2*sh2[m];
  }
  a0[n*16 + c] = acc0;
  #pragma unroll
  for (int m = 0; m < 3; m++) a1[n*48 + c*3 + m] = acc1[m];
  #pragma unroll
  for (int m = 0; m < 5; m++) a2[n*80 + c*5 + m] = acc2[m];
}

// ---------------------------------------------------------------------------
// Forward block 1 (last): a0 += w0*h0c + w3*S1 + w4*S2
// ---------------------------------------------------------------------------
__global__ void k_fwd_b1(const float* __restrict__ pos, const int* __restrict__ ei, int E,
                         const float* __restrict__ Wr, const float* __restrict__ br,
                         const float* __restrict__ h0_in, const float* __restrict__ h1_in,
                         const float* __restrict__ h2_in,
                         const int* __restrict__ off_row, const int* __restrict__ eid_row,
                         float* __restrict__ a0, int N)
{
  int n = blockIdx.x * (blockDim.x >> 4) + (threadIdx.x >> 4);
  int c = threadIdx.x & 15;
  if (n >= N) return;
  float wr0[8], wr3[8], wr4[8];
  #pragma unroll
  for (int k = 0; k < 8; k++) {
    wr0[k] = Wr[k*80 + c];
    wr3[k] = Wr[k*80 + 48 + c];
    wr4[k] = Wr[k*80 + 64 + c];
  }
  float b0v = br[c], b3v = br[48 + c], b4v = br[64 + c];
  float rx = pos[n*3+0], ry = pos[n*3+1], rz = pos[n*3+2];

  float acc0 = 0.f;
  int i0 = off_row[n], i1 = off_row[n+1];
  float pxn=0.f, pyn=0.f, pzn=0.f, h0n=0.f, h1n[3]={0,0,0}, h2n[5]={0,0,0,0,0};
  if (i0 < i1) {
    int e = eid_row[i0]; int col = ei[E + e];
    pxn = rx - pos[col*3+0]; pyn = ry - pos[col*3+1]; pzn = rz - pos[col*3+2];
    h0n = h0_in[col*16 + c];
    #pragma unroll
    for (int m = 0; m < 3; m++) h1n[m] = h1_in[col*48 + c*3 + m];
    #pragma unroll
    for (int m = 0; m < 5; m++) h2n[m] = h2_in[col*80 + c*5 + m];
  }
  for (int i = i0; i < i1; i++) {
    float px = pxn, py = pyn, pz = pzn, h0c = h0n;
    float h1c[3], h2c[5];
    #pragma unroll
    for (int m = 0; m < 3; m++) h1c[m] = h1n[m];
    #pragma unroll
    for (int m = 0; m < 5; m++) h2c[m] = h2n[m];
    if (i+1 < i1) {
      int e = eid_row[i+1]; int col = ei[E + e];
      pxn = rx - pos[col*3+0]; pyn = ry - pos[col*3+1]; pzn = rz - pos[col*3+2];
      h0n = h0_in[col*16 + c];
      #pragma unroll
      for (int m = 0; m < 3; m++) h1n[m] = h1_in[col*48 + c*3 + m];
      #pragma unroll
      for (int m = 0; m < 5; m++) h2n[m] = h2_in[col*80 + c*5 + m];
    }
    float r, inv_r, ux, uy, uz, rad[8], sh1[3], sh2[5];
    geom_core(px, py, pz, r, inv_r, ux, uy, uz, rad, nullptr, sh1, sh2);
    float w0 = b0v, w3 = b3v, w4 = b4v;
    #pragma unroll
    for (int k = 0; k < 8; k++) {
      w0 += rad[k]*wr0[k]; w3 += rad[k]*wr3[k]; w4 += rad[k]*wr4[k];
    }
    float S1 = 0.f, S2 = 0.f;
    #pragma unroll
    for (int m = 0; m < 3; m++) S1 += h1c[m]*sh1[m];
    #pragma unroll
    for (int m = 0; m < 5; m++) S2 += h2c[m]*sh2[m];
    acc0 += w0*h0c + w3*S1 + w4*S2;
  }
  a0[n*16 + c] = acc0;
}

// ---------------------------------------------------------------------------
// Node update: h_out = h_in + a @ U
// ---------------------------------------------------------------------------
__global__ void k_node_update(const float* __restrict__ h0_in,
                              const float* __restrict__ a0, const float* __restrict__ a1,
                              const float* __restrict__ a2,
                              const float* __restrict__ U,
                              float* __restrict__ h0_out, float* __restrict__ h1_out,
                              float* __restrict__ h2_out, int N, int full)
{
  int idx = blockIdx.x * blockDim.x + threadIdx.x;
  int n = idx >> 4, d = idx & 15;
  if (n >= N) return;
  const float* U0 = U;
  const float* U1 = U + 256;
  const float* U2 = U + 512;
  float s = h0_in[n*16 + d];
  #pragma unroll
  for (int c = 0; c < 16; c++) s += a0[n*16 + c] * U0[c*16 + d];
  h0_out[n*16 + d] = s;
  if (full) {
    float v1[3] = {0.f, 0.f, 0.f};
    #pragma unroll
    for (int c = 0; c < 16; c++) {
      float u = U1[c*16 + d];
      #pragma unroll
      for (int m = 0; m < 3; m++) v1[m] += a1[n*48 + c*3 + m] * u;
    }
    #pragma unroll
    for (int m = 0; m < 3; m++) h1_out[n*48 + d*3 + m] = v1[m];
    float v2[5] = {0.f, 0.f, 0.f, 0.f, 0.f};
    #pragma unroll
    for (int c = 0; c < 16; c++) {
      float u = U2[c*16 + d];
      #pragma unroll
      for (int m = 0; m < 5; m++) v2[m] += a2[n*80 + c*5 + m] * u;
    }
    #pragma unroll
    for (int m = 0; m < 5; m++) h2_out[n*80 + d*5 + m] = v2[m];
  }
}

// ---------------------------------------------------------------------------
// Readout fwd + bwd fused
// ---------------------------------------------------------------------------
__global__ void k_readout_bwd(const float* __restrict__ h0, const float* __restrict__ W_read,
                              const float* __restrict__ W1, const float* __restrict__ b1,
                              const float* __restrict__ W2, const float* __restrict__ b2,
                              float* __restrict__ g0, float* __restrict__ energy, int N)
{
  int n = blockIdx.x * blockDim.x + threadIdx.x;
  float site = 0.f;
  if (n < N) {
    float h[16], inv[16], dt[16];
    #pragma unroll
    for (int d = 0; d < 16; d++) h[d] = h0[n*16 + d];
    #pragma unroll
    for (int j = 0; j < 16; j++) {
      float s = 0.f;
      #pragma unroll
      for (int d = 0; d < 16; d++) s += h[d] * W_read[d*16 + j];
      inv[j] = s;
    }
    site = b2[0];
    #pragma unroll
    for (int c = 0; c < 16; c++) {
      float t = b1[c];
      #pragma unroll
      for (int j = 0; j < 16; j++) t += inv[j] * W1[j*16 + c];
      float sg = 1.f / (1.f + expf(-t));
      float w2v = W2[c];
      site += t * sg * w2v;
      dt[c] = w2v * sg * (1.f + t * (1.f - sg));
    }
    float dinv[16];
    #pragma unroll
    for (int j = 0; j < 16; j++) {
      float s = 0.f;
      #pragma unroll
      for (int c = 0; c < 16; c++) s += dt[c] * W1[j*16 + c];
      dinv[j] = s;
    }
    #pragma unroll
    for (int d = 0; d < 16; d++) {
      float s = 0.f;
      #pragma unroll
      for (int j = 0; j < 16; j++) s += dinv[j] * W_read[d*16 + j];
      g0[n*16 + d] = s;
    }
  }
  #pragma unroll
  for (int off = 32; off; off >>= 1) site += __shfl_down(site, off, 64);
  if ((threadIdx.x & 63) == 0) atomicAdd(energy, site);
}

// ---------------------------------------------------------------------------
// ga = g @ U^T
// ---------------------------------------------------------------------------
__global__ void k_ga(const float* __restrict__ g0, const float* __restrict__ g1,
                     const float* __restrict__ g2, const float* __restrict__ U,
                     float* __restrict__ ga0, float* __restrict__ ga1, float* __restrict__ ga2,
                     int N, int full)
{
  int idx = blockIdx.x * blockDim.x + threadIdx.x;
  int n = idx >> 4, c = idx & 15;
  if (n >= N) return;
  const float* U0 = U;
  const float* U1 = U + 256;
  const float* U2 = U + 512;
  float s = 0.f;
  #pragma unroll
  for (int d = 0; d < 16; d++) s += g0[n*16 + d] * U0[c*16 + d];
  ga0[n*16 + c] = s;
  if (full) {
    float v1[3] = {0.f, 0.f, 0.f};
    #pragma unroll
    for (int d = 0; d < 16; d++) {
      float u = U1[c*16 + d];
      #pragma unroll
      for (int m = 0; m < 3; m++) v1[m] += g1[n*48 + d*3 + m] * u;
    }
    #pragma unroll
    for (int m = 0; m < 3; m++) ga1[n*48 + c*3 + m] = v1[m];
    float v2[5] = {0.f, 0.f, 0.f, 0.f, 0.f};
    #pragma unroll
    for (int d = 0; d < 16; d++) {
      float u = U2[c*16 + d];
      #pragma unroll
      for (int m = 0; m < 5; m++) v2[m] += g2[n*80 + d*5 + m] * u;
    }
    #pragma unroll
    for (int m = 0; m < 5; m++) ga2[n*80 + c*5 + m] = v2[m];
  }
}

// ---------------------------------------------------------------------------
// Backward block 1, col-centric. For node n (as col): accumulate g0/g1/g2[n]
// in registers over incident edges; write per-edge dv into dv_buf (assign).
// Per-lane partial (gr, gux, guy, guz) -> 4 grp16 reductions.
// ---------------------------------------------------------------------------
__global__ void k_bwd_b1_col(const float* __restrict__ pos, const int* __restrict__ ei, int E,
                             const float* __restrict__ Wr, const float* __restrict__ br,
                             const float* __restrict__ h0_in, const float* __restrict__ h1_in,
                             const float* __restrict__ h2_in,
                             const float* __restrict__ ga0,
                             const int* __restrict__ off_col, const int* __restrict__ eid_col,
                             float* __restrict__ g0, float* __restrict__ g1, float* __restrict__ g2,
                             float* __restrict__ dv_buf, int N)
{
  int n = blockIdx.x * (blockDim.x >> 4) + (threadIdx.x >> 4);
  int c = threadIdx.x & 15;
  if (n >= N) return;
  float wr0[8], wr3[8], wr4[8];
  #pragma unroll
  for (int k = 0; k < 8; k++) {
    wr0[k] = Wr[k*80 + c];
    wr3[k] = Wr[k*80 + 48 + c];
    wr4[k] = Wr[k*80 + 64 + c];
  }
  float b0v = br[c], b3v = br[48 + c], b4v = br[64 + c];
  float nx = pos[n*3+0], ny = pos[n*3+1], nz = pos[n*3+2];

  float h0c = h0_in[n*16 + c];
  float h1c[3], h2c[5];
  #pragma unroll
  for (int m = 0; m < 3; m++) h1c[m] = h1_in[n*48 + c*3 + m];
  #pragma unroll
  for (int m = 0; m < 5; m++) h2c[m] = h2_in[n*80 + c*5 + m];

  float accg0 = 0.f, accg1[3] = {0.f,0.f,0.f}, accg2[5] = {0.f,0.f,0.f,0.f,0.f};

  int i0 = off_col[n], i1 = off_col[n+1];
  int e_n = 0; float pxn=0.f, pyn=0.f, pzn=0.f, dm0n=0.f;
  if (i0 < i1) {
    e_n = eid_col[i0]; int row = ei[e_n];
    pxn = pos[row*3+0] - nx; pyn = pos[row*3+1] - ny; pzn = pos[row*3+2] - nz;
    dm0n = ga0[row*16 + c];
  }
  for (int i = i0; i < i1; i++) {
    int e = e_n;
    float px = pxn, py = pyn, pz = pzn, dm0 = dm0n;
    if (i+1 < i1) {
      e_n = eid_col[i+1]; int row = ei[e_n];
      pxn = pos[row*3+0] - nx; pyn = pos[row*3+1] - ny; pzn = pos[row*3+2] - nz;
      dm0n = ga0[row*16 + c];
    }
    float r, inv_r, ux, uy, uz, rad[8], ck[8], sh1[3], sh2[5], draddr[8];
    geom_core(px, py, pz, r, inv_r, ux, uy, uz, rad, ck, sh1, sh2);
    geom_drad(inv_r, rad, ck, draddr);

    float w0 = b0v, w3 = b3v, w4 = b4v;
    #pragma unroll
    for (int k = 0; k < 8; k++) {
      w0 += rad[k]*wr0[k]; w3 += rad[k]*wr3[k]; w4 += rad[k]*wr4[k];
    }

    float S1 = 0.f, S2 = 0.f;
    #pragma unroll
    for (int m = 0; m < 3; m++) S1 += h1c[m]*sh1[m];
    #pragma unroll
    for (int m = 0; m < 5; m++) S2 += h2c[m]*sh2[m];

    float dw0 = dm0 * h0c;
    float dw3 = dm0 * S1;
    float dw4 = dm0 * S2;
    float t3 = dm0 * w3, t4 = dm0 * w4;

    accg0 += dm0 * w0;
    #pragma unroll
    for (int m = 0; m < 3; m++) accg1[m] += t3 * sh1[m];
    #pragma unroll
    for (int m = 0; m < 5; m++) accg2[m] += t4 * sh2[m];

    // per-lane partial gsh -> per-lane partial (gr, gu)
    float q1x = t3*h1c[0], q1y = t3*h1c[1], q1z = t3*h1c[2];
    float q0 = t4*h2c[0], q1 = t4*h2c[1], q2 = t4*h2c[2], q3 = t4*h2c[3], q4 = t4*h2c[4];
    float gr = 0.f;
    #pragma unroll
    for (int k = 0; k < 8; k++)
      gr += (dw0*wr0[k] + dw3*wr3[k] + dw4*wr4[k]) * draddr[k];
    float gux = SQRT3f*q1x + SQRT15f*(uy*q0 + uz*q3 + ux*q4);
    float guy = SQRT3f*q1y + SQRT15f*(ux*q0 + uz*q1 - uy*q4);
    float guz = SQRT3f*q1z + SQRT15f*uy*q1 + 3.f*SQRT5f*uz*q2 + SQRT15f*ux*q3;

    gr  = grp16_sum(gr);
    gux = grp16_sum(gux);
    guy = grp16_sum(guy);
    guz = grp16_sum(guz);

    if (c == 0) {
      float gdotu = gux*ux + guy*uy + guz*uz;
      dv_buf[e*3+0] = gr*ux + (gux - gdotu*ux)*inv_r;
      dv_buf[e*3+1] = gr*uy + (guy - gdotu*uy)*inv_r;
      dv_buf[e*3+2] = gr*uz + (guz - gdotu*uz)*inv_r;
    }
  }
  g0[n*16 + c] += accg0;       // residual identity path adds to readout grad
  #pragma unroll
  for (int m = 0; m < 3; m++) g1[n*48 + c*3 + m] = accg1[m];
  #pragma unroll
  for (int m = 0; m < 5; m++) g2[n*80 + c*5 + m] = accg2[m];
}

// ---------------------------------------------------------------------------
// Backward block 0, ROW-centric: ga0/ga1/ga2[n] loaded once per node into
// registers; loop over row-incident edges gathering h0[col]; dv_buf[e] += dv.
// ---------------------------------------------------------------------------
__global__ void k_bwd_b0_row(const float* __restrict__ pos, const int* __restrict__ ei, int E,
                             const float* __restrict__ Wr, const float* __restrict__ br,
                             const float* __restrict__ h0_in,
                             const float* __restrict__ ga0, const float* __restrict__ ga1,
                             const float* __restrict__ ga2,
                             const int* __restrict__ off_row, const int* __restrict__ eid_row,
                             float* __restrict__ dv_buf, int N)
{
  int n = blockIdx.x * (blockDim.x >> 4) + (threadIdx.x >> 4);
  int c = threadIdx.x & 15;
  if (n >= N) return;
  float wr0[8], wr1[8], wr2[8];
  #pragma unroll
  for (int k = 0; k < 8; k++) {
    wr0[k] = Wr[k*80 + c];
    wr1[k] = Wr[k*80 + 16 + c];
    wr2[k] = Wr[k*80 + 32 + c];
  }
  float b1v = br[16 + c], b2v = br[32 + c];
  float nx = pos[n*3+0], ny = pos[n*3+1], nz = pos[n*3+2];

  float dm0 = ga0[n*16 + c];
  float dm1[3], dm2[5];
  #pragma unroll
  for (int m = 0; m < 3; m++) dm1[m] = ga1[n*48 + c*3 + m];
  #pragma unroll
  for (int m = 0; m < 5; m++) dm2[m] = ga2[n*80 + c*5 + m];

  int i0 = off_row[n], i1 = off_row[n+1];
  int e_n = 0; float pxn=0.f, pyn=0.f, pzn=0.f, h0n=0.f;
  if (i0 < i1) {
    e_n = eid_row[i0]; int col = ei[E + e_n];
    pxn = nx - pos[col*3+0]; pyn = ny - pos[col*3+1]; pzn = nz - pos[col*3+2];
    h0n = h0_in[col*16 + c];
  }
  for (int i = i0; i < i1; i++) {
    int e = e_n;
    float px = pxn, py = pyn, pz = pzn, h0c = h0n;
    if (i+1 < i1) {
      e_n = eid_row[i+1]; int col = ei[E + e_n];
      pxn = nx - pos[col*3+0]; pyn = ny - pos[col*3+1]; pzn = nz - pos[col*3+2];
      h0n = h0_in[col*16 + c];
    }
    float r, inv_r, ux, uy, uz, rad[8], ck[8], sh1[3], sh2[5], draddr[8];
    geom_core(px, py, pz, r, inv_r, ux, uy, uz, rad, ck, sh1, sh2);
    geom_drad(inv_r, rad, ck, draddr);

    float w1 = b1v, w2v = b2v;
    #pragma unroll
    for (int k = 0; k < 8; k++) { w1 += rad[k]*wr1[k]; w2v += rad[k]*wr2[k]; }

    float T1 = 0.f, T2 = 0.f;
    #pragma unroll
    for (int m = 0; m < 3; m++) T1 += dm1[m]*sh1[m];
    #pragma unroll
    for (int m = 0; m < 5; m++) T2 += dm2[m]*sh2[m];

    float dw0 = dm0 * h0c;
    float dw1 = h0c * T1;
    float dw2 = h0c * T2;

    float w1h = w1*h0c, w2h = w2v*h0c;
    float q1x = dm1[0]*w1h, q1y = dm1[1]*w1h, q1z = dm1[2]*w1h;
    float q0 = dm2[0]*w2h, q1 = dm2[1]*w2h, q2 = dm2[2]*w2h, q3 = dm2[3]*w2h, q4 = dm2[4]*w2h;

    float gr = 0.f;
    #pragma unroll
    for (int k = 0; k < 8; k++)
      gr += (dw0*wr0[k] + dw1*wr1[k] + dw2*wr2[k]) * draddr[k];
    float gux = SQRT3f*q1x + SQRT15f*(uy*q0 + uz*q3 + ux*q4);
    float guy = SQRT3f*q1y + SQRT15f*(ux*q0 + uz*q1 - uy*q4);
    float guz = SQRT3f*q1z + SQRT15f*uy*q1 + 3.f*SQRT5f*uz*q2 + SQRT15f*ux*q3;

    gr  = grp16_sum(gr);
    gux = grp16_sum(gux);
    guy = grp16_sum(guy);
    guz = grp16_sum(guz);

    if (c == 0) {
      float gdotu = gux*ux + guy*uy + guz*uz;
      dv_buf[e*3+0] += gr*ux + (gux - gdotu*ux)*inv_r;
      dv_buf[e*3+1] += gr*uy + (guy - gdotu*uy)*inv_r;
      dv_buf[e*3+2] += gr*uz + (guz - gdotu*uz)*inv_r;
    }
  }
}

// ---------------------------------------------------------------------------
// Force assembly: force[n] = sum_{col==n} dv - sum_{row==n} dv
// ---------------------------------------------------------------------------
__global__ void k_force(const int* __restrict__ off_row, const int* __restrict__ eid_row,
                        const int* __restrict__ off_col, const int* __restrict__ eid_col,
                        const float* __restrict__ dv, float* __restrict__ force, int N)
{
  int n = blockIdx.x * blockDim.x + threadIdx.x;
  if (n >= N) return;
  float fx = 0.f, fy = 0.f, fz = 0.f;
  for (int i = off_col[n]; i < off_col[n+1]; i++) {
    int e = eid_col[i];
    fx += dv[e*3+0]; fy += dv[e*3+1]; fz += dv[e*3+2];
  }
  for (int i = off_row[n]; i < off_row[n+1]; i++) {
    int e = eid_row[i];
    fx -= dv[e*3+0]; fy -= dv[e*3+1]; fz -= dv[e*3+2];
  }
  force[n*3+0] = fx; force[n*3+1] = fy; force[n*3+2] = fz;
}

// ---------------------------------------------------------------------------
extern "C" void kernel_launch(void* const* d_in, const int* in_sizes, int n_in,
                              void* d_out, int out_size, void* d_ws, size_t ws_size,
                              hipStream_t stream)
{
  const float* pos    = (const float*)d_in[0];
  const int*   z      = (const int*)  d_in[1];
  const int*   ei     = (const int*)  d_in[2];
  const float* emb    = (const float*)d_in[3];
  const float* W_init = (const float*)d_in[4];
  const float* Wr     = (const float*)d_in[5];   // (2, 8, 80)
  const float* br     = (const float*)d_in[6];   // (2, 80)
  const float* W_out  = (const float*)d_in[7];   // (2, 3, 16, 16)
  const float* W_read = (const float*)d_in[8];
  const float* W1     = (const float*)d_in[9];
  const float* b1     = (const float*)d_in[10];
  const float* W2     = (const float*)d_in[11];
  const float* b2     = (const float*)d_in[12];

  const int N = in_sizes[0] / 3;
  const int E = in_sizes[2] / 2;

  float* f = (float*)d_ws;
  float* h0_s0 = f; f += (size_t)N*16;
  float* h0_s1 = f; f += (size_t)N*16;
  float* h0_s2 = f; f += (size_t)N*16;
  float* h1_s1 = f; f += (size_t)N*48;
  float* h2_s1 = f; f += (size_t)N*80;
  float* a0    = f; f += (size_t)N*16;   // also ga0
  float* a1    = f; f += (size_t)N*48;   // also ga1
  float* a2    = f; f += (size_t)N*80;   // also ga2
  float* g0    = f; f += (size_t)N*16;
  float* g1    = f; f += (size_t)N*48;
  float* g2    = f; f += (size_t)N*80;
  float* dv    = f; f += (size_t)E*3;
  int* ip = (int*)f;
  int* deg_row = ip; ip += N;            // deg_row+deg_col contiguous -> one memset
  int* deg_col = ip; ip += N;
  int* off_row = ip; ip += N+1;
  int* off_col = ip; ip += N+1;
  int* cur_row = ip; ip += N;
  int* cur_col = ip; ip += N;
  int* eid_row = ip; ip += E;
  int* eid_col = ip; ip += E;

  float* out    = (float*)d_out;
  float* energy = out;
  float* force  = out + 1;

  const int BLK = 256;
  const int GPB = BLK / 16;  // 16-lane groups per block

  (void)hipMemsetAsync(energy, 0, sizeof(float), stream);
  (void)hipMemsetAsync(deg_row, 0, (size_t)2 * N * sizeof(int), stream);

  // ---- CSR build ----
  k_hist<<<cdiv(E, BLK), BLK, 0, stream>>>(ei, E, deg_row, deg_col);
  k_scan<<<1, 64, 0, stream>>>(deg_row, deg_col, off_row, off_col, cur_row, cur_col, N);
  k_scatter<<<cdiv(E, BLK), BLK, 0, stream>>>(ei, E, cur_row, cur_col, eid_row, eid_col);

  k_node_init<<<cdiv(N, BLK), BLK, 0, stream>>>(emb, z, W_init, h0_s0, N);

  // ---- forward block 0 ----
  k_fwd_b0<<<cdiv(N, GPB), BLK, 0, stream>>>(pos, ei, E, Wr, br, h0_s0,
                                             off_row, eid_row, a0, a1, a2, N);
  k_node_update<<<cdiv(N*16, BLK), BLK, 0, stream>>>(h0_s0, a0, a1, a2,
                                                     W_out, h0_s1, h1_s1, h2_s1, N, 1);

  // ---- forward block 1 (only h0 path live) ----
  k_fwd_b1<<<cdiv(N, GPB), BLK, 0, stream>>>(pos, ei, E, Wr + 640, br + 80,
                                             h0_s1, h1_s1, h2_s1,
                                             off_row, eid_row, a0, N);
  k_node_update<<<cdiv(N*16, BLK), BLK, 0, stream>>>(h0_s1, a0, nullptr, nullptr,
                                                     W_out + 768, h0_s2, nullptr, nullptr, N, 0);

  // ---- readout fwd + bwd ----
  k_readout_bwd<<<cdiv(N, BLK), BLK, 0, stream>>>(h0_s2, W_read, W1, b1, W2, b2, g0, energy, N);

  // ---- backward block 1 ----
  k_ga<<<cdiv(N*16, BLK), BLK, 0, stream>>>(g0, nullptr, nullptr, W_out + 768,
                                            a0, nullptr, nullptr, N, 0);
  k_bwd_b1_col<<<cdiv(N, GPB), BLK, 0, stream>>>(pos, ei, E, Wr + 640, br + 80,
                                                 h0_s1, h1_s1, h2_s1, a0,
                                                 off_col, eid_col, g0, g1, g2, dv, N);

  // ---- backward block 0 ----
  k_ga<<<cdiv(N*16, BLK), BLK, 0, stream>>>(g0, g1, g2, W_out, a0, a1, a2, N, 1);
  k_bwd_b0_row<<<cdiv(N, GPB), BLK, 0, stream>>>(pos, ei, E, Wr, br, h0_s0,
                                                 a0, a1, a2, off_row, eid_row, dv, N);

  // ---- force assembly ----
  k_force<<<cdiv(N, BLK), BLK, 0, stream>>>(off_row, eid_row, off_col, eid_col, dv, force, N);
}

// Round 5
// 751.084 us; speedup vs baseline: 3.1383x; 1.1961x over previous
//
#include <hip/hip_runtime.h>
#include <math.h>

#ifndef M_PI
#define M_PI 3.14159265358979323846
#endif

static inline int cdiv(int a, int b){ return (a + b - 1) / b; }

#define SQRT3f  1.7320508075688772f
#define SQRT5f  2.23606797749979f
#define SQRT15f 3.872983346207417f
#define KRADf   0.6324555320336759f      /* sqrt(2/R_MAX), R_MAX=5 */
#define PI5f    0.6283185307179586f      /* pi/5 */

// ---------------------------------------------------------------------------
// Geometry via Chebyshev recurrence: one sincosf for all 8 radial terms.
// ck may be nullptr (forward: no cos needed).
// ---------------------------------------------------------------------------
__device__ __forceinline__ void geom_core(float px, float py, float pz,
    float& r, float& inv_r, float& ux, float& uy, float& uz,
    float* rad, float* ck, float* sh1, float* sh2)
{
  float r2 = px*px + py*py + pz*pz + 1e-12f;
  r = sqrtf(r2);
  inv_r = 1.0f / r;
  ux = px*inv_r; uy = py*inv_r; uz = pz*inv_r;
  float x = r * PI5f;
  float s1, c1;
  sincosf(x, &s1, &c1);
  float tc = 2.f * c1;
  float sprev = 0.f, s = s1, cprev = 1.f, cc = c1;
  float Ki = KRADf * inv_r;
  #pragma unroll
  for (int k = 0; k < 8; k++) {
    rad[k] = Ki * s;
    if (ck) ck[k] = cc;
    float sn = tc*s - sprev; sprev = s; s = sn;
    float cn = tc*cc - cprev; cprev = cc; cc = cn;
  }
  sh1[0] = SQRT3f*ux; sh1[1] = SQRT3f*uy; sh1[2] = SQRT3f*uz;
  sh2[0] = SQRT15f*ux*uy;
  sh2[1] = SQRT15f*uy*uz;
  sh2[2] = 0.5f*SQRT5f*(3.f*uz*uz - 1.f);
  sh2[3] = SQRT15f*ux*uz;
  sh2[4] = 0.5f*SQRT15f*(ux*ux - uy*uy);
}

// draddr[k] = (K*c_k*cos(c_k r) - rad[k]) / r,  c_k = (k+1)*pi/5
__device__ __forceinline__ void geom_drad(float inv_r, const float* rad, const float* ck,
                                          float* draddr)
{
  const float KPI5 = KRADf * PI5f;
  #pragma unroll
  for (int k = 0; k < 8; k++)
    draddr[k] = (KPI5 * (float)(k+1) * ck[k] - rad[k]) * inv_r;
}

__device__ __forceinline__ float grp16_sum(float v){
  v += __shfl_xor(v, 1, 64);
  v += __shfl_xor(v, 2, 64);
  v += __shfl_xor(v, 4, 64);
  v += __shfl_xor(v, 8, 64);
  return v;
}

// ---------------------------------------------------------------------------
// CSR build: histogram, scan (1 block, 1024 threads), scatter
// ---------------------------------------------------------------------------
__global__ void k_hist(const int* __restrict__ ei, int E,
                       int* __restrict__ deg_row, int* __restrict__ deg_col)
{
  int e = blockIdx.x * blockDim.x + threadIdx.x;
  if (e >= E) return;
  atomicAdd(&deg_row[ei[e]], 1);
  atomicAdd(&deg_col[ei[E + e]], 1);
}

#define SCAN_T 1024
__global__ void k_scan(const int* __restrict__ degA, const int* __restrict__ degB,
                       int* __restrict__ offA, int* __restrict__ offB,
                       int* __restrict__ curA, int* __restrict__ curB, int N)
{
  __shared__ int lds[SCAN_T];
  int t = threadIdx.x;
  int chunk = (N + SCAN_T - 1) / SCAN_T;
  for (int which = 0; which < 2; which++) {
    const int* deg = which ? degB : degA;
    int* off = which ? offB : offA;
    int* cur = which ? curB : curA;
    int lo = t * chunk; if (lo > N) lo = N;
    int hi = lo + chunk; if (hi > N) hi = N;
    int s = 0;
    for (int i = lo; i < hi; i++) s += deg[i];
    lds[t] = s;
    __syncthreads();
    // Hillis-Steele inclusive scan over the 1024 chunk sums
    #pragma unroll
    for (int d = 1; d < SCAN_T; d <<= 1) {
      int y = (t >= d) ? lds[t - d] : 0;
      __syncthreads();
      lds[t] += y;
      __syncthreads();
    }
    int running = lds[t] - s;   // exclusive prefix of this thread's chunk
    for (int i = lo; i < hi; i++) {
      off[i] = running; cur[i] = running;
      running += deg[i];
    }
    if (t == SCAN_T - 1) off[N] = lds[SCAN_T - 1];
    __syncthreads();
  }
}

__global__ void k_scatter(const int* __restrict__ ei, int E,
                          int* __restrict__ cur_row, int* __restrict__ cur_col,
                          int* __restrict__ eid_row, int* __restrict__ eid_col)
{
  int e = blockIdx.x * blockDim.x + threadIdx.x;
  if (e >= E) return;
  int pr = atomicAdd(&cur_row[ei[e]], 1);
  eid_row[pr] = e;
  int pc = atomicAdd(&cur_col[ei[E + e]], 1);
  eid_col[pc] = e;
}

// ---------------------------------------------------------------------------
// h0_init[n,:] = emb[z[n],:] @ W_init
// ---------------------------------------------------------------------------
__global__ void k_node_init(const float* __restrict__ emb, const int* __restrict__ z,
                            const float* __restrict__ W_init, float* __restrict__ h0, int N)
{
  __shared__ float sW[256];
  if (threadIdx.x < 256) sW[threadIdx.x] = W_init[threadIdx.x];
  __syncthreads();
  int n = blockIdx.x * blockDim.x + threadIdx.x;
  if (n >= N) return;
  const float* e = emb + z[n]*16;
  float ev[16];
  #pragma unroll
  for (int k = 0; k < 16; k++) ev[k] = e[k];
  #pragma unroll
  for (int c = 0; c < 16; c++) {
    float s = 0.f;
    #pragma unroll
    for (int k = 0; k < 16; k++) s += ev[k] * sW[k*16+c];
    h0[n*16+c] = s;
  }
}

// ---------------------------------------------------------------------------
// Forward block 0, row-centric gather. 16 lanes per node (one per channel).
// ---------------------------------------------------------------------------
__global__ void k_fwd_b0(const float* __restrict__ pos, const int* __restrict__ ei, int E,
                         const float* __restrict__ Wr, const float* __restrict__ br,
                         const float* __restrict__ h0_in,
                         const int* __restrict__ off_row, const int* __restrict__ eid_row,
                         float* __restrict__ a0, float* __restrict__ a1, float* __restrict__ a2,
                         int N)
{
  int n = blockIdx.x * (blockDim.x >> 4) + (threadIdx.x >> 4);
  int c = threadIdx.x & 15;
  if (n >= N) return;
  float wr0[8], wr1[8], wr2[8];
  #pragma unroll
  for (int k = 0; k < 8; k++) {
    wr0[k] = Wr[k*80 + c];
    wr1[k] = Wr[k*80 + 16 + c];
    wr2[k] = Wr[k*80 + 32 + c];
  }
  float b0v = br[c], b1v = br[16 + c], b2v = br[32 + c];
  float rx = pos[n*3+0], ry = pos[n*3+1], rz = pos[n*3+2];

  float acc0 = 0.f, acc1[3] = {0.f,0.f,0.f}, acc2[5] = {0.f,0.f,0.f,0.f,0.f};

  int i0 = off_row[n], i1 = off_row[n+1];
  float pxn=0.f, pyn=0.f, pzn=0.f, h0n=0.f;
  if (i0 < i1) {
    int e = eid_row[i0]; int col = ei[E + e];
    pxn = rx - pos[col*3+0]; pyn = ry - pos[col*3+1]; pzn = rz - pos[col*3+2];
    h0n = h0_in[col*16 + c];
  }
  for (int i = i0; i < i1; i++) {
    float px = pxn, py = pyn, pz = pzn, h0c = h0n;
    if (i+1 < i1) {
      int e = eid_row[i+1]; int col = ei[E + e];
      pxn = rx - pos[col*3+0]; pyn = ry - pos[col*3+1]; pzn = rz - pos[col*3+2];
      h0n = h0_in[col*16 + c];
    }
    float r, inv_r, ux, uy, uz, rad[8], sh1[3], sh2[5];
    geom_core(px, py, pz, r, inv_r, ux, uy, uz, rad, nullptr, sh1, sh2);
    float w0 = b0v, w1 = b1v, w2 = b2v;
    #pragma unroll
    for (int k = 0; k < 8; k++) {
      w0 += rad[k]*wr0[k]; w1 += rad[k]*wr1[k]; w2 += rad[k]*wr2[k];
    }
    acc0 += w0*h0c;
    float wh1 = w1*h0c, wh2 = w2*h0c;
    #pragma unroll
    for (int m = 0; m < 3; m++) acc1[m] += wh1*sh1[m];
    #pragma unroll
    for (int m = 0; m < 5; m++) acc2[m] += wh2*sh2[m];
  }
  a0[n*16 + c] = acc0;
  #pragma unroll
  for (int m = 0; m < 3; m++) a1[n*48 + c*3 + m] = acc1[m];
  #pragma unroll
  for (int m = 0; m < 5; m++) a2[n*80 + c*5 + m] = acc2[m];
}

// ---------------------------------------------------------------------------
// Forward block 1 (last): a0 += w0*h0c + w3*S1 + w4*S2
// ---------------------------------------------------------------------------
__global__ void k_fwd_b1(const float* __restrict__ pos, const int* __restrict__ ei, int E,
                         const float* __restrict__ Wr, const float* __restrict__ br,
                         const float* __restrict__ h0_in, const float* __restrict__ h1_in,
                         const float* __restrict__ h2_in,
                         const int* __restrict__ off_row, const int* __restrict__ eid_row,
                         float* __restrict__ a0, int N)
{
  int n = blockIdx.x * (blockDim.x >> 4) + (threadIdx.x >> 4);
  int c = threadIdx.x & 15;
  if (n >= N) return;
  float wr0[8], wr3[8], wr4[8];
  #pragma unroll
  for (int k = 0; k < 8; k++) {
    wr0[k] = Wr[k*80 + c];
    wr3[k] = Wr[k*80 + 48 + c];
    wr4[k] = Wr[k*80 + 64 + c];
  }
  float b0v = br[c], b3v = br[48 + c], b4v = br[64 + c];
  float rx = pos[n*3+0], ry = pos[n*3+1], rz = pos[n*3+2];

  float acc0 = 0.f;
  int i0 = off_row[n], i1 = off_row[n+1];
  float pxn=0.f, pyn=0.f, pzn=0.f, h0n=0.f, h1n[3]={0,0,0}, h2n[5]={0,0,0,0,0};
  if (i0 < i1) {
    int e = eid_row[i0]; int col = ei[E + e];
    pxn = rx - pos[col*3+0]; pyn = ry - pos[col*3+1]; pzn = rz - pos[col*3+2];
    h0n = h0_in[col*16 + c];
    #pragma unroll
    for (int m = 0; m < 3; m++) h1n[m] = h1_in[col*48 + c*3 + m];
    #pragma unroll
    for (int m = 0; m < 5; m++) h2n[m] = h2_in[col*80 + c*5 + m];
  }
  for (int i = i0; i < i1; i++) {
    float px = pxn, py = pyn, pz = pzn, h0c = h0n;
    float h1c[3], h2c[5];
    #pragma unroll
    for (int m = 0; m < 3; m++) h1c[m] = h1n[m];
    #pragma unroll
    for (int m = 0; m < 5; m++) h2c[m] = h2n[m];
    if (i+1 < i1) {
      int e = eid_row[i+1]; int col = ei[E + e];
      pxn = rx - pos[col*3+0]; pyn = ry - pos[col*3+1]; pzn = rz - pos[col*3+2];
      h0n = h0_in[col*16 + c];
      #pragma unroll
      for (int m = 0; m < 3; m++) h1n[m] = h1_in[col*48 + c*3 + m];
      #pragma unroll
      for (int m = 0; m < 5; m++) h2n[m] = h2_in[col*80 + c*5 + m];
    }
    float r, inv_r, ux, uy, uz, rad[8], sh1[3], sh2[5];
    geom_core(px, py, pz, r, inv_r, ux, uy, uz, rad, nullptr, sh1, sh2);
    float w0 = b0v, w3 = b3v, w4 = b4v;
    #pragma unroll
    for (int k = 0; k < 8; k++) {
      w0 += rad[k]*wr0[k]; w3 += rad[k]*wr3[k]; w4 += rad[k]*wr4[k];
    }
    float S1 = 0.f, S2 = 0.f;
    #pragma unroll
    for (int m = 0; m < 3; m++) S1 += h1c[m]*sh1[m];
    #pragma unroll
    for (int m = 0; m < 5; m++) S2 += h2c[m]*sh2[m];
    acc0 += w0*h0c + w3*S1 + w4*S2;
  }
  a0[n*16 + c] = acc0;
}

// ---------------------------------------------------------------------------
// Node update: h_out = h_in + a @ U
// ---------------------------------------------------------------------------
__global__ void k_node_update(const float* __restrict__ h0_in,
                              const float* __restrict__ a0, const float* __restrict__ a1,
                              const float* __restrict__ a2,
                              const float* __restrict__ U,
                              float* __restrict__ h0_out, float* __restrict__ h1_out,
                              float* __restrict__ h2_out, int N, int full)
{
  int idx = blockIdx.x * blockDim.x + threadIdx.x;
  int n = idx >> 4, d = idx & 15;
  if (n >= N) return;
  const float* U0 = U;
  const float* U1 = U + 256;
  const float* U2 = U + 512;
  float s = h0_in[n*16 + d];
  #pragma unroll
  for (int c = 0; c < 16; c++) s += a0[n*16 + c] * U0[c*16 + d];
  h0_out[n*16 + d] = s;
  if (full) {
    float v1[3] = {0.f, 0.f, 0.f};
    #pragma unroll
    for (int c = 0; c < 16; c++) {
      float u = U1[c*16 + d];
      #pragma unroll
      for (int m = 0; m < 3; m++) v1[m] += a1[n*48 + c*3 + m] * u;
    }
    #pragma unroll
    for (int m = 0; m < 3; m++) h1_out[n*48 + d*3 + m] = v1[m];
    float v2[5] = {0.f, 0.f, 0.f, 0.f, 0.f};
    #pragma unroll
    for (int c = 0; c < 16; c++) {
      float u = U2[c*16 + d];
      #pragma unroll
      for (int m = 0; m < 5; m++) v2[m] += a2[n*80 + c*5 + m] * u;
    }
    #pragma unroll
    for (int m = 0; m < 5; m++) h2_out[n*80 + d*5 + m] = v2[m];
  }
}

// ---------------------------------------------------------------------------
// Readout fwd + bwd fused
// ---------------------------------------------------------------------------
__global__ void k_readout_bwd(const float* __restrict__ h0, const float* __restrict__ W_read,
                              const float* __restrict__ W1, const float* __restrict__ b1,
                              const float* __restrict__ W2, const float* __restrict__ b2,
                              float* __restrict__ g0, float* __restrict__ energy, int N)
{
  int n = blockIdx.x * blockDim.x + threadIdx.x;
  float site = 0.f;
  if (n < N) {
    float h[16], inv[16], dt[16];
    #pragma unroll
    for (int d = 0; d < 16; d++) h[d] = h0[n*16 + d];
    #pragma unroll
    for (int j = 0; j < 16; j++) {
      float s = 0.f;
      #pragma unroll
      for (int d = 0; d < 16; d++) s += h[d] * W_read[d*16 + j];
      inv[j] = s;
    }
    site = b2[0];
    #pragma unroll
    for (int c = 0; c < 16; c++) {
      float t = b1[c];
      #pragma unroll
      for (int j = 0; j < 16; j++) t += inv[j] * W1[j*16 + c];
      float sg = 1.f / (1.f + expf(-t));
      float w2v = W2[c];
      site += t * sg * w2v;
      dt[c] = w2v * sg * (1.f + t * (1.f - sg));
    }
    float dinv[16];
    #pragma unroll
    for (int j = 0; j < 16; j++) {
      float s = 0.f;
      #pragma unroll
      for (int c = 0; c < 16; c++) s += dt[c] * W1[j*16 + c];
      dinv[j] = s;
    }
    #pragma unroll
    for (int d = 0; d < 16; d++) {
      float s = 0.f;
      #pragma unroll
      for (int j = 0; j < 16; j++) s += dinv[j] * W_read[d*16 + j];
      g0[n*16 + d] = s;
    }
  }
  #pragma unroll
  for (int off = 32; off; off >>= 1) site += __shfl_down(site, off, 64);
  if ((threadIdx.x & 63) == 0) atomicAdd(energy, site);
}

// ---------------------------------------------------------------------------
// ga = g @ U^T
// ---------------------------------------------------------------------------
__global__ void k_ga(const float* __restrict__ g0, const float* __restrict__ g1,
                     const float* __restrict__ g2, const float* __restrict__ U,
                     float* __restrict__ ga0, float* __restrict__ ga1, float* __restrict__ ga2,
                     int N, int full)
{
  int idx = blockIdx.x * blockDim.x + threadIdx.x;
  int n = idx >> 4, c = idx & 15;
  if (n >= N) return;
  const float* U0 = U;
  const float* U1 = U + 256;
  const float* U2 = U + 512;
  float s = 0.f;
  #pragma unroll
  for (int d = 0; d < 16; d++) s += g0[n*16 + d] * U0[c*16 + d];
  ga0[n*16 + c] = s;
  if (full) {
    float v1[3] = {0.f, 0.f, 0.f};
    #pragma unroll
    for (int d = 0; d < 16; d++) {
      float u = U1[c*16 + d];
      #pragma unroll
      for (int m = 0; m < 3; m++) v1[m] += g1[n*48 + d*3 + m] * u;
    }
    #pragma unroll
    for (int m = 0; m < 3; m++) ga1[n*48 + c*3 + m] = v1[m];
    float v2[5] = {0.f, 0.f, 0.f, 0.f, 0.f};
    #pragma unroll
    for (int d = 0; d < 16; d++) {
      float u = U2[c*16 + d];
      #pragma unroll
      for (int m = 0; m < 5; m++) v2[m] += g2[n*80 + d*5 + m] * u;
    }
    #pragma unroll
    for (int m = 0; m < 5; m++) ga2[n*80 + c*5 + m] = v2[m];
  }
}

// ---------------------------------------------------------------------------
// Backward block 1, col-centric.
// ---------------------------------------------------------------------------
__global__ void k_bwd_b1_col(const float* __restrict__ pos, const int* __restrict__ ei, int E,
                             const float* __restrict__ Wr, const float* __restrict__ br,
                             const float* __restrict__ h0_in, const float* __restrict__ h1_in,
                             const float* __restrict__ h2_in,
                             const float* __restrict__ ga0,
                             const int* __restrict__ off_col, const int* __restrict__ eid_col,
                             float* __restrict__ g0, float* __restrict__ g1, float* __restrict__ g2,
                             float* __restrict__ dv_buf, int N)
{
  int n = blockIdx.x * (blockDim.x >> 4) + (threadIdx.x >> 4);
  int c = threadIdx.x & 15;
  if (n >= N) return;
  float wr0[8], wr3[8], wr4[8];
  #pragma unroll
  for (int k = 0; k < 8; k++) {
    wr0[k] = Wr[k*80 + c];
    wr3[k] = Wr[k*80 + 48 + c];
    wr4[k] = Wr[k*80 + 64 + c];
  }
  float b0v = br[c], b3v = br[48 + c], b4v = br[64 + c];
  float nx = pos[n*3+0], ny = pos[n*3+1], nz = pos[n*3+2];

  float h0c = h0_in[n*16 + c];
  float h1c[3], h2c[5];
  #pragma unroll
  for (int m = 0; m < 3; m++) h1c[m] = h1_in[n*48 + c*3 + m];
  #pragma unroll
  for (int m = 0; m < 5; m++) h2c[m] = h2_in[n*80 + c*5 + m];

  float accg0 = 0.f, accg1[3] = {0.f,0.f,0.f}, accg2[5] = {0.f,0.f,0.f,0.f,0.f};

  int i0 = off_col[n], i1 = off_col[n+1];
  int e_n = 0; float pxn=0.f, pyn=0.f, pzn=0.f, dm0n=0.f;
  if (i0 < i1) {
    e_n = eid_col[i0]; int row = ei[e_n];
    pxn = pos[row*3+0] - nx; pyn = pos[row*3+1] - ny; pzn = pos[row*3+2] - nz;
    dm0n = ga0[row*16 + c];
  }
  for (int i = i0; i < i1; i++) {
    int e = e_n;
    float px = pxn, py = pyn, pz = pzn, dm0 = dm0n;
    if (i+1 < i1) {
      e_n = eid_col[i+1]; int row = ei[e_n];
      pxn = pos[row*3+0] - nx; pyn = pos[row*3+1] - ny; pzn = pos[row*3+2] - nz;
      dm0n = ga0[row*16 + c];
    }
    float r, inv_r, ux, uy, uz, rad[8], ck[8], sh1[3], sh2[5], draddr[8];
    geom_core(px, py, pz, r, inv_r, ux, uy, uz, rad, ck, sh1, sh2);
    geom_drad(inv_r, rad, ck, draddr);

    float w0 = b0v, w3 = b3v, w4 = b4v;
    #pragma unroll
    for (int k = 0; k < 8; k++) {
      w0 += rad[k]*wr0[k]; w3 += rad[k]*wr3[k]; w4 += rad[k]*wr4[k];
    }

    float S1 = 0.f, S2 = 0.f;
    #pragma unroll
    for (int m = 0; m < 3; m++) S1 += h1c[m]*sh1[m];
    #pragma unroll
    for (int m = 0; m < 5; m++) S2 += h2c[m]*sh2[m];

    float dw0 = dm0 * h0c;
    float dw3 = dm0 * S1;
    float dw4 = dm0 * S2;
    float t3 = dm0 * w3, t4 = dm0 * w4;

    accg0 += dm0 * w0;
    #pragma unroll
    for (int m = 0; m < 3; m++) accg1[m] += t3 * sh1[m];
    #pragma unroll
    for (int m = 0; m < 5; m++) accg2[m] += t4 * sh2[m];

    float q1x = t3*h1c[0], q1y = t3*h1c[1], q1z = t3*h1c[2];
    float q0 = t4*h2c[0], q1 = t4*h2c[1], q2 = t4*h2c[2], q3 = t4*h2c[3], q4 = t4*h2c[4];
    float gr = 0.f;
    #pragma unroll
    for (int k = 0; k < 8; k++)
      gr += (dw0*wr0[k] + dw3*wr3[k] + dw4*wr4[k]) * draddr[k];
    float gux = SQRT3f*q1x + SQRT15f*(uy*q0 + uz*q3 + ux*q4);
    float guy = SQRT3f*q1y + SQRT15f*(ux*q0 + uz*q1 - uy*q4);
    float guz = SQRT3f*q1z + SQRT15f*uy*q1 + 3.f*SQRT5f*uz*q2 + SQRT15f*ux*q3;

    gr  = grp16_sum(gr);
    gux = grp16_sum(gux);
    guy = grp16_sum(guy);
    guz = grp16_sum(guz);

    if (c == 0) {
      float gdotu = gux*ux + guy*uy + guz*uz;
      dv_buf[e*3+0] = gr*ux + (gux - gdotu*ux)*inv_r;
      dv_buf[e*3+1] = gr*uy + (guy - gdotu*uy)*inv_r;
      dv_buf[e*3+2] = gr*uz + (guz - gdotu*uz)*inv_r;
    }
  }
  g0[n*16 + c] += accg0;
  #pragma unroll
  for (int m = 0; m < 3; m++) g1[n*48 + c*3 + m] = accg1[m];
  #pragma unroll
  for (int m = 0; m < 5; m++) g2[n*80 + c*5 + m] = accg2[m];
}

// ---------------------------------------------------------------------------
// Backward block 0, ROW-centric.
// ---------------------------------------------------------------------------
__global__ void k_bwd_b0_row(const float* __restrict__ pos, const int* __restrict__ ei, int E,
                             const float* __restrict__ Wr, const float* __restrict__ br,
                             const float* __restrict__ h0_in,
                             const float* __restrict__ ga0, const float* __restrict__ ga1,
                             const float* __restrict__ ga2,
                             const int* __restrict__ off_row, const int* __restrict__ eid_row,
                             float* __restrict__ dv_buf, int N)
{
  int n = blockIdx.x * (blockDim.x >> 4) + (threadIdx.x >> 4);
  int c = threadIdx.x & 15;
  if (n >= N) return;
  float wr0[8], wr1[8], wr2[8];
  #pragma unroll
  for (int k = 0; k < 8; k++) {
    wr0[k] = Wr[k*80 + c];
    wr1[k] = Wr[k*80 + 16 + c];
    wr2[k] = Wr[k*80 + 32 + c];
  }
  float b1v = br[16 + c], b2v = br[32 + c];
  float nx = pos[n*3+0], ny = pos[n*3+1], nz = pos[n*3+2];

  float dm0 = ga0[n*16 + c];
  float dm1[3], dm2[5];
  #pragma unroll
  for (int m = 0; m < 3; m++) dm1[m] = ga1[n*48 + c*3 + m];
  #pragma unroll
  for (int m = 0; m < 5; m++) dm2[m] = ga2[n*80 + c*5 + m];

  int i0 = off_row[n], i1 = off_row[n+1];
  int e_n = 0; float pxn=0.f, pyn=0.f, pzn=0.f, h0n=0.f;
  if (i0 < i1) {
    e_n = eid_row[i0]; int col = ei[E + e_n];
    pxn = nx - pos[col*3+0]; pyn = ny - pos[col*3+1]; pzn = nz - pos[col*3+2];
    h0n = h0_in[col*16 + c];
  }
  for (int i = i0; i < i1; i++) {
    int e = e_n;
    float px = pxn, py = pyn, pz = pzn, h0c = h0n;
    if (i+1 < i1) {
      e_n = eid_row[i+1]; int col = ei[E + e_n];
      pxn = nx - pos[col*3+0]; pyn = ny - pos[col*3+1]; pzn = nz - pos[col*3+2];
      h0n = h0_in[col*16 + c];
    }
    float r, inv_r, ux, uy, uz, rad[8], ck[8], sh1[3], sh2[5], draddr[8];
    geom_core(px, py, pz, r, inv_r, ux, uy, uz, rad, ck, sh1, sh2);
    geom_drad(inv_r, rad, ck, draddr);

    float w1 = b1v, w2v = b2v;
    #pragma unroll
    for (int k = 0; k < 8; k++) { w1 += rad[k]*wr1[k]; w2v += rad[k]*wr2[k]; }

    float T1 = 0.f, T2 = 0.f;
    #pragma unroll
    for (int m = 0; m < 3; m++) T1 += dm1[m]*sh1[m];
    #pragma unroll
    for (int m = 0; m < 5; m++) T2 += dm2[m]*sh2[m];

    float dw0 = dm0 * h0c;
    float dw1 = h0c * T1;
    float dw2 = h0c * T2;

    float w1h = w1*h0c, w2h = w2v*h0c;
    float q1x = dm1[0]*w1h, q1y = dm1[1]*w1h, q1z = dm1[2]*w1h;
    float q0 = dm2[0]*w2h, q1 = dm2[1]*w2h, q2 = dm2[2]*w2h, q3 = dm2[3]*w2h, q4 = dm2[4]*w2h;

    float gr = 0.f;
    #pragma unroll
    for (int k = 0; k < 8; k++)
      gr += (dw0*wr0[k] + dw1*wr1[k] + dw2*wr2[k]) * draddr[k];
    float gux = SQRT3f*q1x + SQRT15f*(uy*q0 + uz*q3 + ux*q4);
    float guy = SQRT3f*q1y + SQRT15f*(ux*q0 + uz*q1 - uy*q4);
    float guz = SQRT3f*q1z + SQRT15f*uy*q1 + 3.f*SQRT5f*uz*q2 + SQRT15f*ux*q3;

    gr  = grp16_sum(gr);
    gux = grp16_sum(gux);
    guy = grp16_sum(guy);
    guz = grp16_sum(guz);

    if (c == 0) {
      float gdotu = gux*ux + guy*uy + guz*uz;
      dv_buf[e*3+0] += gr*ux + (gux - gdotu*ux)*inv_r;
      dv_buf[e*3+1] += gr*uy + (guy - gdotu*uy)*inv_r;
      dv_buf[e*3+2] += gr*uz + (guz - gdotu*uz)*inv_r;
    }
  }
}

// ---------------------------------------------------------------------------
// Force assembly: force[n] = sum_{col==n} dv - sum_{row==n} dv
// ---------------------------------------------------------------------------
__global__ void k_force(const int* __restrict__ off_row, const int* __restrict__ eid_row,
                        const int* __restrict__ off_col, const int* __restrict__ eid_col,
                        const float* __restrict__ dv, float* __restrict__ force, int N)
{
  int n = blockIdx.x * blockDim.x + threadIdx.x;
  if (n >= N) return;
  float fx = 0.f, fy = 0.f, fz = 0.f;
  for (int i = off_col[n]; i < off_col[n+1]; i++) {
    int e = eid_col[i];
    fx += dv[e*3+0]; fy += dv[e*3+1]; fz += dv[e*3+2];
  }
  for (int i = off_row[n]; i < off_row[n+1]; i++) {
    int e = eid_row[i];
    fx -= dv[e*3+0]; fy -= dv[e*3+1]; fz -= dv[e*3+2];
  }
  force[n*3+0] = fx; force[n*3+1] = fy; force[n*3+2] = fz;
}

// ---------------------------------------------------------------------------
extern "C" void kernel_launch(void* const* d_in, const int* in_sizes, int n_in,
                              void* d_out, int out_size, void* d_ws, size_t ws_size,
                              hipStream_t stream)
{
  const float* pos    = (const float*)d_in[0];
  const int*   z      = (const int*)  d_in[1];
  const int*   ei     = (const int*)  d_in[2];
  const float* emb    = (const float*)d_in[3];
  const float* W_init = (const float*)d_in[4];
  const float* Wr     = (const float*)d_in[5];   // (2, 8, 80)
  const float* br     = (const float*)d_in[6];   // (2, 80)
  const float* W_out  = (const float*)d_in[7];   // (2, 3, 16, 16)
  const float* W_read = (const float*)d_in[8];
  const float* W1     = (const float*)d_in[9];
  const float* b1     = (const float*)d_in[10];
  const float* W2     = (const float*)d_in[11];
  const float* b2     = (const float*)d_in[12];

  const int N = in_sizes[0] / 3;
  const int E = in_sizes[2] / 2;

  float* f = (float*)d_ws;
  float* h0_s0 = f; f += (size_t)N*16;
  float* h0_s1 = f; f += (size_t)N*16;
  float* h0_s2 = f; f += (size_t)N*16;
  float* h1_s1 = f; f += (size_t)N*48;
  float* h2_s1 = f; f += (size_t)N*80;
  float* a0    = f; f += (size_t)N*16;   // also ga0
  float* a1    = f; f += (size_t)N*48;   // also ga1
  float* a2    = f; f += (size_t)N*80;   // also ga2
  float* g0    = f; f += (size_t)N*16;
  float* g1    = f; f += (size_t)N*48;
  float* g2    = f; f += (size_t)N*80;
  float* dv    = f; f += (size_t)E*3;
  int* ip = (int*)f;
  int* deg_row = ip; ip += N;            // deg_row+deg_col contiguous -> one memset
  int* deg_col = ip; ip += N;
  int* off_row = ip; ip += N+1;
  int* off_col = ip; ip += N+1;
  int* cur_row = ip; ip += N;
  int* cur_col = ip; ip += N;
  int* eid_row = ip; ip += E;
  int* eid_col = ip; ip += E;

  float* out    = (float*)d_out;
  float* energy = out;
  float* force  = out + 1;

  const int BLK = 256;
  const int GPB = BLK / 16;  // 16-lane groups per block

  (void)hipMemsetAsync(energy, 0, sizeof(float), stream);
  (void)hipMemsetAsync(deg_row, 0, (size_t)2 * N * sizeof(int), stream);

  // ---- CSR build ----
  k_hist<<<cdiv(E, BLK), BLK, 0, stream>>>(ei, E, deg_row, deg_col);
  k_scan<<<1, SCAN_T, 0, stream>>>(deg_row, deg_col, off_row, off_col, cur_row, cur_col, N);
  k_scatter<<<cdiv(E, BLK), BLK, 0, stream>>>(ei, E, cur_row, cur_col, eid_row, eid_col);

  k_node_init<<<cdiv(N, BLK), BLK, 0, stream>>>(emb, z, W_init, h0_s0, N);

  // ---- forward block 0 ----
  k_fwd_b0<<<cdiv(N, GPB), BLK, 0, stream>>>(pos, ei, E, Wr, br, h0_s0,
                                             off_row, eid_row, a0, a1, a2, N);
  k_node_update<<<cdiv(N*16, BLK), BLK, 0, stream>>>(h0_s0, a0, a1, a2,
                                                     W_out, h0_s1, h1_s1, h2_s1, N, 1);

  // ---- forward block 1 (only h0 path live) ----
  k_fwd_b1<<<cdiv(N, GPB), BLK, 0, stream>>>(pos, ei, E, Wr + 640, br + 80,
                                             h0_s1, h1_s1, h2_s1,
                                             off_row, eid_row, a0, N);
  k_node_update<<<cdiv(N*16, BLK), BLK, 0, stream>>>(h0_s1, a0, nullptr, nullptr,
                                                     W_out + 768, h0_s2, nullptr, nullptr, N, 0);

  // ---- readout fwd + bwd ----
  k_readout_bwd<<<cdiv(N, BLK), BLK, 0, stream>>>(h0_s2, W_read, W1, b1, W2, b2, g0, energy, N);

  // ---- backward block 1 ----
  k_ga<<<cdiv(N*16, BLK), BLK, 0, stream>>>(g0, nullptr, nullptr, W_out + 768,
                                            a0, nullptr, nullptr, N, 0);
  k_bwd_b1_col<<<cdiv(N, GPB), BLK, 0, stream>>>(pos, ei, E, Wr + 640, br + 80,
                                                 h0_s1, h1_s1, h2_s1, a0,
                                                 off_col, eid_col, g0, g1, g2, dv, N);

  // ---- backward block 0 ----
  k_ga<<<cdiv(N*16, BLK), BLK, 0, stream>>>(g0, g1, g2, W_out, a0, a1, a2, N, 1);
  k_bwd_b0_row<<<cdiv(N, GPB), BLK, 0, stream>>>(pos, ei, E, Wr, br, h0_s0,
                                                 a0, a1, a2, off_row, eid_row, dv, N);

  // ---- force assembly ----
  k_force<<<cdiv(N, BLK), BLK, 0, stream>>>(off_row, eid_row, off_col, eid_col, dv, force, N);
}

// Round 6
// 722.065 us; speedup vs baseline: 3.2644x; 1.0402x over previous
//
#include <hip/hip_runtime.h>
#include <math.h>

#ifndef M_PI
#define M_PI 3.14159265358979323846
#endif

static inline int cdiv(int a, int b){ return (a + b - 1) / b; }

#define SQRT3f  1.7320508075688772f
#define SQRT5f  2.23606797749979f
#define SQRT15f 3.872983346207417f
#define KRADf   0.6324555320336759f      /* sqrt(2/R_MAX), R_MAX=5 */
#define PI5f    0.6283185307179586f      /* pi/5 */

__device__ __forceinline__ float grp16_sum(float v){
  v += __shfl_xor(v, 1, 64);
  v += __shfl_xor(v, 2, 64);
  v += __shfl_xor(v, 4, 64);
  v += __shfl_xor(v, 8, 64);
  return v;
}

// sh from unit vector (8 ops)
__device__ __forceinline__ void sh_from_u(float ux, float uy, float uz,
                                          float* sh1, float* sh2)
{
  sh1[0] = SQRT3f*ux; sh1[1] = SQRT3f*uy; sh1[2] = SQRT3f*uz;
  sh2[0] = SQRT15f*ux*uy;
  sh2[1] = SQRT15f*uy*uz;
  sh2[2] = 0.5f*SQRT5f*(3.f*uz*uz - 1.f);
  sh2[3] = SQRT15f*ux*uz;
  sh2[4] = 0.5f*SQRT15f*(ux*ux - uy*uy);
}

// ---------------------------------------------------------------------------
// Per-edge geometry precompute (ONE thread per edge; was computed 16x in each
// of 4 edge kernels). Layout: geo[e*5+0]=rad[0..3], +1=rad[4..7],
// +2=draddr[0..3], +3=draddr[4..7], +4=(ux,uy,uz,inv_r).
// ---------------------------------------------------------------------------
__global__ void k_geom(const float* __restrict__ pos, const int* __restrict__ ei, int E,
                       float4* __restrict__ geo)
{
  int e = blockIdx.x * blockDim.x + threadIdx.x;
  if (e >= E) return;
  int row = ei[e], col = ei[E + e];
  float px = pos[row*3+0] - pos[col*3+0];
  float py = pos[row*3+1] - pos[col*3+1];
  float pz = pos[row*3+2] - pos[col*3+2];
  float r2 = px*px + py*py + pz*pz + 1e-12f;
  float r = sqrtf(r2);
  float inv_r = 1.0f / r;
  float ux = px*inv_r, uy = py*inv_r, uz = pz*inv_r;
  float x = r * PI5f;
  float s1, c1;
  sincosf(x, &s1, &c1);
  float tc = 2.f * c1;
  float sprev = 0.f, s = s1, cprev = 1.f, cc = c1;
  float Ki = KRADf * inv_r;
  float rad[8], draddr[8];
  const float KPI5 = KRADf * PI5f;
  #pragma unroll
  for (int k = 0; k < 8; k++) {
    rad[k] = Ki * s;
    draddr[k] = (KPI5 * (float)(k+1) * cc - rad[k]) * inv_r;
    float sn = tc*s - sprev; sprev = s; s = sn;
    float cn = tc*cc - cprev; cprev = cc; cc = cn;
  }
  geo[e*5+0] = make_float4(rad[0], rad[1], rad[2], rad[3]);
  geo[e*5+1] = make_float4(rad[4], rad[5], rad[6], rad[7]);
  geo[e*5+2] = make_float4(draddr[0], draddr[1], draddr[2], draddr[3]);
  geo[e*5+3] = make_float4(draddr[4], draddr[5], draddr[6], draddr[7]);
  geo[e*5+4] = make_float4(ux, uy, uz, inv_r);
}

// ---------------------------------------------------------------------------
// CSR build: histogram, scan (1 block, 1024 threads), scatter
// ---------------------------------------------------------------------------
__global__ void k_hist(const int* __restrict__ ei, int E,
                       int* __restrict__ deg_row, int* __restrict__ deg_col)
{
  int e = blockIdx.x * blockDim.x + threadIdx.x;
  if (e >= E) return;
  atomicAdd(&deg_row[ei[e]], 1);
  atomicAdd(&deg_col[ei[E + e]], 1);
}

#define SCAN_T 1024
__global__ void k_scan(const int* __restrict__ degA, const int* __restrict__ degB,
                       int* __restrict__ offA, int* __restrict__ offB,
                       int* __restrict__ curA, int* __restrict__ curB, int N)
{
  __shared__ int lds[SCAN_T];
  int t = threadIdx.x;
  int chunk = (N + SCAN_T - 1) / SCAN_T;
  for (int which = 0; which < 2; which++) {
    const int* deg = which ? degB : degA;
    int* off = which ? offB : offA;
    int* cur = which ? curB : curA;
    int lo = t * chunk; if (lo > N) lo = N;
    int hi = lo + chunk; if (hi > N) hi = N;
    int s = 0;
    for (int i = lo; i < hi; i++) s += deg[i];
    lds[t] = s;
    __syncthreads();
    #pragma unroll
    for (int d = 1; d < SCAN_T; d <<= 1) {
      int y = (t >= d) ? lds[t - d] : 0;
      __syncthreads();
      lds[t] += y;
      __syncthreads();
    }
    int running = lds[t] - s;
    for (int i = lo; i < hi; i++) {
      off[i] = running; cur[i] = running;
      running += deg[i];
    }
    if (t == SCAN_T - 1) off[N] = lds[SCAN_T - 1];
    __syncthreads();
  }
}

__global__ void k_scatter(const int* __restrict__ ei, int E,
                          int* __restrict__ cur_row, int* __restrict__ cur_col,
                          int* __restrict__ eid_row, int* __restrict__ eid_col)
{
  int e = blockIdx.x * blockDim.x + threadIdx.x;
  if (e >= E) return;
  int pr = atomicAdd(&cur_row[ei[e]], 1);
  eid_row[pr] = e;
  int pc = atomicAdd(&cur_col[ei[E + e]], 1);
  eid_col[pc] = e;
}

// ---------------------------------------------------------------------------
// h0_init[n,:] = emb[z[n],:] @ W_init
// ---------------------------------------------------------------------------
__global__ void k_node_init(const float* __restrict__ emb, const int* __restrict__ z,
                            const float* __restrict__ W_init, float* __restrict__ h0, int N)
{
  __shared__ float sW[256];
  if (threadIdx.x < 256) sW[threadIdx.x] = W_init[threadIdx.x];
  __syncthreads();
  int n = blockIdx.x * blockDim.x + threadIdx.x;
  if (n >= N) return;
  const float* e = emb + z[n]*16;
  float ev[16];
  #pragma unroll
  for (int k = 0; k < 16; k++) ev[k] = e[k];
  #pragma unroll
  for (int c = 0; c < 16; c++) {
    float s = 0.f;
    #pragma unroll
    for (int k = 0; k < 16; k++) s += ev[k] * sW[k*16+c];
    h0[n*16+c] = s;
  }
}

// ---------------------------------------------------------------------------
// Forward block 0, row-centric gather. 16 lanes per node (one per channel).
// ---------------------------------------------------------------------------
__global__ void k_fwd_b0(const int* __restrict__ ei, int E,
                         const float* __restrict__ Wr, const float* __restrict__ br,
                         const float* __restrict__ h0_in, const float4* __restrict__ geo,
                         const int* __restrict__ off_row, const int* __restrict__ eid_row,
                         float* __restrict__ a0, float* __restrict__ a1, float* __restrict__ a2,
                         int N)
{
  int n = blockIdx.x * (blockDim.x >> 4) + (threadIdx.x >> 4);
  int c = threadIdx.x & 15;
  if (n >= N) return;
  float wr0[8], wr1[8], wr2[8];
  #pragma unroll
  for (int k = 0; k < 8; k++) {
    wr0[k] = Wr[k*80 + c];
    wr1[k] = Wr[k*80 + 16 + c];
    wr2[k] = Wr[k*80 + 32 + c];
  }
  float b0v = br[c], b1v = br[16 + c], b2v = br[32 + c];

  float acc0 = 0.f, acc1[3] = {0.f,0.f,0.f}, acc2[5] = {0.f,0.f,0.f,0.f,0.f};

  int i0 = off_row[n], i1 = off_row[n+1];
  float4 G0n = {0,0,0,0}, G1n = {0,0,0,0}, G4n = {0,0,0,0};
  float h0n = 0.f;
  if (i0 < i1) {
    int e = eid_row[i0]; int col = ei[E + e];
    G0n = geo[e*5+0]; G1n = geo[e*5+1]; G4n = geo[e*5+4];
    h0n = h0_in[col*16 + c];
  }
  for (int i = i0; i < i1; i++) {
    float4 G0 = G0n, G1 = G1n, G4 = G4n;
    float h0c = h0n;
    if (i+1 < i1) {
      int e = eid_row[i+1]; int col = ei[E + e];
      G0n = geo[e*5+0]; G1n = geo[e*5+1]; G4n = geo[e*5+4];
      h0n = h0_in[col*16 + c];
    }
    float rad[8] = {G0.x,G0.y,G0.z,G0.w,G1.x,G1.y,G1.z,G1.w};
    float sh1[3], sh2[5];
    sh_from_u(G4.x, G4.y, G4.z, sh1, sh2);
    float w0 = b0v, w1 = b1v, w2 = b2v;
    #pragma unroll
    for (int k = 0; k < 8; k++) {
      w0 += rad[k]*wr0[k]; w1 += rad[k]*wr1[k]; w2 += rad[k]*wr2[k];
    }
    acc0 += w0*h0c;
    float wh1 = w1*h0c, wh2 = w2*h0c;
    #pragma unroll
    for (int m = 0; m < 3; m++) acc1[m] += wh1*sh1[m];
    #pragma unroll
    for (int m = 0; m < 5; m++) acc2[m] += wh2*sh2[m];
  }
  a0[n*16 + c] = acc0;
  #pragma unroll
  for (int m = 0; m < 3; m++) a1[n*48 + c*3 + m] = acc1[m];
  #pragma unroll
  for (int m = 0; m < 5; m++) a2[n*80 + c*5 + m] = acc2[m];
}

// ---------------------------------------------------------------------------
// Forward block 1 (last): a0 += w0*h0c + w3*S1 + w4*S2
// ---------------------------------------------------------------------------
__global__ void k_fwd_b1(const int* __restrict__ ei, int E,
                         const float* __restrict__ Wr, const float* __restrict__ br,
                         const float* __restrict__ h0_in, const float* __restrict__ h1_in,
                         const float* __restrict__ h2_in, const float4* __restrict__ geo,
                         const int* __restrict__ off_row, const int* __restrict__ eid_row,
                         float* __restrict__ a0, int N)
{
  int n = blockIdx.x * (blockDim.x >> 4) + (threadIdx.x >> 4);
  int c = threadIdx.x & 15;
  if (n >= N) return;
  float wr0[8], wr3[8], wr4[8];
  #pragma unroll
  for (int k = 0; k < 8; k++) {
    wr0[k] = Wr[k*80 + c];
    wr3[k] = Wr[k*80 + 48 + c];
    wr4[k] = Wr[k*80 + 64 + c];
  }
  float b0v = br[c], b3v = br[48 + c], b4v = br[64 + c];

  float acc0 = 0.f;
  int i0 = off_row[n], i1 = off_row[n+1];
  float4 G0n = {0,0,0,0}, G1n = {0,0,0,0}, G4n = {0,0,0,0};
  float h0n = 0.f, h1n[3] = {0,0,0}, h2n[5] = {0,0,0,0,0};
  if (i0 < i1) {
    int e = eid_row[i0]; int col = ei[E + e];
    G0n = geo[e*5+0]; G1n = geo[e*5+1]; G4n = geo[e*5+4];
    h0n = h0_in[col*16 + c];
    #pragma unroll
    for (int m = 0; m < 3; m++) h1n[m] = h1_in[col*48 + c*3 + m];
    #pragma unroll
    for (int m = 0; m < 5; m++) h2n[m] = h2_in[col*80 + c*5 + m];
  }
  for (int i = i0; i < i1; i++) {
    float4 G0 = G0n, G1 = G1n, G4 = G4n;
    float h0c = h0n;
    float h1c[3], h2c[5];
    #pragma unroll
    for (int m = 0; m < 3; m++) h1c[m] = h1n[m];
    #pragma unroll
    for (int m = 0; m < 5; m++) h2c[m] = h2n[m];
    if (i+1 < i1) {
      int e = eid_row[i+1]; int col = ei[E + e];
      G0n = geo[e*5+0]; G1n = geo[e*5+1]; G4n = geo[e*5+4];
      h0n = h0_in[col*16 + c];
      #pragma unroll
      for (int m = 0; m < 3; m++) h1n[m] = h1_in[col*48 + c*3 + m];
      #pragma unroll
      for (int m = 0; m < 5; m++) h2n[m] = h2_in[col*80 + c*5 + m];
    }
    float rad[8] = {G0.x,G0.y,G0.z,G0.w,G1.x,G1.y,G1.z,G1.w};
    float sh1[3], sh2[5];
    sh_from_u(G4.x, G4.y, G4.z, sh1, sh2);
    float w0 = b0v, w3 = b3v, w4 = b4v;
    #pragma unroll
    for (int k = 0; k < 8; k++) {
      w0 += rad[k]*wr0[k]; w3 += rad[k]*wr3[k]; w4 += rad[k]*wr4[k];
    }
    float S1 = 0.f, S2 = 0.f;
    #pragma unroll
    for (int m = 0; m < 3; m++) S1 += h1c[m]*sh1[m];
    #pragma unroll
    for (int m = 0; m < 5; m++) S2 += h2c[m]*sh2[m];
    acc0 += w0*h0c + w3*S1 + w4*S2;
  }
  a0[n*16 + c] = acc0;
}

// ---------------------------------------------------------------------------
// Node update: h_out = h_in + a @ U
// ---------------------------------------------------------------------------
__global__ void k_node_update(const float* __restrict__ h0_in,
                              const float* __restrict__ a0, const float* __restrict__ a1,
                              const float* __restrict__ a2,
                              const float* __restrict__ U,
                              float* __restrict__ h0_out, float* __restrict__ h1_out,
                              float* __restrict__ h2_out, int N, int full)
{
  int idx = blockIdx.x * blockDim.x + threadIdx.x;
  int n = idx >> 4, d = idx & 15;
  if (n >= N) return;
  const float* U0 = U;
  const float* U1 = U + 256;
  const float* U2 = U + 512;
  float s = h0_in[n*16 + d];
  #pragma unroll
  for (int c = 0; c < 16; c++) s += a0[n*16 + c] * U0[c*16 + d];
  h0_out[n*16 + d] = s;
  if (full) {
    float v1[3] = {0.f, 0.f, 0.f};
    #pragma unroll
    for (int c = 0; c < 16; c++) {
      float u = U1[c*16 + d];
      #pragma unroll
      for (int m = 0; m < 3; m++) v1[m] += a1[n*48 + c*3 + m] * u;
    }
    #pragma unroll
    for (int m = 0; m < 3; m++) h1_out[n*48 + d*3 + m] = v1[m];
    float v2[5] = {0.f, 0.f, 0.f, 0.f, 0.f};
    #pragma unroll
    for (int c = 0; c < 16; c++) {
      float u = U2[c*16 + d];
      #pragma unroll
      for (int m = 0; m < 5; m++) v2[m] += a2[n*80 + c*5 + m] * u;
    }
    #pragma unroll
    for (int m = 0; m < 5; m++) h2_out[n*80 + d*5 + m] = v2[m];
  }
}

// ---------------------------------------------------------------------------
// Readout fwd + bwd fused
// ---------------------------------------------------------------------------
__global__ void k_readout_bwd(const float* __restrict__ h0, const float* __restrict__ W_read,
                              const float* __restrict__ W1, const float* __restrict__ b1,
                              const float* __restrict__ W2, const float* __restrict__ b2,
                              float* __restrict__ g0, float* __restrict__ energy, int N)
{
  int n = blockIdx.x * blockDim.x + threadIdx.x;
  float site = 0.f;
  if (n < N) {
    float h[16], inv[16], dt[16];
    #pragma unroll
    for (int d = 0; d < 16; d++) h[d] = h0[n*16 + d];
    #pragma unroll
    for (int j = 0; j < 16; j++) {
      float s = 0.f;
      #pragma unroll
      for (int d = 0; d < 16; d++) s += h[d] * W_read[d*16 + j];
      inv[j] = s;
    }
    site = b2[0];
    #pragma unroll
    for (int c = 0; c < 16; c++) {
      float t = b1[c];
      #pragma unroll
      for (int j = 0; j < 16; j++) t += inv[j] * W1[j*16 + c];
      float sg = 1.f / (1.f + expf(-t));
      float w2v = W2[c];
      site += t * sg * w2v;
      dt[c] = w2v * sg * (1.f + t * (1.f - sg));
    }
    float dinv[16];
    #pragma unroll
    for (int j = 0; j < 16; j++) {
      float s = 0.f;
      #pragma unroll
      for (int c = 0; c < 16; c++) s += dt[c] * W1[j*16 + c];
      dinv[j] = s;
    }
    #pragma unroll
    for (int d = 0; d < 16; d++) {
      float s = 0.f;
      #pragma unroll
      for (int j = 0; j < 16; j++) s += dinv[j] * W_read[d*16 + j];
      g0[n*16 + d] = s;
    }
  }
  #pragma unroll
  for (int off = 32; off; off >>= 1) site += __shfl_down(site, off, 64);
  if ((threadIdx.x & 63) == 0) atomicAdd(energy, site);
}

// ---------------------------------------------------------------------------
// ga = g @ U^T
// ---------------------------------------------------------------------------
__global__ void k_ga(const float* __restrict__ g0, const float* __restrict__ g1,
                     const float* __restrict__ g2, const float* __restrict__ U,
                     float* __restrict__ ga0, float* __restrict__ ga1, float* __restrict__ ga2,
                     int N, int full)
{
  int idx = blockIdx.x * blockDim.x + threadIdx.x;
  int n = idx >> 4, c = idx & 15;
  if (n >= N) return;
  const float* U0 = U;
  const float* U1 = U + 256;
  const float* U2 = U + 512;
  float s = 0.f;
  #pragma unroll
  for (int d = 0; d < 16; d++) s += g0[n*16 + d] * U0[c*16 + d];
  ga0[n*16 + c] = s;
  if (full) {
    float v1[3] = {0.f, 0.f, 0.f};
    #pragma unroll
    for (int d = 0; d < 16; d++) {
      float u = U1[c*16 + d];
      #pragma unroll
      for (int m = 0; m < 3; m++) v1[m] += g1[n*48 + d*3 + m] * u;
    }
    #pragma unroll
    for (int m = 0; m < 3; m++) ga1[n*48 + c*3 + m] = v1[m];
    float v2[5] = {0.f, 0.f, 0.f, 0.f, 0.f};
    #pragma unroll
    for (int d = 0; d < 16; d++) {
      float u = U2[c*16 + d];
      #pragma unroll
      for (int m = 0; m < 5; m++) v2[m] += g2[n*80 + d*5 + m] * u;
    }
    #pragma unroll
    for (int m = 0; m < 5; m++) ga2[n*80 + c*5 + m] = v2[m];
  }
}

// ---------------------------------------------------------------------------
// Backward block 1, col-centric.
// ---------------------------------------------------------------------------
__global__ void k_bwd_b1_col(const int* __restrict__ ei, int E,
                             const float* __restrict__ Wr, const float* __restrict__ br,
                             const float* __restrict__ h0_in, const float* __restrict__ h1_in,
                             const float* __restrict__ h2_in,
                             const float* __restrict__ ga0, const float4* __restrict__ geo,
                             const int* __restrict__ off_col, const int* __restrict__ eid_col,
                             float* __restrict__ g0, float* __restrict__ g1, float* __restrict__ g2,
                             float* __restrict__ dv_buf, int N)
{
  int n = blockIdx.x * (blockDim.x >> 4) + (threadIdx.x >> 4);
  int c = threadIdx.x & 15;
  if (n >= N) return;
  float wr0[8], wr3[8], wr4[8];
  #pragma unroll
  for (int k = 0; k < 8; k++) {
    wr0[k] = Wr[k*80 + c];
    wr3[k] = Wr[k*80 + 48 + c];
    wr4[k] = Wr[k*80 + 64 + c];
  }
  float b0v = br[c], b3v = br[48 + c], b4v = br[64 + c];

  float h0c = h0_in[n*16 + c];
  float h1c[3], h2c[5];
  #pragma unroll
  for (int m = 0; m < 3; m++) h1c[m] = h1_in[n*48 + c*3 + m];
  #pragma unroll
  for (int m = 0; m < 5; m++) h2c[m] = h2_in[n*80 + c*5 + m];

  float accg0 = 0.f, accg1[3] = {0.f,0.f,0.f}, accg2[5] = {0.f,0.f,0.f,0.f,0.f};

  int i0 = off_col[n], i1 = off_col[n+1];
  int e_n = 0;
  float4 G0n = {0,0,0,0}, G1n = {0,0,0,0}, G2n = {0,0,0,0}, G3n = {0,0,0,0}, G4n = {0,0,0,0};
  float dm0n = 0.f;
  if (i0 < i1) {
    e_n = eid_col[i0]; int row = ei[e_n];
    G0n = geo[e_n*5+0]; G1n = geo[e_n*5+1]; G2n = geo[e_n*5+2];
    G3n = geo[e_n*5+3]; G4n = geo[e_n*5+4];
    dm0n = ga0[row*16 + c];
  }
  for (int i = i0; i < i1; i++) {
    int e = e_n;
    float4 G0 = G0n, G1 = G1n, G2 = G2n, G3 = G3n, G4 = G4n;
    float dm0 = dm0n;
    if (i+1 < i1) {
      e_n = eid_col[i+1]; int row = ei[e_n];
      G0n = geo[e_n*5+0]; G1n = geo[e_n*5+1]; G2n = geo[e_n*5+2];
      G3n = geo[e_n*5+3]; G4n = geo[e_n*5+4];
      dm0n = ga0[row*16 + c];
    }
    float rad[8]    = {G0.x,G0.y,G0.z,G0.w,G1.x,G1.y,G1.z,G1.w};
    float draddr[8] = {G2.x,G2.y,G2.z,G2.w,G3.x,G3.y,G3.z,G3.w};
    float ux = G4.x, uy = G4.y, uz = G4.z, inv_r = G4.w;
    float sh1[3], sh2[5];
    sh_from_u(ux, uy, uz, sh1, sh2);

    float w0 = b0v, w3 = b3v, w4 = b4v;
    #pragma unroll
    for (int k = 0; k < 8; k++) {
      w0 += rad[k]*wr0[k]; w3 += rad[k]*wr3[k]; w4 += rad[k]*wr4[k];
    }

    float S1 = 0.f, S2 = 0.f;
    #pragma unroll
    for (int m = 0; m < 3; m++) S1 += h1c[m]*sh1[m];
    #pragma unroll
    for (int m = 0; m < 5; m++) S2 += h2c[m]*sh2[m];

    float dw0 = dm0 * h0c;
    float dw3 = dm0 * S1;
    float dw4 = dm0 * S2;
    float t3 = dm0 * w3, t4 = dm0 * w4;

    accg0 += dm0 * w0;
    #pragma unroll
    for (int m = 0; m < 3; m++) accg1[m] += t3 * sh1[m];
    #pragma unroll
    for (int m = 0; m < 5; m++) accg2[m] += t4 * sh2[m];

    float q1x = t3*h1c[0], q1y = t3*h1c[1], q1z = t3*h1c[2];
    float q0 = t4*h2c[0], q1 = t4*h2c[1], q2 = t4*h2c[2], q3 = t4*h2c[3], q4 = t4*h2c[4];
    float gr = 0.f;
    #pragma unroll
    for (int k = 0; k < 8; k++)
      gr += (dw0*wr0[k] + dw3*wr3[k] + dw4*wr4[k]) * draddr[k];
    float gux = SQRT3f*q1x + SQRT15f*(uy*q0 + uz*q3 + ux*q4);
    float guy = SQRT3f*q1y + SQRT15f*(ux*q0 + uz*q1 - uy*q4);
    float guz = SQRT3f*q1z + SQRT15f*uy*q1 + 3.f*SQRT5f*uz*q2 + SQRT15f*ux*q3;

    gr  = grp16_sum(gr);
    gux = grp16_sum(gux);
    guy = grp16_sum(guy);
    guz = grp16_sum(guz);

    if (c == 0) {
      float gdotu = gux*ux + guy*uy + guz*uz;
      dv_buf[e*3+0] = gr*ux + (gux - gdotu*ux)*inv_r;
      dv_buf[e*3+1] = gr*uy + (guy - gdotu*uy)*inv_r;
      dv_buf[e*3+2] = gr*uz + (guz - gdotu*uz)*inv_r;
    }
  }
  g0[n*16 + c] += accg0;
  #pragma unroll
  for (int m = 0; m < 3; m++) g1[n*48 + c*3 + m] = accg1[m];
  #pragma unroll
  for (int m = 0; m < 5; m++) g2[n*80 + c*5 + m] = accg2[m];
}

// ---------------------------------------------------------------------------
// Backward block 0, ROW-centric.
// ---------------------------------------------------------------------------
__global__ void k_bwd_b0_row(const int* __restrict__ ei, int E,
                             const float* __restrict__ Wr, const float* __restrict__ br,
                             const float* __restrict__ h0_in,
                             const float* __restrict__ ga0, const float* __restrict__ ga1,
                             const float* __restrict__ ga2, const float4* __restrict__ geo,
                             const int* __restrict__ off_row, const int* __restrict__ eid_row,
                             float* __restrict__ dv_buf, int N)
{
  int n = blockIdx.x * (blockDim.x >> 4) + (threadIdx.x >> 4);
  int c = threadIdx.x & 15;
  if (n >= N) return;
  float wr0[8], wr1[8], wr2[8];
  #pragma unroll
  for (int k = 0; k < 8; k++) {
    wr0[k] = Wr[k*80 + c];
    wr1[k] = Wr[k*80 + 16 + c];
    wr2[k] = Wr[k*80 + 32 + c];
  }
  float b1v = br[16 + c], b2v = br[32 + c];

  float dm0 = ga0[n*16 + c];
  float dm1[3], dm2[5];
  #pragma unroll
  for (int m = 0; m < 3; m++) dm1[m] = ga1[n*48 + c*3 + m];
  #pragma unroll
  for (int m = 0; m < 5; m++) dm2[m] = ga2[n*80 + c*5 + m];

  int i0 = off_row[n], i1 = off_row[n+1];
  int e_n = 0;
  float4 G0n = {0,0,0,0}, G1n = {0,0,0,0}, G2n = {0,0,0,0}, G3n = {0,0,0,0}, G4n = {0,0,0,0};
  float h0n = 0.f;
  if (i0 < i1) {
    e_n = eid_row[i0]; int col = ei[E + e_n];
    G0n = geo[e_n*5+0]; G1n = geo[e_n*5+1]; G2n = geo[e_n*5+2];
    G3n = geo[e_n*5+3]; G4n = geo[e_n*5+4];
    h0n = h0_in[col*16 + c];
  }
  for (int i = i0; i < i1; i++) {
    int e = e_n;
    float4 G0 = G0n, G1 = G1n, G2 = G2n, G3 = G3n, G4 = G4n;
    float h0c = h0n;
    if (i+1 < i1) {
      e_n = eid_row[i+1]; int col = ei[E + e_n];
      G0n = geo[e_n*5+0]; G1n = geo[e_n*5+1]; G2n = geo[e_n*5+2];
      G3n = geo[e_n*5+3]; G4n = geo[e_n*5+4];
      h0n = h0_in[col*16 + c];
    }
    float rad[8]    = {G0.x,G0.y,G0.z,G0.w,G1.x,G1.y,G1.z,G1.w};
    float draddr[8] = {G2.x,G2.y,G2.z,G2.w,G3.x,G3.y,G3.z,G3.w};
    float ux = G4.x, uy = G4.y, uz = G4.z, inv_r = G4.w;
    float sh1[3], sh2[5];
    sh_from_u(ux, uy, uz, sh1, sh2);

    float w1 = b1v, w2v = b2v;
    #pragma unroll
    for (int k = 0; k < 8; k++) { w1 += rad[k]*wr1[k]; w2v += rad[k]*wr2[k]; }

    float T1 = 0.f, T2 = 0.f;
    #pragma unroll
    for (int m = 0; m < 3; m++) T1 += dm1[m]*sh1[m];
    #pragma unroll
    for (int m = 0; m < 5; m++) T2 += dm2[m]*sh2[m];

    float dw0 = dm0 * h0c;
    float dw1 = h0c * T1;
    float dw2 = h0c * T2;

    float w1h = w1*h0c, w2h = w2v*h0c;
    float q1x = dm1[0]*w1h, q1y = dm1[1]*w1h, q1z = dm1[2]*w1h;
    float q0 = dm2[0]*w2h, q1 = dm2[1]*w2h, q2 = dm2[2]*w2h, q3 = dm2[3]*w2h, q4 = dm2[4]*w2h;

    float gr = 0.f;
    #pragma unroll
    for (int k = 0; k < 8; k++)
      gr += (dw0*wr0[k] + dw1*wr1[k] + dw2*wr2[k]) * draddr[k];
    float gux = SQRT3f*q1x + SQRT15f*(uy*q0 + uz*q3 + ux*q4);
    float guy = SQRT3f*q1y + SQRT15f*(ux*q0 + uz*q1 - uy*q4);
    float guz = SQRT3f*q1z + SQRT15f*uy*q1 + 3.f*SQRT5f*uz*q2 + SQRT15f*ux*q3;

    gr  = grp16_sum(gr);
    gux = grp16_sum(gux);
    guy = grp16_sum(guy);
    guz = grp16_sum(guz);

    if (c == 0) {
      float gdotu = gux*ux + guy*uy + guz*uz;
      dv_buf[e*3+0] += gr*ux + (gux - gdotu*ux)*inv_r;
      dv_buf[e*3+1] += gr*uy + (guy - gdotu*uy)*inv_r;
      dv_buf[e*3+2] += gr*uz + (guz - gdotu*uz)*inv_r;
    }
  }
}

// ---------------------------------------------------------------------------
// Force assembly: force[n] = sum_{col==n} dv - sum_{row==n} dv
// ---------------------------------------------------------------------------
__global__ void k_force(const int* __restrict__ off_row, const int* __restrict__ eid_row,
                        const int* __restrict__ off_col, const int* __restrict__ eid_col,
                        const float* __restrict__ dv, float* __restrict__ force, int N)
{
  int n = blockIdx.x * blockDim.x + threadIdx.x;
  if (n >= N) return;
  float fx = 0.f, fy = 0.f, fz = 0.f;
  for (int i = off_col[n]; i < off_col[n+1]; i++) {
    int e = eid_col[i];
    fx += dv[e*3+0]; fy += dv[e*3+1]; fz += dv[e*3+2];
  }
  for (int i = off_row[n]; i < off_row[n+1]; i++) {
    int e = eid_row[i];
    fx -= dv[e*3+0]; fy -= dv[e*3+1]; fz -= dv[e*3+2];
  }
  force[n*3+0] = fx; force[n*3+1] = fy; force[n*3+2] = fz;
}

// ---------------------------------------------------------------------------
extern "C" void kernel_launch(void* const* d_in, const int* in_sizes, int n_in,
                              void* d_out, int out_size, void* d_ws, size_t ws_size,
                              hipStream_t stream)
{
  const float* pos    = (const float*)d_in[0];
  const int*   z      = (const int*)  d_in[1];
  const int*   ei     = (const int*)  d_in[2];
  const float* emb    = (const float*)d_in[3];
  const float* W_init = (const float*)d_in[4];
  const float* Wr     = (const float*)d_in[5];   // (2, 8, 80)
  const float* br     = (const float*)d_in[6];   // (2, 80)
  const float* W_out  = (const float*)d_in[7];   // (2, 3, 16, 16)
  const float* W_read = (const float*)d_in[8];
  const float* W1     = (const float*)d_in[9];
  const float* b1     = (const float*)d_in[10];
  const float* W2     = (const float*)d_in[11];
  const float* b2     = (const float*)d_in[12];

  const int N = in_sizes[0] / 3;
  const int E = in_sizes[2] / 2;

  float* f = (float*)d_ws;
  float* geo_f = f; f += (size_t)E*20;   // float4-aligned (d_ws base is aligned)
  float* h0_s0 = f; f += (size_t)N*16;
  float* h0_s1 = f; f += (size_t)N*16;
  float* h0_s2 = f; f += (size_t)N*16;
  float* h1_s1 = f; f += (size_t)N*48;
  float* h2_s1 = f; f += (size_t)N*80;
  float* a0    = f; f += (size_t)N*16;   // also ga0
  float* a1    = f; f += (size_t)N*48;   // also ga1
  float* a2    = f; f += (size_t)N*80;   // also ga2
  float* g0    = f; f += (size_t)N*16;
  float* g1    = f; f += (size_t)N*48;
  float* g2    = f; f += (size_t)N*80;
  float* dv    = f; f += (size_t)E*3;
  int* ip = (int*)f;
  int* deg_row = ip; ip += N;            // deg_row+deg_col contiguous -> one memset
  int* deg_col = ip; ip += N;
  int* off_row = ip; ip += N+1;
  int* off_col = ip; ip += N+1;
  int* cur_row = ip; ip += N;
  int* cur_col = ip; ip += N;
  int* eid_row = ip; ip += E;
  int* eid_col = ip; ip += E;

  float4* geo = (float4*)geo_f;

  float* out    = (float*)d_out;
  float* energy = out;
  float* force  = out + 1;

  const int BLK = 256;
  const int GPB = BLK / 16;  // 16-lane groups per block

  (void)hipMemsetAsync(energy, 0, sizeof(float), stream);
  (void)hipMemsetAsync(deg_row, 0, (size_t)2 * N * sizeof(int), stream);

  // ---- CSR build + geometry precompute ----
  k_hist<<<cdiv(E, BLK), BLK, 0, stream>>>(ei, E, deg_row, deg_col);
  k_geom<<<cdiv(E, BLK), BLK, 0, stream>>>(pos, ei, E, geo);
  k_scan<<<1, SCAN_T, 0, stream>>>(deg_row, deg_col, off_row, off_col, cur_row, cur_col, N);
  k_scatter<<<cdiv(E, BLK), BLK, 0, stream>>>(ei, E, cur_row, cur_col, eid_row, eid_col);

  k_node_init<<<cdiv(N, BLK), BLK, 0, stream>>>(emb, z, W_init, h0_s0, N);

  // ---- forward block 0 ----
  k_fwd_b0<<<cdiv(N, GPB), BLK, 0, stream>>>(ei, E, Wr, br, h0_s0, geo,
                                             off_row, eid_row, a0, a1, a2, N);
  k_node_update<<<cdiv(N*16, BLK), BLK, 0, stream>>>(h0_s0, a0, a1, a2,
                                                     W_out, h0_s1, h1_s1, h2_s1, N, 1);

  // ---- forward block 1 (only h0 path live) ----
  k_fwd_b1<<<cdiv(N, GPB), BLK, 0, stream>>>(ei, E, Wr + 640, br + 80,
                                             h0_s1, h1_s1, h2_s1, geo,
                                             off_row, eid_row, a0, N);
  k_node_update<<<cdiv(N*16, BLK), BLK, 0, stream>>>(h0_s1, a0, nullptr, nullptr,
                                                     W_out + 768, h0_s2, nullptr, nullptr, N, 0);

  // ---- readout fwd + bwd ----
  k_readout_bwd<<<cdiv(N, BLK), BLK, 0, stream>>>(h0_s2, W_read, W1, b1, W2, b2, g0, energy, N);

  // ---- backward block 1 ----
  k_ga<<<cdiv(N*16, BLK), BLK, 0, stream>>>(g0, nullptr, nullptr, W_out + 768,
                                            a0, nullptr, nullptr, N, 0);
  k_bwd_b1_col<<<cdiv(N, GPB), BLK, 0, stream>>>(ei, E, Wr + 640, br + 80,
                                                 h0_s1, h1_s1, h2_s1, a0, geo,
                                                 off_col, eid_col, g0, g1, g2, dv, N);

  // ---- backward block 0 ----
  k_ga<<<cdiv(N*16, BLK), BLK, 0, stream>>>(g0, g1, g2, W_out, a0, a1, a2, N, 1);
  k_bwd_b0_row<<<cdiv(N, GPB), BLK, 0, stream>>>(ei, E, Wr, br, h0_s0,
                                                 a0, a1, a2, geo,
                                                 off_row, eid_row, dv, N);

  // ---- force assembly ----
  k_force<<<cdiv(N, BLK), BLK, 0, stream>>>(off_row, eid_row, off_col, eid_col, dv, force, N);
}

// Round 7
// 626.438 us; speedup vs baseline: 3.7627x; 1.1527x over previous
//
#include <hip/hip_runtime.h>
#include <math.h>

#ifndef M_PI
#define M_PI 3.14159265358979323846
#endif

static inline int cdiv(int a, int b){ return (a + b - 1) / b; }

#define SQRT3f  1.7320508075688772f
#define SQRT5f  2.23606797749979f
#define SQRT15f 3.872983346207417f
#define KRADf   0.6324555320336759f      /* sqrt(2/R_MAX), R_MAX=5 */
#define PI5f    0.6283185307179586f      /* pi/5 */

__device__ __forceinline__ float grp16_sum(float v){
  v += __shfl_xor(v, 1, 64);
  v += __shfl_xor(v, 2, 64);
  v += __shfl_xor(v, 4, 64);
  v += __shfl_xor(v, 8, 64);
  return v;
}

// sh from unit vector (8 ops)
__device__ __forceinline__ void sh_from_u(float ux, float uy, float uz,
                                          float* sh1, float* sh2)
{
  sh1[0] = SQRT3f*ux; sh1[1] = SQRT3f*uy; sh1[2] = SQRT3f*uz;
  sh2[0] = SQRT15f*ux*uy;
  sh2[1] = SQRT15f*uy*uz;
  sh2[2] = 0.5f*SQRT5f*(3.f*uz*uz - 1.f);
  sh2[3] = SQRT15f*ux*uz;
  sh2[4] = 0.5f*SQRT15f*(ux*ux - uy*uy);
}

// ---------------------------------------------------------------------------
// Per-edge geometry precompute + degree histogram (merged; both E-parallel).
// geo[e*5+0]=rad[0..3], +1=rad[4..7], +2=draddr[0..3], +3=draddr[4..7],
// +4=(ux,uy,uz,inv_r).
// ---------------------------------------------------------------------------
__global__ void k_geom_hist(const float* __restrict__ pos, const int* __restrict__ ei, int E,
                            float4* __restrict__ geo,
                            int* __restrict__ deg_row, int* __restrict__ deg_col)
{
  int e = blockIdx.x * blockDim.x + threadIdx.x;
  if (e >= E) return;
  int row = ei[e], col = ei[E + e];
  atomicAdd(&deg_row[row], 1);
  atomicAdd(&deg_col[col], 1);
  float px = pos[row*3+0] - pos[col*3+0];
  float py = pos[row*3+1] - pos[col*3+1];
  float pz = pos[row*3+2] - pos[col*3+2];
  float r2 = px*px + py*py + pz*pz + 1e-12f;
  float r = sqrtf(r2);
  float inv_r = 1.0f / r;
  float ux = px*inv_r, uy = py*inv_r, uz = pz*inv_r;
  float x = r * PI5f;
  float s1, c1;
  sincosf(x, &s1, &c1);
  float tc = 2.f * c1;
  float sprev = 0.f, s = s1, cprev = 1.f, cc = c1;
  float Ki = KRADf * inv_r;
  float rad[8], draddr[8];
  const float KPI5 = KRADf * PI5f;
  #pragma unroll
  for (int k = 0; k < 8; k++) {
    rad[k] = Ki * s;
    draddr[k] = (KPI5 * (float)(k+1) * cc - rad[k]) * inv_r;
    float sn = tc*s - sprev; sprev = s; s = sn;
    float cn = tc*cc - cprev; cprev = cc; cc = cn;
  }
  geo[e*5+0] = make_float4(rad[0], rad[1], rad[2], rad[3]);
  geo[e*5+1] = make_float4(rad[4], rad[5], rad[6], rad[7]);
  geo[e*5+2] = make_float4(draddr[0], draddr[1], draddr[2], draddr[3]);
  geo[e*5+3] = make_float4(draddr[4], draddr[5], draddr[6], draddr[7]);
  geo[e*5+4] = make_float4(ux, uy, uz, inv_r);
}

// ---------------------------------------------------------------------------
// Segment allocation WITHOUT a prefix scan: segment bases need not be in node
// order — wave-aggregated atomicAdd on a global cursor hands each node a
// disjoint [start, start+deg) range. Fully parallel (was: 1-block scan,
// 117 us of pure latency).
// ---------------------------------------------------------------------------
__global__ void k_alloc(const int* __restrict__ deg_row, const int* __restrict__ deg_col,
                        int* __restrict__ start_row, int* __restrict__ cur_row,
                        int* __restrict__ start_col, int* __restrict__ cur_col,
                        int* __restrict__ cursors, int N)
{
  int idx = blockIdx.x * blockDim.x + threadIdx.x;
  int lane = threadIdx.x & 63;
  #pragma unroll
  for (int which = 0; which < 2; which++) {
    const int* deg = which ? deg_col : deg_row;
    int* start = which ? start_col : start_row;
    int* cur   = which ? cur_col   : cur_row;
    int v = (idx < N) ? deg[idx] : 0;
    int incl = v;
    #pragma unroll
    for (int d = 1; d < 64; d <<= 1) {
      int y = __shfl_up(incl, d, 64);
      if (lane >= d) incl += y;
    }
    int wtot = __shfl(incl, 63, 64);
    int base = 0;
    if (lane == 63) base = atomicAdd(&cursors[which], wtot);
    base = __shfl(base, 63, 64);
    if (idx < N) { int st = base + incl - v; start[idx] = st; cur[idx] = st; }
  }
}

__global__ void k_scatter(const int* __restrict__ ei, int E,
                          int* __restrict__ cur_row, int* __restrict__ cur_col,
                          int* __restrict__ eid_row, int* __restrict__ eid_col)
{
  int e = blockIdx.x * blockDim.x + threadIdx.x;
  if (e >= E) return;
  int pr = atomicAdd(&cur_row[ei[e]], 1);
  eid_row[pr] = e;
  int pc = atomicAdd(&cur_col[ei[E + e]], 1);
  eid_col[pc] = e;
}

// ---------------------------------------------------------------------------
// h0_init[n,:] = emb[z[n],:] @ W_init
// ---------------------------------------------------------------------------
__global__ void k_node_init(const float* __restrict__ emb, const int* __restrict__ z,
                            const float* __restrict__ W_init, float* __restrict__ h0, int N)
{
  __shared__ float sW[256];
  if (threadIdx.x < 256) sW[threadIdx.x] = W_init[threadIdx.x];
  __syncthreads();
  int n = blockIdx.x * blockDim.x + threadIdx.x;
  if (n >= N) return;
  const float* e = emb + z[n]*16;
  float ev[16];
  #pragma unroll
  for (int k = 0; k < 16; k++) ev[k] = e[k];
  #pragma unroll
  for (int c = 0; c < 16; c++) {
    float s = 0.f;
    #pragma unroll
    for (int k = 0; k < 16; k++) s += ev[k] * sW[k*16+c];
    h0[n*16+c] = s;
  }
}

// ---------------------------------------------------------------------------
// Forward block 0, row-centric gather. 16 lanes per node (one per channel).
// ---------------------------------------------------------------------------
__global__ void k_fwd_b0(const int* __restrict__ ei, int E,
                         const float* __restrict__ Wr, const float* __restrict__ br,
                         const float* __restrict__ h0_in, const float4* __restrict__ geo,
                         const int* __restrict__ start_row, const int* __restrict__ deg_row,
                         const int* __restrict__ eid_row,
                         float* __restrict__ a0, float* __restrict__ a1, float* __restrict__ a2,
                         int N)
{
  int n = blockIdx.x * (blockDim.x >> 4) + (threadIdx.x >> 4);
  int c = threadIdx.x & 15;
  if (n >= N) return;
  float wr0[8], wr1[8], wr2[8];
  #pragma unroll
  for (int k = 0; k < 8; k++) {
    wr0[k] = Wr[k*80 + c];
    wr1[k] = Wr[k*80 + 16 + c];
    wr2[k] = Wr[k*80 + 32 + c];
  }
  float b0v = br[c], b1v = br[16 + c], b2v = br[32 + c];

  float acc0 = 0.f, acc1[3] = {0.f,0.f,0.f}, acc2[5] = {0.f,0.f,0.f,0.f,0.f};

  int i0 = start_row[n], i1 = i0 + deg_row[n];
  float4 G0n = {0,0,0,0}, G1n = {0,0,0,0}, G4n = {0,0,0,0};
  float h0n = 0.f;
  if (i0 < i1) {
    int e = eid_row[i0]; int col = ei[E + e];
    G0n = geo[e*5+0]; G1n = geo[e*5+1]; G4n = geo[e*5+4];
    h0n = h0_in[col*16 + c];
  }
  for (int i = i0; i < i1; i++) {
    float4 G0 = G0n, G1 = G1n, G4 = G4n;
    float h0c = h0n;
    if (i+1 < i1) {
      int e = eid_row[i+1]; int col = ei[E + e];
      G0n = geo[e*5+0]; G1n = geo[e*5+1]; G4n = geo[e*5+4];
      h0n = h0_in[col*16 + c];
    }
    float rad[8] = {G0.x,G0.y,G0.z,G0.w,G1.x,G1.y,G1.z,G1.w};
    float sh1[3], sh2[5];
    sh_from_u(G4.x, G4.y, G4.z, sh1, sh2);
    float w0 = b0v, w1 = b1v, w2 = b2v;
    #pragma unroll
    for (int k = 0; k < 8; k++) {
      w0 += rad[k]*wr0[k]; w1 += rad[k]*wr1[k]; w2 += rad[k]*wr2[k];
    }
    acc0 += w0*h0c;
    float wh1 = w1*h0c, wh2 = w2*h0c;
    #pragma unroll
    for (int m = 0; m < 3; m++) acc1[m] += wh1*sh1[m];
    #pragma unroll
    for (int m = 0; m < 5; m++) acc2[m] += wh2*sh2[m];
  }
  a0[n*16 + c] = acc0;
  #pragma unroll
  for (int m = 0; m < 3; m++) a1[n*48 + c*3 + m] = acc1[m];
  #pragma unroll
  for (int m = 0; m < 5; m++) a2[n*80 + c*5 + m] = acc2[m];
}

// ---------------------------------------------------------------------------
// Forward block 1 (last): a0 += w0*h0c + w3*S1 + w4*S2
// ---------------------------------------------------------------------------
__global__ void k_fwd_b1(const int* __restrict__ ei, int E,
                         const float* __restrict__ Wr, const float* __restrict__ br,
                         const float* __restrict__ h0_in, const float* __restrict__ h1_in,
                         const float* __restrict__ h2_in, const float4* __restrict__ geo,
                         const int* __restrict__ start_row, const int* __restrict__ deg_row,
                         const int* __restrict__ eid_row,
                         float* __restrict__ a0, int N)
{
  int n = blockIdx.x * (blockDim.x >> 4) + (threadIdx.x >> 4);
  int c = threadIdx.x & 15;
  if (n >= N) return;
  float wr0[8], wr3[8], wr4[8];
  #pragma unroll
  for (int k = 0; k < 8; k++) {
    wr0[k] = Wr[k*80 + c];
    wr3[k] = Wr[k*80 + 48 + c];
    wr4[k] = Wr[k*80 + 64 + c];
  }
  float b0v = br[c], b3v = br[48 + c], b4v = br[64 + c];

  float acc0 = 0.f;
  int i0 = start_row[n], i1 = i0 + deg_row[n];
  float4 G0n = {0,0,0,0}, G1n = {0,0,0,0}, G4n = {0,0,0,0};
  float h0n = 0.f, h1n[3] = {0,0,0}, h2n[5] = {0,0,0,0,0};
  if (i0 < i1) {
    int e = eid_row[i0]; int col = ei[E + e];
    G0n = geo[e*5+0]; G1n = geo[e*5+1]; G4n = geo[e*5+4];
    h0n = h0_in[col*16 + c];
    #pragma unroll
    for (int m = 0; m < 3; m++) h1n[m] = h1_in[col*48 + c*3 + m];
    #pragma unroll
    for (int m = 0; m < 5; m++) h2n[m] = h2_in[col*80 + c*5 + m];
  }
  for (int i = i0; i < i1; i++) {
    float4 G0 = G0n, G1 = G1n, G4 = G4n;
    float h0c = h0n;
    float h1c[3], h2c[5];
    #pragma unroll
    for (int m = 0; m < 3; m++) h1c[m] = h1n[m];
    #pragma unroll
    for (int m = 0; m < 5; m++) h2c[m] = h2n[m];
    if (i+1 < i1) {
      int e = eid_row[i+1]; int col = ei[E + e];
      G0n = geo[e*5+0]; G1n = geo[e*5+1]; G4n = geo[e*5+4];
      h0n = h0_in[col*16 + c];
      #pragma unroll
      for (int m = 0; m < 3; m++) h1n[m] = h1_in[col*48 + c*3 + m];
      #pragma unroll
      for (int m = 0; m < 5; m++) h2n[m] = h2_in[col*80 + c*5 + m];
    }
    float rad[8] = {G0.x,G0.y,G0.z,G0.w,G1.x,G1.y,G1.z,G1.w};
    float sh1[3], sh2[5];
    sh_from_u(G4.x, G4.y, G4.z, sh1, sh2);
    float w0 = b0v, w3 = b3v, w4 = b4v;
    #pragma unroll
    for (int k = 0; k < 8; k++) {
      w0 += rad[k]*wr0[k]; w3 += rad[k]*wr3[k]; w4 += rad[k]*wr4[k];
    }
    float S1 = 0.f, S2 = 0.f;
    #pragma unroll
    for (int m = 0; m < 3; m++) S1 += h1c[m]*sh1[m];
    #pragma unroll
    for (int m = 0; m < 5; m++) S2 += h2c[m]*sh2[m];
    acc0 += w0*h0c + w3*S1 + w4*S2;
  }
  a0[n*16 + c] = acc0;
}

// ---------------------------------------------------------------------------
// Node update: h_out = h_in + a @ U
// ---------------------------------------------------------------------------
__global__ void k_node_update(const float* __restrict__ h0_in,
                              const float* __restrict__ a0, const float* __restrict__ a1,
                              const float* __restrict__ a2,
                              const float* __restrict__ U,
                              float* __restrict__ h0_out, float* __restrict__ h1_out,
                              float* __restrict__ h2_out, int N, int full)
{
  int idx = blockIdx.x * blockDim.x + threadIdx.x;
  int n = idx >> 4, d = idx & 15;
  if (n >= N) return;
  const float* U0 = U;
  const float* U1 = U + 256;
  const float* U2 = U + 512;
  float s = h0_in[n*16 + d];
  #pragma unroll
  for (int c = 0; c < 16; c++) s += a0[n*16 + c] * U0[c*16 + d];
  h0_out[n*16 + d] = s;
  if (full) {
    float v1[3] = {0.f, 0.f, 0.f};
    #pragma unroll
    for (int c = 0; c < 16; c++) {
      float u = U1[c*16 + d];
      #pragma unroll
      for (int m = 0; m < 3; m++) v1[m] += a1[n*48 + c*3 + m] * u;
    }
    #pragma unroll
    for (int m = 0; m < 3; m++) h1_out[n*48 + d*3 + m] = v1[m];
    float v2[5] = {0.f, 0.f, 0.f, 0.f, 0.f};
    #pragma unroll
    for (int c = 0; c < 16; c++) {
      float u = U2[c*16 + d];
      #pragma unroll
      for (int m = 0; m < 5; m++) v2[m] += a2[n*80 + c*5 + m] * u;
    }
    #pragma unroll
    for (int m = 0; m < 5; m++) h2_out[n*80 + d*5 + m] = v2[m];
  }
}

// ---------------------------------------------------------------------------
// Readout fwd + bwd fused
// ---------------------------------------------------------------------------
__global__ void k_readout_bwd(const float* __restrict__ h0, const float* __restrict__ W_read,
                              const float* __restrict__ W1, const float* __restrict__ b1,
                              const float* __restrict__ W2, const float* __restrict__ b2,
                              float* __restrict__ g0, float* __restrict__ energy, int N)
{
  int n = blockIdx.x * blockDim.x + threadIdx.x;
  float site = 0.f;
  if (n < N) {
    float h[16], inv[16], dt[16];
    #pragma unroll
    for (int d = 0; d < 16; d++) h[d] = h0[n*16 + d];
    #pragma unroll
    for (int j = 0; j < 16; j++) {
      float s = 0.f;
      #pragma unroll
      for (int d = 0; d < 16; d++) s += h[d] * W_read[d*16 + j];
      inv[j] = s;
    }
    site = b2[0];
    #pragma unroll
    for (int c = 0; c < 16; c++) {
      float t = b1[c];
      #pragma unroll
      for (int j = 0; j < 16; j++) t += inv[j] * W1[j*16 + c];
      float sg = 1.f / (1.f + expf(-t));
      float w2v = W2[c];
      site += t * sg * w2v;
      dt[c] = w2v * sg * (1.f + t * (1.f - sg));
    }
    float dinv[16];
    #pragma unroll
    for (int j = 0; j < 16; j++) {
      float s = 0.f;
      #pragma unroll
      for (int c = 0; c < 16; c++) s += dt[c] * W1[j*16 + c];
      dinv[j] = s;
    }
    #pragma unroll
    for (int d = 0; d < 16; d++) {
      float s = 0.f;
      #pragma unroll
      for (int j = 0; j < 16; j++) s += dinv[j] * W_read[d*16 + j];
      g0[n*16 + d] = s;
    }
  }
  #pragma unroll
  for (int off = 32; off; off >>= 1) site += __shfl_down(site, off, 64);
  if ((threadIdx.x & 63) == 0) atomicAdd(energy, site);
}

// ---------------------------------------------------------------------------
// ga = g @ U^T
// ---------------------------------------------------------------------------
__global__ void k_ga(const float* __restrict__ g0, const float* __restrict__ g1,
                     const float* __restrict__ g2, const float* __restrict__ U,
                     float* __restrict__ ga0, float* __restrict__ ga1, float* __restrict__ ga2,
                     int N, int full)
{
  int idx = blockIdx.x * blockDim.x + threadIdx.x;
  int n = idx >> 4, c = idx & 15;
  if (n >= N) return;
  const float* U0 = U;
  const float* U1 = U + 256;
  const float* U2 = U + 512;
  float s = 0.f;
  #pragma unroll
  for (int d = 0; d < 16; d++) s += g0[n*16 + d] * U0[c*16 + d];
  ga0[n*16 + c] = s;
  if (full) {
    float v1[3] = {0.f, 0.f, 0.f};
    #pragma unroll
    for (int d = 0; d < 16; d++) {
      float u = U1[c*16 + d];
      #pragma unroll
      for (int m = 0; m < 3; m++) v1[m] += g1[n*48 + d*3 + m] * u;
    }
    #pragma unroll
    for (int m = 0; m < 3; m++) ga1[n*48 + c*3 + m] = v1[m];
    float v2[5] = {0.f, 0.f, 0.f, 0.f, 0.f};
    #pragma unroll
    for (int d = 0; d < 16; d++) {
      float u = U2[c*16 + d];
      #pragma unroll
      for (int m = 0; m < 5; m++) v2[m] += g2[n*80 + d*5 + m] * u;
    }
    #pragma unroll
    for (int m = 0; m < 5; m++) ga2[n*80 + c*5 + m] = v2[m];
  }
}

// ---------------------------------------------------------------------------
// Backward block 1, col-centric.
// ---------------------------------------------------------------------------
__global__ void k_bwd_b1_col(const int* __restrict__ ei, int E,
                             const float* __restrict__ Wr, const float* __restrict__ br,
                             const float* __restrict__ h0_in, const float* __restrict__ h1_in,
                             const float* __restrict__ h2_in,
                             const float* __restrict__ ga0, const float4* __restrict__ geo,
                             const int* __restrict__ start_col, const int* __restrict__ deg_col,
                             const int* __restrict__ eid_col,
                             float* __restrict__ g0, float* __restrict__ g1, float* __restrict__ g2,
                             float* __restrict__ dv_buf, int N)
{
  int n = blockIdx.x * (blockDim.x >> 4) + (threadIdx.x >> 4);
  int c = threadIdx.x & 15;
  if (n >= N) return;
  float wr0[8], wr3[8], wr4[8];
  #pragma unroll
  for (int k = 0; k < 8; k++) {
    wr0[k] = Wr[k*80 + c];
    wr3[k] = Wr[k*80 + 48 + c];
    wr4[k] = Wr[k*80 + 64 + c];
  }
  float b0v = br[c], b3v = br[48 + c], b4v = br[64 + c];

  float h0c = h0_in[n*16 + c];
  float h1c[3], h2c[5];
  #pragma unroll
  for (int m = 0; m < 3; m++) h1c[m] = h1_in[n*48 + c*3 + m];
  #pragma unroll
  for (int m = 0; m < 5; m++) h2c[m] = h2_in[n*80 + c*5 + m];

  float accg0 = 0.f, accg1[3] = {0.f,0.f,0.f}, accg2[5] = {0.f,0.f,0.f,0.f,0.f};

  int i0 = start_col[n], i1 = i0 + deg_col[n];
  int e_n = 0;
  float4 G0n = {0,0,0,0}, G1n = {0,0,0,0}, G2n = {0,0,0,0}, G3n = {0,0,0,0}, G4n = {0,0,0,0};
  float dm0n = 0.f;
  if (i0 < i1) {
    e_n = eid_col[i0]; int row = ei[e_n];
    G0n = geo[e_n*5+0]; G1n = geo[e_n*5+1]; G2n = geo[e_n*5+2];
    G3n = geo[e_n*5+3]; G4n = geo[e_n*5+4];
    dm0n = ga0[row*16 + c];
  }
  for (int i = i0; i < i1; i++) {
    int e = e_n;
    float4 G0 = G0n, G1 = G1n, G2 = G2n, G3 = G3n, G4 = G4n;
    float dm0 = dm0n;
    if (i+1 < i1) {
      e_n = eid_col[i+1]; int row = ei[e_n];
      G0n = geo[e_n*5+0]; G1n = geo[e_n*5+1]; G2n = geo[e_n*5+2];
      G3n = geo[e_n*5+3]; G4n = geo[e_n*5+4];
      dm0n = ga0[row*16 + c];
    }
    float rad[8]    = {G0.x,G0.y,G0.z,G0.w,G1.x,G1.y,G1.z,G1.w};
    float draddr[8] = {G2.x,G2.y,G2.z,G2.w,G3.x,G3.y,G3.z,G3.w};
    float ux = G4.x, uy = G4.y, uz = G4.z, inv_r = G4.w;
    float sh1[3], sh2[5];
    sh_from_u(ux, uy, uz, sh1, sh2);

    float w0 = b0v, w3 = b3v, w4 = b4v;
    #pragma unroll
    for (int k = 0; k < 8; k++) {
      w0 += rad[k]*wr0[k]; w3 += rad[k]*wr3[k]; w4 += rad[k]*wr4[k];
    }

    float S1 = 0.f, S2 = 0.f;
    #pragma unroll
    for (int m = 0; m < 3; m++) S1 += h1c[m]*sh1[m];
    #pragma unroll
    for (int m = 0; m < 5; m++) S2 += h2c[m]*sh2[m];

    float dw0 = dm0 * h0c;
    float dw3 = dm0 * S1;
    float dw4 = dm0 * S2;
    float t3 = dm0 * w3, t4 = dm0 * w4;

    accg0 += dm0 * w0;
    #pragma unroll
    for (int m = 0; m < 3; m++) accg1[m] += t3 * sh1[m];
    #pragma unroll
    for (int m = 0; m < 5; m++) accg2[m] += t4 * sh2[m];

    float q1x = t3*h1c[0], q1y = t3*h1c[1], q1z = t3*h1c[2];
    float q0 = t4*h2c[0], q1 = t4*h2c[1], q2 = t4*h2c[2], q3 = t4*h2c[3], q4 = t4*h2c[4];
    float gr = 0.f;
    #pragma unroll
    for (int k = 0; k < 8; k++)
      gr += (dw0*wr0[k] + dw3*wr3[k] + dw4*wr4[k]) * draddr[k];
    float gux = SQRT3f*q1x + SQRT15f*(uy*q0 + uz*q3 + ux*q4);
    float guy = SQRT3f*q1y + SQRT15f*(ux*q0 + uz*q1 - uy*q4);
    float guz = SQRT3f*q1z + SQRT15f*uy*q1 + 3.f*SQRT5f*uz*q2 + SQRT15f*ux*q3;

    gr  = grp16_sum(gr);
    gux = grp16_sum(gux);
    guy = grp16_sum(guy);
    guz = grp16_sum(guz);

    if (c == 0) {
      float gdotu = gux*ux + guy*uy + guz*uz;
      dv_buf[e*3+0] = gr*ux + (gux - gdotu*ux)*inv_r;
      dv_buf[e*3+1] = gr*uy + (guy - gdotu*uy)*inv_r;
      dv_buf[e*3+2] = gr*uz + (guz - gdotu*uz)*inv_r;
    }
  }
  g0[n*16 + c] += accg0;
  #pragma unroll
  for (int m = 0; m < 3; m++) g1[n*48 + c*3 + m] = accg1[m];
  #pragma unroll
  for (int m = 0; m < 5; m++) g2[n*80 + c*5 + m] = accg2[m];
}

// ---------------------------------------------------------------------------
// Backward block 0, ROW-centric.
// ---------------------------------------------------------------------------
__global__ void k_bwd_b0_row(const int* __restrict__ ei, int E,
                             const float* __restrict__ Wr, const float* __restrict__ br,
                             const float* __restrict__ h0_in,
                             const float* __restrict__ ga0, const float* __restrict__ ga1,
                             const float* __restrict__ ga2, const float4* __restrict__ geo,
                             const int* __restrict__ start_row, const int* __restrict__ deg_row,
                             const int* __restrict__ eid_row,
                             float* __restrict__ dv_buf, int N)
{
  int n = blockIdx.x * (blockDim.x >> 4) + (threadIdx.x >> 4);
  int c = threadIdx.x & 15;
  if (n >= N) return;
  float wr0[8], wr1[8], wr2[8];
  #pragma unroll
  for (int k = 0; k < 8; k++) {
    wr0[k] = Wr[k*80 + c];
    wr1[k] = Wr[k*80 + 16 + c];
    wr2[k] = Wr[k*80 + 32 + c];
  }
  float b1v = br[16 + c], b2v = br[32 + c];

  float dm0 = ga0[n*16 + c];
  float dm1[3], dm2[5];
  #pragma unroll
  for (int m = 0; m < 3; m++) dm1[m] = ga1[n*48 + c*3 + m];
  #pragma unroll
  for (int m = 0; m < 5; m++) dm2[m] = ga2[n*80 + c*5 + m];

  int i0 = start_row[n], i1 = i0 + deg_row[n];
  int e_n = 0;
  float4 G0n = {0,0,0,0}, G1n = {0,0,0,0}, G2n = {0,0,0,0}, G3n = {0,0,0,0}, G4n = {0,0,0,0};
  float h0n = 0.f;
  if (i0 < i1) {
    e_n = eid_row[i0]; int col = ei[E + e_n];
    G0n = geo[e_n*5+0]; G1n = geo[e_n*5+1]; G2n = geo[e_n*5+2];
    G3n = geo[e_n*5+3]; G4n = geo[e_n*5+4];
    h0n = h0_in[col*16 + c];
  }
  for (int i = i0; i < i1; i++) {
    int e = e_n;
    float4 G0 = G0n, G1 = G1n, G2 = G2n, G3 = G3n, G4 = G4n;
    float h0c = h0n;
    if (i+1 < i1) {
      e_n = eid_row[i+1]; int col = ei[E + e_n];
      G0n = geo[e_n*5+0]; G1n = geo[e_n*5+1]; G2n = geo[e_n*5+2];
      G3n = geo[e_n*5+3]; G4n = geo[e_n*5+4];
      h0n = h0_in[col*16 + c];
    }
    float rad[8]    = {G0.x,G0.y,G0.z,G0.w,G1.x,G1.y,G1.z,G1.w};
    float draddr[8] = {G2.x,G2.y,G2.z,G2.w,G3.x,G3.y,G3.z,G3.w};
    float ux = G4.x, uy = G4.y, uz = G4.z, inv_r = G4.w;
    float sh1[3], sh2[5];
    sh_from_u(ux, uy, uz, sh1, sh2);

    float w1 = b1v, w2v = b2v;
    #pragma unroll
    for (int k = 0; k < 8; k++) { w1 += rad[k]*wr1[k]; w2v += rad[k]*wr2[k]; }

    float T1 = 0.f, T2 = 0.f;
    #pragma unroll
    for (int m = 0; m < 3; m++) T1 += dm1[m]*sh1[m];
    #pragma unroll
    for (int m = 0; m < 5; m++) T2 += dm2[m]*sh2[m];

    float dw0 = dm0 * h0c;
    float dw1 = h0c * T1;
    float dw2 = h0c * T2;

    float w1h = w1*h0c, w2h = w2v*h0c;
    float q1x = dm1[0]*w1h, q1y = dm1[1]*w1h, q1z = dm1[2]*w1h;
    float q0 = dm2[0]*w2h, q1 = dm2[1]*w2h, q2 = dm2[2]*w2h, q3 = dm2[3]*w2h, q4 = dm2[4]*w2h;

    float gr = 0.f;
    #pragma unroll
    for (int k = 0; k < 8; k++)
      gr += (dw0*wr0[k] + dw1*wr1[k] + dw2*wr2[k]) * draddr[k];
    float gux = SQRT3f*q1x + SQRT15f*(uy*q0 + uz*q3 + ux*q4);
    float guy = SQRT3f*q1y + SQRT15f*(ux*q0 + uz*q1 - uy*q4);
    float guz = SQRT3f*q1z + SQRT15f*uy*q1 + 3.f*SQRT5f*uz*q2 + SQRT15f*ux*q3;

    gr  = grp16_sum(gr);
    gux = grp16_sum(gux);
    guy = grp16_sum(guy);
    guz = grp16_sum(guz);

    if (c == 0) {
      float gdotu = gux*ux + guy*uy + guz*uz;
      dv_buf[e*3+0] += gr*ux + (gux - gdotu*ux)*inv_r;
      dv_buf[e*3+1] += gr*uy + (guy - gdotu*uy)*inv_r;
      dv_buf[e*3+2] += gr*uz + (guz - gdotu*uz)*inv_r;
    }
  }
}

// ---------------------------------------------------------------------------
// Force assembly: force[n] = sum_{col==n} dv - sum_{row==n} dv
// ---------------------------------------------------------------------------
__global__ void k_force(const int* __restrict__ start_row, const int* __restrict__ deg_row,
                        const int* __restrict__ eid_row,
                        const int* __restrict__ start_col, const int* __restrict__ deg_col,
                        const int* __restrict__ eid_col,
                        const float* __restrict__ dv, float* __restrict__ force, int N)
{
  int n = blockIdx.x * blockDim.x + threadIdx.x;
  if (n >= N) return;
  float fx = 0.f, fy = 0.f, fz = 0.f;
  int c0 = start_col[n], c1 = c0 + deg_col[n];
  for (int i = c0; i < c1; i++) {
    int e = eid_col[i];
    fx += dv[e*3+0]; fy += dv[e*3+1]; fz += dv[e*3+2];
  }
  int r0 = start_row[n], r1 = r0 + deg_row[n];
  for (int i = r0; i < r1; i++) {
    int e = eid_row[i];
    fx -= dv[e*3+0]; fy -= dv[e*3+1]; fz -= dv[e*3+2];
  }
  force[n*3+0] = fx; force[n*3+1] = fy; force[n*3+2] = fz;
}

// ---------------------------------------------------------------------------
extern "C" void kernel_launch(void* const* d_in, const int* in_sizes, int n_in,
                              void* d_out, int out_size, void* d_ws, size_t ws_size,
                              hipStream_t stream)
{
  const float* pos    = (const float*)d_in[0];
  const int*   z      = (const int*)  d_in[1];
  const int*   ei     = (const int*)  d_in[2];
  const float* emb    = (const float*)d_in[3];
  const float* W_init = (const float*)d_in[4];
  const float* Wr     = (const float*)d_in[5];   // (2, 8, 80)
  const float* br     = (const float*)d_in[6];   // (2, 80)
  const float* W_out  = (const float*)d_in[7];   // (2, 3, 16, 16)
  const float* W_read = (const float*)d_in[8];
  const float* W1     = (const float*)d_in[9];
  const float* b1     = (const float*)d_in[10];
  const float* W2     = (const float*)d_in[11];
  const float* b2     = (const float*)d_in[12];

  const int N = in_sizes[0] / 3;
  const int E = in_sizes[2] / 2;

  float* f = (float*)d_ws;
  float* geo_f = f; f += (size_t)E*20;   // float4-aligned (d_ws base is aligned)
  float* h0_s0 = f; f += (size_t)N*16;
  float* h0_s1 = f; f += (size_t)N*16;
  float* h0_s2 = f; f += (size_t)N*16;
  float* h1_s1 = f; f += (size_t)N*48;
  float* h2_s1 = f; f += (size_t)N*80;
  float* a0    = f; f += (size_t)N*16;   // also ga0
  float* a1    = f; f += (size_t)N*48;   // also ga1
  float* a2    = f; f += (size_t)N*80;   // also ga2
  float* g0    = f; f += (size_t)N*16;
  float* g1    = f; f += (size_t)N*48;
  float* g2    = f; f += (size_t)N*80;
  float* dv    = f; f += (size_t)E*3;
  int* ip = (int*)f;
  int* cursors   = ip; ip += 2;          // cursors+deg contiguous -> one memset
  int* deg_row   = ip; ip += N;
  int* deg_col   = ip; ip += N;
  int* start_row = ip; ip += N;
  int* start_col = ip; ip += N;
  int* cur_row   = ip; ip += N;
  int* cur_col   = ip; ip += N;
  int* eid_row   = ip; ip += E;
  int* eid_col   = ip; ip += E;

  float4* geo = (float4*)geo_f;

  float* out    = (float*)d_out;
  float* energy = out;
  float* force  = out + 1;

  const int BLK = 256;
  const int GPB = BLK / 16;  // 16-lane groups per block

  (void)hipMemsetAsync(energy, 0, sizeof(float), stream);
  (void)hipMemsetAsync(cursors, 0, (size_t)(2 + 2*N) * sizeof(int), stream);

  // ---- CSR build (scan-free) + geometry precompute ----
  k_geom_hist<<<cdiv(E, BLK), BLK, 0, stream>>>(pos, ei, E, geo, deg_row, deg_col);
  k_alloc<<<cdiv(N, BLK), BLK, 0, stream>>>(deg_row, deg_col, start_row, cur_row,
                                            start_col, cur_col, cursors, N);
  k_scatter<<<cdiv(E, BLK), BLK, 0, stream>>>(ei, E, cur_row, cur_col, eid_row, eid_col);

  k_node_init<<<cdiv(N, BLK), BLK, 0, stream>>>(emb, z, W_init, h0_s0, N);

  // ---- forward block 0 ----
  k_fwd_b0<<<cdiv(N, GPB), BLK, 0, stream>>>(ei, E, Wr, br, h0_s0, geo,
                                             start_row, deg_row, eid_row, a0, a1, a2, N);
  k_node_update<<<cdiv(N*16, BLK), BLK, 0, stream>>>(h0_s0, a0, a1, a2,
                                                     W_out, h0_s1, h1_s1, h2_s1, N, 1);

  // ---- forward block 1 (only h0 path live) ----
  k_fwd_b1<<<cdiv(N, GPB), BLK, 0, stream>>>(ei, E, Wr + 640, br + 80,
                                             h0_s1, h1_s1, h2_s1, geo,
                                             start_row, deg_row, eid_row, a0, N);
  k_node_update<<<cdiv(N*16, BLK), BLK, 0, stream>>>(h0_s1, a0, nullptr, nullptr,
                                                     W_out + 768, h0_s2, nullptr, nullptr, N, 0);

  // ---- readout fwd + bwd ----
  k_readout_bwd<<<cdiv(N, BLK), BLK, 0, stream>>>(h0_s2, W_read, W1, b1, W2, b2, g0, energy, N);

  // ---- backward block 1 ----
  k_ga<<<cdiv(N*16, BLK), BLK, 0, stream>>>(g0, nullptr, nullptr, W_out + 768,
                                            a0, nullptr, nullptr, N, 0);
  k_bwd_b1_col<<<cdiv(N, GPB), BLK, 0, stream>>>(ei, E, Wr + 640, br + 80,
                                                 h0_s1, h1_s1, h2_s1, a0, geo,
                                                 start_col, deg_col, eid_col,
                                                 g0, g1, g2, dv, N);

  // ---- backward block 0 ----
  k_ga<<<cdiv(N*16, BLK), BLK, 0, stream>>>(g0, g1, g2, W_out, a0, a1, a2, N, 1);
  k_bwd_b0_row<<<cdiv(N, GPB), BLK, 0, stream>>>(ei, E, Wr, br, h0_s0,
                                                 a0, a1, a2, geo,
                                                 start_row, deg_row, eid_row, dv, N);

  // ---- force assembly ----
  k_force<<<cdiv(N, BLK), BLK, 0, stream>>>(start_row, deg_row, eid_row,
                                            start_col, deg_col, eid_col, dv, force, N);
}

// Round 8
// 555.691 us; speedup vs baseline: 4.2418x; 1.1273x over previous
//
#include <hip/hip_runtime.h>
#include <math.h>

#ifndef M_PI
#define M_PI 3.14159265358979323846
#endif

static inline int cdiv(int a, int b){ return (a + b - 1) / b; }

#define SQRT3f  1.7320508075688772f
#define SQRT5f  2.23606797749979f
#define SQRT15f 3.872983346207417f
#define KRADf   0.6324555320336759f      /* sqrt(2/R_MAX), R_MAX=5 */
#define PI5f    0.6283185307179586f      /* pi/5 */

__device__ __forceinline__ float grp16_sum(float v){
  v += __shfl_xor(v, 1, 64);
  v += __shfl_xor(v, 2, 64);
  v += __shfl_xor(v, 4, 64);
  v += __shfl_xor(v, 8, 64);
  return v;
}

// sh from unit vector (8 ops)
__device__ __forceinline__ void sh_from_u(float ux, float uy, float uz,
                                          float* sh1, float* sh2)
{
  sh1[0] = SQRT3f*ux; sh1[1] = SQRT3f*uy; sh1[2] = SQRT3f*uz;
  sh2[0] = SQRT15f*ux*uy;
  sh2[1] = SQRT15f*uy*uz;
  sh2[2] = 0.5f*SQRT5f*(3.f*uz*uz - 1.f);
  sh2[3] = SQRT15f*ux*uz;
  sh2[4] = 0.5f*SQRT15f*(ux*ux - uy*uy);
}

// ---------------------------------------------------------------------------
// Degree histogram (E-parallel)
// ---------------------------------------------------------------------------
__global__ void k_hist(const int* __restrict__ ei, int E,
                       int* __restrict__ deg_row, int* __restrict__ deg_col)
{
  int e = blockIdx.x * blockDim.x + threadIdx.x;
  if (e >= E) return;
  atomicAdd(&deg_row[ei[e]], 1);
  atomicAdd(&deg_col[ei[E + e]], 1);
}

// ---------------------------------------------------------------------------
// Scan-free segment allocation: wave-aggregated atomicAdd on global cursors.
// Segment bases need not be in node order.
// ---------------------------------------------------------------------------
__global__ void k_alloc(const int* __restrict__ deg_row, const int* __restrict__ deg_col,
                        int* __restrict__ start_row, int* __restrict__ cur_row,
                        int* __restrict__ start_col, int* __restrict__ cur_col,
                        int* __restrict__ cursors, int N)
{
  int idx = blockIdx.x * blockDim.x + threadIdx.x;
  int lane = threadIdx.x & 63;
  #pragma unroll
  for (int which = 0; which < 2; which++) {
    const int* deg = which ? deg_col : deg_row;
    int* start = which ? start_col : start_row;
    int* cur   = which ? cur_col   : cur_row;
    int v = (idx < N) ? deg[idx] : 0;
    int incl = v;
    #pragma unroll
    for (int d = 1; d < 64; d <<= 1) {
      int y = __shfl_up(incl, d, 64);
      if (lane >= d) incl += y;
    }
    int wtot = __shfl(incl, 63, 64);
    int base = 0;
    if (lane == 63) base = atomicAdd(&cursors[which], wtot);
    base = __shfl(base, 63, 64);
    if (idx < N) { int st = base + incl - v; start[idx] = st; cur[idx] = st; }
  }
}

// ---------------------------------------------------------------------------
// Scatter + geometry, CSR-ordered: compute per-edge geometry ONCE and write it
// directly at the edge's row-CSR position. Also store col index, the edge's
// col-CSR position (cposR), and for the col ordering: row index + row-CSR
// position (rowC/rposC). Hot loops then stream contiguously — no eid/ei
// indirection chain.
// geoR[i*5+0]=rad[0..3], +1=rad[4..7], +2=draddr[0..3], +3=draddr[4..7],
// +4=(ux,uy,uz,inv_r).
// ---------------------------------------------------------------------------
__global__ void k_scatter_geom(const float* __restrict__ pos, const int* __restrict__ ei, int E,
                               int* __restrict__ cur_row, int* __restrict__ cur_col,
                               float4* __restrict__ geoR,
                               int* __restrict__ colR, int* __restrict__ cposR,
                               int* __restrict__ rowC, int* __restrict__ rposC)
{
  int e = blockIdx.x * blockDim.x + threadIdx.x;
  if (e >= E) return;
  int row = ei[e], col = ei[E + e];
  int pr = atomicAdd(&cur_row[row], 1);
  int pc = atomicAdd(&cur_col[col], 1);
  colR[pr] = col; cposR[pr] = pc;
  rowC[pc] = row; rposC[pc] = pr;

  float px = pos[row*3+0] - pos[col*3+0];
  float py = pos[row*3+1] - pos[col*3+1];
  float pz = pos[row*3+2] - pos[col*3+2];
  float r2 = px*px + py*py + pz*pz + 1e-12f;
  float r = sqrtf(r2);
  float inv_r = 1.0f / r;
  float ux = px*inv_r, uy = py*inv_r, uz = pz*inv_r;
  float x = r * PI5f;
  float s1, c1;
  sincosf(x, &s1, &c1);
  float tc = 2.f * c1;
  float sprev = 0.f, s = s1, cprev = 1.f, cc = c1;
  float Ki = KRADf * inv_r;
  float rad[8], draddr[8];
  const float KPI5 = KRADf * PI5f;
  #pragma unroll
  for (int k = 0; k < 8; k++) {
    rad[k] = Ki * s;
    draddr[k] = (KPI5 * (float)(k+1) * cc - rad[k]) * inv_r;
    float sn = tc*s - sprev; sprev = s; s = sn;
    float cn = tc*cc - cprev; cprev = cc; cc = cn;
  }
  geoR[pr*5+0] = make_float4(rad[0], rad[1], rad[2], rad[3]);
  geoR[pr*5+1] = make_float4(rad[4], rad[5], rad[6], rad[7]);
  geoR[pr*5+2] = make_float4(draddr[0], draddr[1], draddr[2], draddr[3]);
  geoR[pr*5+3] = make_float4(draddr[4], draddr[5], draddr[6], draddr[7]);
  geoR[pr*5+4] = make_float4(ux, uy, uz, inv_r);
}

// ---------------------------------------------------------------------------
// h0_init[n,:] = emb[z[n],:] @ W_init
// ---------------------------------------------------------------------------
__global__ void k_node_init(const float* __restrict__ emb, const int* __restrict__ z,
                            const float* __restrict__ W_init, float* __restrict__ h0, int N)
{
  __shared__ float sW[256];
  if (threadIdx.x < 256) sW[threadIdx.x] = W_init[threadIdx.x];
  __syncthreads();
  int n = blockIdx.x * blockDim.x + threadIdx.x;
  if (n >= N) return;
  const float* e = emb + z[n]*16;
  float ev[16];
  #pragma unroll
  for (int k = 0; k < 16; k++) ev[k] = e[k];
  #pragma unroll
  for (int c = 0; c < 16; c++) {
    float s = 0.f;
    #pragma unroll
    for (int k = 0; k < 16; k++) s += ev[k] * sW[k*16+c];
    h0[n*16+c] = s;
  }
}

// ---------------------------------------------------------------------------
// Forward block 0, row-centric gather: streams geoR/colR, gathers h0[col].
// ---------------------------------------------------------------------------
__global__ void k_fwd_b0(const float* __restrict__ Wr, const float* __restrict__ br,
                         const float* __restrict__ h0_in, const float4* __restrict__ geoR,
                         const int* __restrict__ colR,
                         const int* __restrict__ start_row, const int* __restrict__ deg_row,
                         float* __restrict__ a0, float* __restrict__ a1, float* __restrict__ a2,
                         int N)
{
  int n = blockIdx.x * (blockDim.x >> 4) + (threadIdx.x >> 4);
  int c = threadIdx.x & 15;
  if (n >= N) return;
  float wr0[8], wr1[8], wr2[8];
  #pragma unroll
  for (int k = 0; k < 8; k++) {
    wr0[k] = Wr[k*80 + c];
    wr1[k] = Wr[k*80 + 16 + c];
    wr2[k] = Wr[k*80 + 32 + c];
  }
  float b0v = br[c], b1v = br[16 + c], b2v = br[32 + c];

  float acc0 = 0.f, acc1[3] = {0.f,0.f,0.f}, acc2[5] = {0.f,0.f,0.f,0.f,0.f};

  int i0 = start_row[n], i1 = i0 + deg_row[n];
  float4 G0n = {0,0,0,0}, G1n = {0,0,0,0}, G4n = {0,0,0,0};
  float h0n = 0.f;
  if (i0 < i1) {
    G0n = geoR[i0*5+0]; G1n = geoR[i0*5+1]; G4n = geoR[i0*5+4];
    h0n = h0_in[colR[i0]*16 + c];
  }
  for (int i = i0; i < i1; i++) {
    float4 G0 = G0n, G1 = G1n, G4 = G4n;
    float h0c = h0n;
    if (i+1 < i1) {
      G0n = geoR[(i+1)*5+0]; G1n = geoR[(i+1)*5+1]; G4n = geoR[(i+1)*5+4];
      h0n = h0_in[colR[i+1]*16 + c];
    }
    float rad[8] = {G0.x,G0.y,G0.z,G0.w,G1.x,G1.y,G1.z,G1.w};
    float sh1[3], sh2[5];
    sh_from_u(G4.x, G4.y, G4.z, sh1, sh2);
    float w0 = b0v, w1 = b1v, w2 = b2v;
    #pragma unroll
    for (int k = 0; k < 8; k++) {
      w0 += rad[k]*wr0[k]; w1 += rad[k]*wr1[k]; w2 += rad[k]*wr2[k];
    }
    acc0 += w0*h0c;
    float wh1 = w1*h0c, wh2 = w2*h0c;
    #pragma unroll
    for (int m = 0; m < 3; m++) acc1[m] += wh1*sh1[m];
    #pragma unroll
    for (int m = 0; m < 5; m++) acc2[m] += wh2*sh2[m];
  }
  a0[n*16 + c] = acc0;
  #pragma unroll
  for (int m = 0; m < 3; m++) a1[n*48 + c*3 + m] = acc1[m];
  #pragma unroll
  for (int m = 0; m < 5; m++) a2[n*80 + c*5 + m] = acc2[m];
}

// ---------------------------------------------------------------------------
// Forward block 1 (last): a0 += w0*h0c + w3*S1 + w4*S2
// ---------------------------------------------------------------------------
__global__ void k_fwd_b1(const float* __restrict__ Wr, const float* __restrict__ br,
                         const float* __restrict__ h0_in, const float* __restrict__ h1_in,
                         const float* __restrict__ h2_in, const float4* __restrict__ geoR,
                         const int* __restrict__ colR,
                         const int* __restrict__ start_row, const int* __restrict__ deg_row,
                         float* __restrict__ a0, int N)
{
  int n = blockIdx.x * (blockDim.x >> 4) + (threadIdx.x >> 4);
  int c = threadIdx.x & 15;
  if (n >= N) return;
  float wr0[8], wr3[8], wr4[8];
  #pragma unroll
  for (int k = 0; k < 8; k++) {
    wr0[k] = Wr[k*80 + c];
    wr3[k] = Wr[k*80 + 48 + c];
    wr4[k] = Wr[k*80 + 64 + c];
  }
  float b0v = br[c], b3v = br[48 + c], b4v = br[64 + c];

  float acc0 = 0.f;
  int i0 = start_row[n], i1 = i0 + deg_row[n];
  float4 G0n = {0,0,0,0}, G1n = {0,0,0,0}, G4n = {0,0,0,0};
  float h0n = 0.f, h1n[3] = {0,0,0}, h2n[5] = {0,0,0,0,0};
  if (i0 < i1) {
    int col = colR[i0];
    G0n = geoR[i0*5+0]; G1n = geoR[i0*5+1]; G4n = geoR[i0*5+4];
    h0n = h0_in[col*16 + c];
    #pragma unroll
    for (int m = 0; m < 3; m++) h1n[m] = h1_in[col*48 + c*3 + m];
    #pragma unroll
    for (int m = 0; m < 5; m++) h2n[m] = h2_in[col*80 + c*5 + m];
  }
  for (int i = i0; i < i1; i++) {
    float4 G0 = G0n, G1 = G1n, G4 = G4n;
    float h0c = h0n;
    float h1c[3], h2c[5];
    #pragma unroll
    for (int m = 0; m < 3; m++) h1c[m] = h1n[m];
    #pragma unroll
    for (int m = 0; m < 5; m++) h2c[m] = h2n[m];
    if (i+1 < i1) {
      int col = colR[i+1];
      G0n = geoR[(i+1)*5+0]; G1n = geoR[(i+1)*5+1]; G4n = geoR[(i+1)*5+4];
      h0n = h0_in[col*16 + c];
      #pragma unroll
      for (int m = 0; m < 3; m++) h1n[m] = h1_in[col*48 + c*3 + m];
      #pragma unroll
      for (int m = 0; m < 5; m++) h2n[m] = h2_in[col*80 + c*5 + m];
    }
    float rad[8] = {G0.x,G0.y,G0.z,G0.w,G1.x,G1.y,G1.z,G1.w};
    float sh1[3], sh2[5];
    sh_from_u(G4.x, G4.y, G4.z, sh1, sh2);
    float w0 = b0v, w3 = b3v, w4 = b4v;
    #pragma unroll
    for (int k = 0; k < 8; k++) {
      w0 += rad[k]*wr0[k]; w3 += rad[k]*wr3[k]; w4 += rad[k]*wr4[k];
    }
    float S1 = 0.f, S2 = 0.f;
    #pragma unroll
    for (int m = 0; m < 3; m++) S1 += h1c[m]*sh1[m];
    #pragma unroll
    for (int m = 0; m < 5; m++) S2 += h2c[m]*sh2[m];
    acc0 += w0*h0c + w3*S1 + w4*S2;
  }
  a0[n*16 + c] = acc0;
}

// ---------------------------------------------------------------------------
// Node update: h_out = h_in + a @ U
// ---------------------------------------------------------------------------
__global__ void k_node_update(const float* __restrict__ h0_in,
                              const float* __restrict__ a0, const float* __restrict__ a1,
                              const float* __restrict__ a2,
                              const float* __restrict__ U,
                              float* __restrict__ h0_out, float* __restrict__ h1_out,
                              float* __restrict__ h2_out, int N, int full)
{
  int idx = blockIdx.x * blockDim.x + threadIdx.x;
  int n = idx >> 4, d = idx & 15;
  if (n >= N) return;
  const float* U0 = U;
  const float* U1 = U + 256;
  const float* U2 = U + 512;
  float s = h0_in[n*16 + d];
  #pragma unroll
  for (int c = 0; c < 16; c++) s += a0[n*16 + c] * U0[c*16 + d];
  h0_out[n*16 + d] = s;
  if (full) {
    float v1[3] = {0.f, 0.f, 0.f};
    #pragma unroll
    for (int c = 0; c < 16; c++) {
      float u = U1[c*16 + d];
      #pragma unroll
      for (int m = 0; m < 3; m++) v1[m] += a1[n*48 + c*3 + m] * u;
    }
    #pragma unroll
    for (int m = 0; m < 3; m++) h1_out[n*48 + d*3 + m] = v1[m];
    float v2[5] = {0.f, 0.f, 0.f, 0.f, 0.f};
    #pragma unroll
    for (int c = 0; c < 16; c++) {
      float u = U2[c*16 + d];
      #pragma unroll
      for (int m = 0; m < 5; m++) v2[m] += a2[n*80 + c*5 + m] * u;
    }
    #pragma unroll
    for (int m = 0; m < 5; m++) h2_out[n*80 + d*5 + m] = v2[m];
  }
}

// ---------------------------------------------------------------------------
// Readout fwd + bwd fused
// ---------------------------------------------------------------------------
__global__ void k_readout_bwd(const float* __restrict__ h0, const float* __restrict__ W_read,
                              const float* __restrict__ W1, const float* __restrict__ b1,
                              const float* __restrict__ W2, const float* __restrict__ b2,
                              float* __restrict__ g0, float* __restrict__ energy, int N)
{
  int n = blockIdx.x * blockDim.x + threadIdx.x;
  float site = 0.f;
  if (n < N) {
    float h[16], inv[16], dt[16];
    #pragma unroll
    for (int d = 0; d < 16; d++) h[d] = h0[n*16 + d];
    #pragma unroll
    for (int j = 0; j < 16; j++) {
      float s = 0.f;
      #pragma unroll
      for (int d = 0; d < 16; d++) s += h[d] * W_read[d*16 + j];
      inv[j] = s;
    }
    site = b2[0];
    #pragma unroll
    for (int c = 0; c < 16; c++) {
      float t = b1[c];
      #pragma unroll
      for (int j = 0; j < 16; j++) t += inv[j] * W1[j*16 + c];
      float sg = 1.f / (1.f + expf(-t));
      float w2v = W2[c];
      site += t * sg * w2v;
      dt[c] = w2v * sg * (1.f + t * (1.f - sg));
    }
    float dinv[16];
    #pragma unroll
    for (int j = 0; j < 16; j++) {
      float s = 0.f;
      #pragma unroll
      for (int c = 0; c < 16; c++) s += dt[c] * W1[j*16 + c];
      dinv[j] = s;
    }
    #pragma unroll
    for (int d = 0; d < 16; d++) {
      float s = 0.f;
      #pragma unroll
      for (int j = 0; j < 16; j++) s += dinv[j] * W_read[d*16 + j];
      g0[n*16 + d] = s;
    }
  }
  #pragma unroll
  for (int off = 32; off; off >>= 1) site += __shfl_down(site, off, 64);
  if ((threadIdx.x & 63) == 0) atomicAdd(energy, site);
}

// ---------------------------------------------------------------------------
// ga = g @ U^T
// ---------------------------------------------------------------------------
__global__ void k_ga(const float* __restrict__ g0, const float* __restrict__ g1,
                     const float* __restrict__ g2, const float* __restrict__ U,
                     float* __restrict__ ga0, float* __restrict__ ga1, float* __restrict__ ga2,
                     int N, int full)
{
  int idx = blockIdx.x * blockDim.x + threadIdx.x;
  int n = idx >> 4, c = idx & 15;
  if (n >= N) return;
  const float* U0 = U;
  const float* U1 = U + 256;
  const float* U2 = U + 512;
  float s = 0.f;
  #pragma unroll
  for (int d = 0; d < 16; d++) s += g0[n*16 + d] * U0[c*16 + d];
  ga0[n*16 + c] = s;
  if (full) {
    float v1[3] = {0.f, 0.f, 0.f};
    #pragma unroll
    for (int d = 0; d < 16; d++) {
      float u = U1[c*16 + d];
      #pragma unroll
      for (int m = 0; m < 3; m++) v1[m] += g1[n*48 + d*3 + m] * u;
    }
    #pragma unroll
    for (int m = 0; m < 3; m++) ga1[n*48 + c*3 + m] = v1[m];
    float v2[5] = {0.f, 0.f, 0.f, 0.f, 0.f};
    #pragma unroll
    for (int d = 0; d < 16; d++) {
      float u = U2[c*16 + d];
      #pragma unroll
      for (int m = 0; m < 5; m++) v2[m] += g2[n*80 + d*5 + m] * u;
    }
    #pragma unroll
    for (int m = 0; m < 5; m++) ga2[n*80 + c*5 + m] = v2[m];
  }
}

// ---------------------------------------------------------------------------
// Backward block 1, col-centric: streams rowC/rposC, gathers geoR[rp] and
// ga0[row]; writes dv_col positionally (contiguous).
// ---------------------------------------------------------------------------
__global__ void k_bwd_b1_col(const float* __restrict__ Wr, const float* __restrict__ br,
                             const float* __restrict__ h0_in, const float* __restrict__ h1_in,
                             const float* __restrict__ h2_in,
                             const float* __restrict__ ga0, const float4* __restrict__ geoR,
                             const int* __restrict__ rowC, const int* __restrict__ rposC,
                             const int* __restrict__ start_col, const int* __restrict__ deg_col,
                             float* __restrict__ g0, float* __restrict__ g1, float* __restrict__ g2,
                             float* __restrict__ dv_col, int N)
{
  int n = blockIdx.x * (blockDim.x >> 4) + (threadIdx.x >> 4);
  int c = threadIdx.x & 15;
  if (n >= N) return;
  float wr0[8], wr3[8], wr4[8];
  #pragma unroll
  for (int k = 0; k < 8; k++) {
    wr0[k] = Wr[k*80 + c];
    wr3[k] = Wr[k*80 + 48 + c];
    wr4[k] = Wr[k*80 + 64 + c];
  }
  float b0v = br[c], b3v = br[48 + c], b4v = br[64 + c];

  float h0c = h0_in[n*16 + c];
  float h1c[3], h2c[5];
  #pragma unroll
  for (int m = 0; m < 3; m++) h1c[m] = h1_in[n*48 + c*3 + m];
  #pragma unroll
  for (int m = 0; m < 5; m++) h2c[m] = h2_in[n*80 + c*5 + m];

  float accg0 = 0.f, accg1[3] = {0.f,0.f,0.f}, accg2[5] = {0.f,0.f,0.f,0.f,0.f};

  int i0 = start_col[n], i1 = i0 + deg_col[n];
  float4 G0n = {0,0,0,0}, G1n = {0,0,0,0}, G2n = {0,0,0,0}, G3n = {0,0,0,0}, G4n = {0,0,0,0};
  float dm0n = 0.f;
  if (i0 < i1) {
    int rp = rposC[i0];
    G0n = geoR[rp*5+0]; G1n = geoR[rp*5+1]; G2n = geoR[rp*5+2];
    G3n = geoR[rp*5+3]; G4n = geoR[rp*5+4];
    dm0n = ga0[rowC[i0]*16 + c];
  }
  for (int i = i0; i < i1; i++) {
    float4 G0 = G0n, G1 = G1n, G2 = G2n, G3 = G3n, G4 = G4n;
    float dm0 = dm0n;
    if (i+1 < i1) {
      int rp = rposC[i+1];
      G0n = geoR[rp*5+0]; G1n = geoR[rp*5+1]; G2n = geoR[rp*5+2];
      G3n = geoR[rp*5+3]; G4n = geoR[rp*5+4];
      dm0n = ga0[rowC[i+1]*16 + c];
    }
    float rad[8]    = {G0.x,G0.y,G0.z,G0.w,G1.x,G1.y,G1.z,G1.w};
    float draddr[8] = {G2.x,G2.y,G2.z,G2.w,G3.x,G3.y,G3.z,G3.w};
    float ux = G4.x, uy = G4.y, uz = G4.z, inv_r = G4.w;
    float sh1[3], sh2[5];
    sh_from_u(ux, uy, uz, sh1, sh2);

    float w0 = b0v, w3 = b3v, w4 = b4v;
    #pragma unroll
    for (int k = 0; k < 8; k++) {
      w0 += rad[k]*wr0[k]; w3 += rad[k]*wr3[k]; w4 += rad[k]*wr4[k];
    }

    float S1 = 0.f, S2 = 0.f;
    #pragma unroll
    for (int m = 0; m < 3; m++) S1 += h1c[m]*sh1[m];
    #pragma unroll
    for (int m = 0; m < 5; m++) S2 += h2c[m]*sh2[m];

    float dw0 = dm0 * h0c;
    float dw3 = dm0 * S1;
    float dw4 = dm0 * S2;
    float t3 = dm0 * w3, t4 = dm0 * w4;

    accg0 += dm0 * w0;
    #pragma unroll
    for (int m = 0; m < 3; m++) accg1[m] += t3 * sh1[m];
    #pragma unroll
    for (int m = 0; m < 5; m++) accg2[m] += t4 * sh2[m];

    float q1x = t3*h1c[0], q1y = t3*h1c[1], q1z = t3*h1c[2];
    float q0 = t4*h2c[0], q1 = t4*h2c[1], q2 = t4*h2c[2], q3 = t4*h2c[3], q4 = t4*h2c[4];
    float gr = 0.f;
    #pragma unroll
    for (int k = 0; k < 8; k++)
      gr += (dw0*wr0[k] + dw3*wr3[k] + dw4*wr4[k]) * draddr[k];
    float gux = SQRT3f*q1x + SQRT15f*(uy*q0 + uz*q3 + ux*q4);
    float guy = SQRT3f*q1y + SQRT15f*(ux*q0 + uz*q1 - uy*q4);
    float guz = SQRT3f*q1z + SQRT15f*uy*q1 + 3.f*SQRT5f*uz*q2 + SQRT15f*ux*q3;

    gr  = grp16_sum(gr);
    gux = grp16_sum(gux);
    guy = grp16_sum(guy);
    guz = grp16_sum(guz);

    if (c == 0) {
      float gdotu = gux*ux + guy*uy + guz*uz;
      dv_col[i*3+0] = gr*ux + (gux - gdotu*ux)*inv_r;
      dv_col[i*3+1] = gr*uy + (guy - gdotu*uy)*inv_r;
      dv_col[i*3+2] = gr*uz + (guz - gdotu*uz)*inv_r;
    }
  }
  g0[n*16 + c] += accg0;
  #pragma unroll
  for (int m = 0; m < 3; m++) g1[n*48 + c*3 + m] = accg1[m];
  #pragma unroll
  for (int m = 0; m < 5; m++) g2[n*80 + c*5 + m] = accg2[m];
}

// ---------------------------------------------------------------------------
// Backward block 0, row-centric: streams geoR/colR/cposR; gathers h0[col];
// adds its dv into the edge's col-position (unique writer, no atomics).
// ---------------------------------------------------------------------------
__global__ void k_bwd_b0_row(const float* __restrict__ Wr, const float* __restrict__ br,
                             const float* __restrict__ h0_in,
                             const float* __restrict__ ga0, const float* __restrict__ ga1,
                             const float* __restrict__ ga2, const float4* __restrict__ geoR,
                             const int* __restrict__ colR, const int* __restrict__ cposR,
                             const int* __restrict__ start_row, const int* __restrict__ deg_row,
                             float* __restrict__ dv_col, int N)
{
  int n = blockIdx.x * (blockDim.x >> 4) + (threadIdx.x >> 4);
  int c = threadIdx.x & 15;
  if (n >= N) return;
  float wr0[8], wr1[8], wr2[8];
  #pragma unroll
  for (int k = 0; k < 8; k++) {
    wr0[k] = Wr[k*80 + c];
    wr1[k] = Wr[k*80 + 16 + c];
    wr2[k] = Wr[k*80 + 32 + c];
  }
  float b1v = br[16 + c], b2v = br[32 + c];

  float dm0 = ga0[n*16 + c];
  float dm1[3], dm2[5];
  #pragma unroll
  for (int m = 0; m < 3; m++) dm1[m] = ga1[n*48 + c*3 + m];
  #pragma unroll
  for (int m = 0; m < 5; m++) dm2[m] = ga2[n*80 + c*5 + m];

  int i0 = start_row[n], i1 = i0 + deg_row[n];
  float4 G0n = {0,0,0,0}, G1n = {0,0,0,0}, G2n = {0,0,0,0}, G3n = {0,0,0,0}, G4n = {0,0,0,0};
  float h0n = 0.f;
  if (i0 < i1) {
    G0n = geoR[i0*5+0]; G1n = geoR[i0*5+1]; G2n = geoR[i0*5+2];
    G3n = geoR[i0*5+3]; G4n = geoR[i0*5+4];
    h0n = h0_in[colR[i0]*16 + c];
  }
  for (int i = i0; i < i1; i++) {
    float4 G0 = G0n, G1 = G1n, G2 = G2n, G3 = G3n, G4 = G4n;
    float h0c = h0n;
    if (i+1 < i1) {
      G0n = geoR[(i+1)*5+0]; G1n = geoR[(i+1)*5+1]; G2n = geoR[(i+1)*5+2];
      G3n = geoR[(i+1)*5+3]; G4n = geoR[(i+1)*5+4];
      h0n = h0_in[colR[i+1]*16 + c];
    }
    float rad[8]    = {G0.x,G0.y,G0.z,G0.w,G1.x,G1.y,G1.z,G1.w};
    float draddr[8] = {G2.x,G2.y,G2.z,G2.w,G3.x,G3.y,G3.z,G3.w};
    float ux = G4.x, uy = G4.y, uz = G4.z, inv_r = G4.w;
    float sh1[3], sh2[5];
    sh_from_u(ux, uy, uz, sh1, sh2);

    float w1 = b1v, w2v = b2v;
    #pragma unroll
    for (int k = 0; k < 8; k++) { w1 += rad[k]*wr1[k]; w2v += rad[k]*wr2[k]; }

    float T1 = 0.f, T2 = 0.f;
    #pragma unroll
    for (int m = 0; m < 3; m++) T1 += dm1[m]*sh1[m];
    #pragma unroll
    for (int m = 0; m < 5; m++) T2 += dm2[m]*sh2[m];

    float dw0 = dm0 * h0c;
    float dw1 = h0c * T1;
    float dw2 = h0c * T2;

    float w1h = w1*h0c, w2h = w2v*h0c;
    float q1x = dm1[0]*w1h, q1y = dm1[1]*w1h, q1z = dm1[2]*w1h;
    float q0 = dm2[0]*w2h, q1 = dm2[1]*w2h, q2 = dm2[2]*w2h, q3 = dm2[3]*w2h, q4 = dm2[4]*w2h;

    float gr = 0.f;
    #pragma unroll
    for (int k = 0; k < 8; k++)
      gr += (dw0*wr0[k] + dw1*wr1[k] + dw2*wr2[k]) * draddr[k];
    float gux = SQRT3f*q1x + SQRT15f*(uy*q0 + uz*q3 + ux*q4);
    float guy = SQRT3f*q1y + SQRT15f*(ux*q0 + uz*q1 - uy*q4);
    float guz = SQRT3f*q1z + SQRT15f*uy*q1 + 3.f*SQRT5f*uz*q2 + SQRT15f*ux*q3;

    gr  = grp16_sum(gr);
    gux = grp16_sum(gux);
    guy = grp16_sum(guy);
    guz = grp16_sum(guz);

    if (c == 0) {
      int cp = cposR[i];
      float gdotu = gux*ux + guy*uy + guz*uz;
      dv_col[cp*3+0] += gr*ux + (gux - gdotu*ux)*inv_r;
      dv_col[cp*3+1] += gr*uy + (guy - gdotu*uy)*inv_r;
      dv_col[cp*3+2] += gr*uz + (guz - gdotu*uz)*inv_r;
    }
  }
}

// ---------------------------------------------------------------------------
// Force assembly: force[n] = sum_{col==n} dv - sum_{row==n} dv
// Col side streams dv_col contiguously; row side gathers via cposR.
// ---------------------------------------------------------------------------
__global__ void k_force(const int* __restrict__ start_row, const int* __restrict__ deg_row,
                        const int* __restrict__ cposR,
                        const int* __restrict__ start_col, const int* __restrict__ deg_col,
                        const float* __restrict__ dv_col, float* __restrict__ force, int N)
{
  int n = blockIdx.x * blockDim.x + threadIdx.x;
  if (n >= N) return;
  float fx = 0.f, fy = 0.f, fz = 0.f;
  int c0 = start_col[n], c1 = c0 + deg_col[n];
  for (int i = c0; i < c1; i++) {
    fx += dv_col[i*3+0]; fy += dv_col[i*3+1]; fz += dv_col[i*3+2];
  }
  int r0 = start_row[n], r1 = r0 + deg_row[n];
  for (int i = r0; i < r1; i++) {
    int cp = cposR[i];
    fx -= dv_col[cp*3+0]; fy -= dv_col[cp*3+1]; fz -= dv_col[cp*3+2];
  }
  force[n*3+0] = fx; force[n*3+1] = fy; force[n*3+2] = fz;
}

// ---------------------------------------------------------------------------
extern "C" void kernel_launch(void* const* d_in, const int* in_sizes, int n_in,
                              void* d_out, int out_size, void* d_ws, size_t ws_size,
                              hipStream_t stream)
{
  const float* pos    = (const float*)d_in[0];
  const int*   z      = (const int*)  d_in[1];
  const int*   ei     = (const int*)  d_in[2];
  const float* emb    = (const float*)d_in[3];
  const float* W_init = (const float*)d_in[4];
  const float* Wr     = (const float*)d_in[5];   // (2, 8, 80)
  const float* br     = (const float*)d_in[6];   // (2, 80)
  const float* W_out  = (const float*)d_in[7];   // (2, 3, 16, 16)
  const float* W_read = (const float*)d_in[8];
  const float* W1     = (const float*)d_in[9];
  const float* b1     = (const float*)d_in[10];
  const float* W2     = (const float*)d_in[11];
  const float* b2     = (const float*)d_in[12];

  const int N = in_sizes[0] / 3;
  const int E = in_sizes[2] / 2;

  float* f = (float*)d_ws;
  float* geo_f = f; f += (size_t)E*20;   // float4-aligned (d_ws base is aligned)
  float* h0_s0 = f; f += (size_t)N*16;
  float* h0_s1 = f; f += (size_t)N*16;
  float* h0_s2 = f; f += (size_t)N*16;
  float* h1_s1 = f; f += (size_t)N*48;
  float* h2_s1 = f; f += (size_t)N*80;
  float* a0    = f; f += (size_t)N*16;   // also ga0
  float* a1    = f; f += (size_t)N*48;   // also ga1
  float* a2    = f; f += (size_t)N*80;   // also ga2
  float* g0    = f; f += (size_t)N*16;
  float* g1    = f; f += (size_t)N*48;
  float* g2    = f; f += (size_t)N*80;
  float* dv    = f; f += (size_t)E*3;    // dv_col, positional in col order
  int* ip = (int*)f;
  int* cursors   = ip; ip += 2;          // cursors+deg contiguous -> one memset
  int* deg_row   = ip; ip += N;
  int* deg_col   = ip; ip += N;
  int* start_row = ip; ip += N;
  int* start_col = ip; ip += N;
  int* cur_row   = ip; ip += N;
  int* cur_col   = ip; ip += N;
  int* colR      = ip; ip += E;
  int* cposR     = ip; ip += E;
  int* rowC      = ip; ip += E;
  int* rposC     = ip; ip += E;

  float4* geoR = (float4*)geo_f;

  float* out    = (float*)d_out;
  float* energy = out;
  float* force  = out + 1;

  const int BLK = 256;
  const int GPB = BLK / 16;  // 16-lane groups per block

  (void)hipMemsetAsync(energy, 0, sizeof(float), stream);
  (void)hipMemsetAsync(cursors, 0, (size_t)(2 + 2*N) * sizeof(int), stream);

  // ---- CSR build (scan-free) + geometry in CSR order ----
  k_hist<<<cdiv(E, BLK), BLK, 0, stream>>>(ei, E, deg_row, deg_col);
  k_alloc<<<cdiv(N, BLK), BLK, 0, stream>>>(deg_row, deg_col, start_row, cur_row,
                                            start_col, cur_col, cursors, N);
  k_scatter_geom<<<cdiv(E, BLK), BLK, 0, stream>>>(pos, ei, E, cur_row, cur_col,
                                                   geoR, colR, cposR, rowC, rposC);

  k_node_init<<<cdiv(N, BLK), BLK, 0, stream>>>(emb, z, W_init, h0_s0, N);

  // ---- forward block 0 ----
  k_fwd_b0<<<cdiv(N, GPB), BLK, 0, stream>>>(Wr, br, h0_s0, geoR, colR,
                                             start_row, deg_row, a0, a1, a2, N);
  k_node_update<<<cdiv(N*16, BLK), BLK, 0, stream>>>(h0_s0, a0, a1, a2,
                                                     W_out, h0_s1, h1_s1, h2_s1, N, 1);

  // ---- forward block 1 (only h0 path live) ----
  k_fwd_b1<<<cdiv(N, GPB), BLK, 0, stream>>>(Wr + 640, br + 80,
                                             h0_s1, h1_s1, h2_s1, geoR, colR,
                                             start_row, deg_row, a0, N);
  k_node_update<<<cdiv(N*16, BLK), BLK, 0, stream>>>(h0_s1, a0, nullptr, nullptr,
                                                     W_out + 768, h0_s2, nullptr, nullptr, N, 0);

  // ---- readout fwd + bwd ----
  k_readout_bwd<<<cdiv(N, BLK), BLK, 0, stream>>>(h0_s2, W_read, W1, b1, W2, b2, g0, energy, N);

  // ---- backward block 1 ----
  k_ga<<<cdiv(N*16, BLK), BLK, 0, stream>>>(g0, nullptr, nullptr, W_out + 768,
                                            a0, nullptr, nullptr, N, 0);
  k_bwd_b1_col<<<cdiv(N, GPB), BLK, 0, stream>>>(Wr + 640, br + 80,
                                                 h0_s1, h1_s1, h2_s1, a0, geoR,
                                                 rowC, rposC, start_col, deg_col,
                                                 g0, g1, g2, dv, N);

  // ---- backward block 0 ----
  k_ga<<<cdiv(N*16, BLK), BLK, 0, stream>>>(g0, g1, g2, W_out, a0, a1, a2, N, 1);
  k_bwd_b0_row<<<cdiv(N, GPB), BLK, 0, stream>>>(Wr, br, h0_s0,
                                                 a0, a1, a2, geoR, colR, cposR,
                                                 start_row, deg_row, dv, N);

  // ---- force assembly ----
  k_force<<<cdiv(N, BLK), BLK, 0, stream>>>(start_row, deg_row, cposR,
                                            start_col, deg_col, dv, force, N);
}

// Round 9
// 529.341 us; speedup vs baseline: 4.4529x; 1.0498x over previous
//
#include <hip/hip_runtime.h>
#include <math.h>

#ifndef M_PI
#define M_PI 3.14159265358979323846
#endif

static inline int cdiv(int a, int b){ return (a + b - 1) / b; }

#define SQRT3f  1.7320508075688772f
#define SQRT5f  2.23606797749979f
#define SQRT15f 3.872983346207417f
#define KRADf   0.6324555320336759f      /* sqrt(2/R_MAX), R_MAX=5 */
#define PI5f    0.6283185307179586f      /* pi/5 */

// sum over the 16-lane channel group (within-group, xor 1..8)
__device__ __forceinline__ float grp16_sum(float v){
  v += __shfl_xor(v, 1, 64);
  v += __shfl_xor(v, 2, 64);
  v += __shfl_xor(v, 4, 64);
  v += __shfl_xor(v, 8, 64);
  return v;
}
// sum across the 4 groups of a wave (same channel lane in each group)
__device__ __forceinline__ float xgrp_sum(float v){
  v += __shfl_xor(v, 16, 64);
  v += __shfl_xor(v, 32, 64);
  return v;
}

// sh from unit vector (8 ops)
__device__ __forceinline__ void sh_from_u(float ux, float uy, float uz,
                                          float* sh1, float* sh2)
{
  sh1[0] = SQRT3f*ux; sh1[1] = SQRT3f*uy; sh1[2] = SQRT3f*uz;
  sh2[0] = SQRT15f*ux*uy;
  sh2[1] = SQRT15f*uy*uz;
  sh2[2] = 0.5f*SQRT5f*(3.f*uz*uz - 1.f);
  sh2[3] = SQRT15f*ux*uz;
  sh2[4] = 0.5f*SQRT15f*(ux*ux - uy*uy);
}

// ---------------------------------------------------------------------------
// Degree histogram (E-parallel)
// ---------------------------------------------------------------------------
__global__ void k_hist(const int* __restrict__ ei, int E,
                       int* __restrict__ deg_row, int* __restrict__ deg_col)
{
  int e = blockIdx.x * blockDim.x + threadIdx.x;
  if (e >= E) return;
  atomicAdd(&deg_row[ei[e]], 1);
  atomicAdd(&deg_col[ei[E + e]], 1);
}

// ---------------------------------------------------------------------------
// Scan-free segment allocation: wave-aggregated atomicAdd on global cursors.
// ---------------------------------------------------------------------------
__global__ void k_alloc(const int* __restrict__ deg_row, const int* __restrict__ deg_col,
                        int* __restrict__ start_row, int* __restrict__ cur_row,
                        int* __restrict__ start_col, int* __restrict__ cur_col,
                        int* __restrict__ cursors, int N)
{
  int idx = blockIdx.x * blockDim.x + threadIdx.x;
  int lane = threadIdx.x & 63;
  #pragma unroll
  for (int which = 0; which < 2; which++) {
    const int* deg = which ? deg_col : deg_row;
    int* start = which ? start_col : start_row;
    int* cur   = which ? cur_col   : cur_row;
    int v = (idx < N) ? deg[idx] : 0;
    int incl = v;
    #pragma unroll
    for (int d = 1; d < 64; d <<= 1) {
      int y = __shfl_up(incl, d, 64);
      if (lane >= d) incl += y;
    }
    int wtot = __shfl(incl, 63, 64);
    int base = 0;
    if (lane == 63) base = atomicAdd(&cursors[which], wtot);
    base = __shfl(base, 63, 64);
    if (idx < N) { int st = base + incl - v; start[idx] = st; cur[idx] = st; }
  }
}

// ---------------------------------------------------------------------------
// Scatter + geometry, CSR-ordered (geometry computed once, stored at the
// edge's row-CSR position). colR/cposR stream for row-side loops; rowC/rposC
// for col-side loops.
// ---------------------------------------------------------------------------
__global__ void k_scatter_geom(const float* __restrict__ pos, const int* __restrict__ ei, int E,
                               int* __restrict__ cur_row, int* __restrict__ cur_col,
                               float4* __restrict__ geoR,
                               int* __restrict__ colR, int* __restrict__ cposR,
                               int* __restrict__ rowC, int* __restrict__ rposC)
{
  int e = blockIdx.x * blockDim.x + threadIdx.x;
  if (e >= E) return;
  int row = ei[e], col = ei[E + e];
  int pr = atomicAdd(&cur_row[row], 1);
  int pc = atomicAdd(&cur_col[col], 1);
  colR[pr] = col; cposR[pr] = pc;
  rowC[pc] = row; rposC[pc] = pr;

  float px = pos[row*3+0] - pos[col*3+0];
  float py = pos[row*3+1] - pos[col*3+1];
  float pz = pos[row*3+2] - pos[col*3+2];
  float r2 = px*px + py*py + pz*pz + 1e-12f;
  float r = sqrtf(r2);
  float inv_r = 1.0f / r;
  float ux = px*inv_r, uy = py*inv_r, uz = pz*inv_r;
  float x = r * PI5f;
  float s1, c1;
  sincosf(x, &s1, &c1);
  float tc = 2.f * c1;
  float sprev = 0.f, s = s1, cprev = 1.f, cc = c1;
  float Ki = KRADf * inv_r;
  float rad[8], draddr[8];
  const float KPI5 = KRADf * PI5f;
  #pragma unroll
  for (int k = 0; k < 8; k++) {
    rad[k] = Ki * s;
    draddr[k] = (KPI5 * (float)(k+1) * cc - rad[k]) * inv_r;
    float sn = tc*s - sprev; sprev = s; s = sn;
    float cn = tc*cc - cprev; cprev = cc; cc = cn;
  }
  geoR[pr*5+0] = make_float4(rad[0], rad[1], rad[2], rad[3]);
  geoR[pr*5+1] = make_float4(rad[4], rad[5], rad[6], rad[7]);
  geoR[pr*5+2] = make_float4(draddr[0], draddr[1], draddr[2], draddr[3]);
  geoR[pr*5+3] = make_float4(draddr[4], draddr[5], draddr[6], draddr[7]);
  geoR[pr*5+4] = make_float4(ux, uy, uz, inv_r);
}

// ---------------------------------------------------------------------------
// h0_init[n,:] = emb[z[n],:] @ W_init
// ---------------------------------------------------------------------------
__global__ void k_node_init(const float* __restrict__ emb, const int* __restrict__ z,
                            const float* __restrict__ W_init, float* __restrict__ h0, int N)
{
  __shared__ float sW[256];
  if (threadIdx.x < 256) sW[threadIdx.x] = W_init[threadIdx.x];
  __syncthreads();
  int n = blockIdx.x * blockDim.x + threadIdx.x;
  if (n >= N) return;
  const float* e = emb + z[n]*16;
  float ev[16];
  #pragma unroll
  for (int k = 0; k < 16; k++) ev[k] = e[k];
  #pragma unroll
  for (int c = 0; c < 16; c++) {
    float s = 0.f;
    #pragma unroll
    for (int k = 0; k < 16; k++) s += ev[k] * sW[k*16+c];
    h0[n*16+c] = s;
  }
}

// ---------------------------------------------------------------------------
// Forward block 0 — WAVE per node: 4 groups x 16 channels, group g strides
// edges by 4. Final cross-group reduce.
// ---------------------------------------------------------------------------
__global__ void k_fwd_b0(const float* __restrict__ Wr, const float* __restrict__ br,
                         const float* __restrict__ h0_in, const float4* __restrict__ geoR,
                         const int* __restrict__ colR,
                         const int* __restrict__ start_row, const int* __restrict__ deg_row,
                         float* __restrict__ a0, float* __restrict__ a1, float* __restrict__ a2,
                         int N)
{
  int n = (blockIdx.x * blockDim.x + threadIdx.x) >> 6;
  int lane = threadIdx.x & 63;
  int g = lane >> 4, c = lane & 15;
  if (n >= N) return;
  float wr0[8], wr1[8], wr2[8];
  #pragma unroll
  for (int k = 0; k < 8; k++) {
    wr0[k] = Wr[k*80 + c];
    wr1[k] = Wr[k*80 + 16 + c];
    wr2[k] = Wr[k*80 + 32 + c];
  }
  float b0v = br[c], b1v = br[16 + c], b2v = br[32 + c];

  float acc0 = 0.f, acc1[3] = {0.f,0.f,0.f}, acc2[5] = {0.f,0.f,0.f,0.f,0.f};

  int i0 = start_row[n] + g, i1 = start_row[n] + deg_row[n];
  float4 G0n = {0,0,0,0}, G1n = {0,0,0,0}, G4n = {0,0,0,0};
  float h0n = 0.f;
  if (i0 < i1) {
    G0n = geoR[i0*5+0]; G1n = geoR[i0*5+1]; G4n = geoR[i0*5+4];
    h0n = h0_in[colR[i0]*16 + c];
  }
  for (int i = i0; i < i1; i += 4) {
    float4 G0 = G0n, G1 = G1n, G4 = G4n;
    float h0c = h0n;
    if (i+4 < i1) {
      G0n = geoR[(i+4)*5+0]; G1n = geoR[(i+4)*5+1]; G4n = geoR[(i+4)*5+4];
      h0n = h0_in[colR[i+4]*16 + c];
    }
    float rad[8] = {G0.x,G0.y,G0.z,G0.w,G1.x,G1.y,G1.z,G1.w};
    float sh1[3], sh2[5];
    sh_from_u(G4.x, G4.y, G4.z, sh1, sh2);
    float w0 = b0v, w1 = b1v, w2 = b2v;
    #pragma unroll
    for (int k = 0; k < 8; k++) {
      w0 += rad[k]*wr0[k]; w1 += rad[k]*wr1[k]; w2 += rad[k]*wr2[k];
    }
    acc0 += w0*h0c;
    float wh1 = w1*h0c, wh2 = w2*h0c;
    #pragma unroll
    for (int m = 0; m < 3; m++) acc1[m] += wh1*sh1[m];
    #pragma unroll
    for (int m = 0; m < 5; m++) acc2[m] += wh2*sh2[m];
  }
  acc0 = xgrp_sum(acc0);
  #pragma unroll
  for (int m = 0; m < 3; m++) acc1[m] = xgrp_sum(acc1[m]);
  #pragma unroll
  for (int m = 0; m < 5; m++) acc2[m] = xgrp_sum(acc2[m]);
  if (g == 0) {
    a0[n*16 + c] = acc0;
    #pragma unroll
    for (int m = 0; m < 3; m++) a1[n*48 + c*3 + m] = acc1[m];
    #pragma unroll
    for (int m = 0; m < 5; m++) a2[n*80 + c*5 + m] = acc2[m];
  }
}

// ---------------------------------------------------------------------------
// Forward block 1 (last) — wave per node.
// ---------------------------------------------------------------------------
__global__ void k_fwd_b1(const float* __restrict__ Wr, const float* __restrict__ br,
                         const float* __restrict__ h0_in, const float* __restrict__ h1_in,
                         const float* __restrict__ h2_in, const float4* __restrict__ geoR,
                         const int* __restrict__ colR,
                         const int* __restrict__ start_row, const int* __restrict__ deg_row,
                         float* __restrict__ a0, int N)
{
  int n = (blockIdx.x * blockDim.x + threadIdx.x) >> 6;
  int lane = threadIdx.x & 63;
  int g = lane >> 4, c = lane & 15;
  if (n >= N) return;
  float wr0[8], wr3[8], wr4[8];
  #pragma unroll
  for (int k = 0; k < 8; k++) {
    wr0[k] = Wr[k*80 + c];
    wr3[k] = Wr[k*80 + 48 + c];
    wr4[k] = Wr[k*80 + 64 + c];
  }
  float b0v = br[c], b3v = br[48 + c], b4v = br[64 + c];

  float acc0 = 0.f;
  int i0 = start_row[n] + g, i1 = start_row[n] + deg_row[n];
  float4 G0n = {0,0,0,0}, G1n = {0,0,0,0}, G4n = {0,0,0,0};
  float h0n = 0.f, h1n[3] = {0,0,0}, h2n[5] = {0,0,0,0,0};
  if (i0 < i1) {
    int col = colR[i0];
    G0n = geoR[i0*5+0]; G1n = geoR[i0*5+1]; G4n = geoR[i0*5+4];
    h0n = h0_in[col*16 + c];
    #pragma unroll
    for (int m = 0; m < 3; m++) h1n[m] = h1_in[col*48 + c*3 + m];
    #pragma unroll
    for (int m = 0; m < 5; m++) h2n[m] = h2_in[col*80 + c*5 + m];
  }
  for (int i = i0; i < i1; i += 4) {
    float4 G0 = G0n, G1 = G1n, G4 = G4n;
    float h0c = h0n;
    float h1c[3], h2c[5];
    #pragma unroll
    for (int m = 0; m < 3; m++) h1c[m] = h1n[m];
    #pragma unroll
    for (int m = 0; m < 5; m++) h2c[m] = h2n[m];
    if (i+4 < i1) {
      int col = colR[i+4];
      G0n = geoR[(i+4)*5+0]; G1n = geoR[(i+4)*5+1]; G4n = geoR[(i+4)*5+4];
      h0n = h0_in[col*16 + c];
      #pragma unroll
      for (int m = 0; m < 3; m++) h1n[m] = h1_in[col*48 + c*3 + m];
      #pragma unroll
      for (int m = 0; m < 5; m++) h2n[m] = h2_in[col*80 + c*5 + m];
    }
    float rad[8] = {G0.x,G0.y,G0.z,G0.w,G1.x,G1.y,G1.z,G1.w};
    float sh1[3], sh2[5];
    sh_from_u(G4.x, G4.y, G4.z, sh1, sh2);
    float w0 = b0v, w3 = b3v, w4 = b4v;
    #pragma unroll
    for (int k = 0; k < 8; k++) {
      w0 += rad[k]*wr0[k]; w3 += rad[k]*wr3[k]; w4 += rad[k]*wr4[k];
    }
    float S1 = 0.f, S2 = 0.f;
    #pragma unroll
    for (int m = 0; m < 3; m++) S1 += h1c[m]*sh1[m];
    #pragma unroll
    for (int m = 0; m < 5; m++) S2 += h2c[m]*sh2[m];
    acc0 += w0*h0c + w3*S1 + w4*S2;
  }
  acc0 = xgrp_sum(acc0);
  if (g == 0) a0[n*16 + c] = acc0;
}

// ---------------------------------------------------------------------------
// Node update: h_out = h_in + a @ U
// ---------------------------------------------------------------------------
__global__ void k_node_update(const float* __restrict__ h0_in,
                              const float* __restrict__ a0, const float* __restrict__ a1,
                              const float* __restrict__ a2,
                              const float* __restrict__ U,
                              float* __restrict__ h0_out, float* __restrict__ h1_out,
                              float* __restrict__ h2_out, int N, int full)
{
  int idx = blockIdx.x * blockDim.x + threadIdx.x;
  int n = idx >> 4, d = idx & 15;
  if (n >= N) return;
  const float* U0 = U;
  const float* U1 = U + 256;
  const float* U2 = U + 512;
  float s = h0_in[n*16 + d];
  #pragma unroll
  for (int c = 0; c < 16; c++) s += a0[n*16 + c] * U0[c*16 + d];
  h0_out[n*16 + d] = s;
  if (full) {
    float v1[3] = {0.f, 0.f, 0.f};
    #pragma unroll
    for (int c = 0; c < 16; c++) {
      float u = U1[c*16 + d];
      #pragma unroll
      for (int m = 0; m < 3; m++) v1[m] += a1[n*48 + c*3 + m] * u;
    }
    #pragma unroll
    for (int m = 0; m < 3; m++) h1_out[n*48 + d*3 + m] = v1[m];
    float v2[5] = {0.f, 0.f, 0.f, 0.f, 0.f};
    #pragma unroll
    for (int c = 0; c < 16; c++) {
      float u = U2[c*16 + d];
      #pragma unroll
      for (int m = 0; m < 5; m++) v2[m] += a2[n*80 + c*5 + m] * u;
    }
    #pragma unroll
    for (int m = 0; m < 5; m++) h2_out[n*80 + d*5 + m] = v2[m];
  }
}

// ---------------------------------------------------------------------------
// Readout fwd + bwd fused; epilogue also computes ga0_b1 = g0 @ U0(block1)^T
// (folds the light k_ga dispatch — g0 already in registers here).
// ---------------------------------------------------------------------------
__global__ void k_readout_bwd(const float* __restrict__ h0, const float* __restrict__ W_read,
                              const float* __restrict__ W1, const float* __restrict__ b1,
                              const float* __restrict__ W2, const float* __restrict__ b2,
                              const float* __restrict__ U0b1,
                              float* __restrict__ g0, float* __restrict__ ga0,
                              float* __restrict__ energy, int N)
{
  int n = blockIdx.x * blockDim.x + threadIdx.x;
  float site = 0.f;
  if (n < N) {
    float h[16], inv[16], dt[16], g0v[16];
    #pragma unroll
    for (int d = 0; d < 16; d++) h[d] = h0[n*16 + d];
    #pragma unroll
    for (int j = 0; j < 16; j++) {
      float s = 0.f;
      #pragma unroll
      for (int d = 0; d < 16; d++) s += h[d] * W_read[d*16 + j];
      inv[j] = s;
    }
    site = b2[0];
    #pragma unroll
    for (int c = 0; c < 16; c++) {
      float t = b1[c];
      #pragma unroll
      for (int j = 0; j < 16; j++) t += inv[j] * W1[j*16 + c];
      float sg = 1.f / (1.f + expf(-t));
      float w2v = W2[c];
      site += t * sg * w2v;
      dt[c] = w2v * sg * (1.f + t * (1.f - sg));
    }
    float dinv[16];
    #pragma unroll
    for (int j = 0; j < 16; j++) {
      float s = 0.f;
      #pragma unroll
      for (int c = 0; c < 16; c++) s += dt[c] * W1[j*16 + c];
      dinv[j] = s;
    }
    #pragma unroll
    for (int d = 0; d < 16; d++) {
      float s = 0.f;
      #pragma unroll
      for (int j = 0; j < 16; j++) s += dinv[j] * W_read[d*16 + j];
      g0v[d] = s;
      g0[n*16 + d] = s;
    }
    #pragma unroll
    for (int c = 0; c < 16; c++) {
      float s = 0.f;
      #pragma unroll
      for (int d = 0; d < 16; d++) s += g0v[d] * U0b1[c*16 + d];
      ga0[n*16 + c] = s;
    }
  }
  #pragma unroll
  for (int off = 32; off; off >>= 1) site += __shfl_down(site, off, 64);
  if ((threadIdx.x & 63) == 0) atomicAdd(energy, site);
}

// ---------------------------------------------------------------------------
// ga = g @ U^T (full, for block 0 backward)
// ---------------------------------------------------------------------------
__global__ void k_ga(const float* __restrict__ g0, const float* __restrict__ g1,
                     const float* __restrict__ g2, const float* __restrict__ U,
                     float* __restrict__ ga0, float* __restrict__ ga1, float* __restrict__ ga2,
                     int N)
{
  int idx = blockIdx.x * blockDim.x + threadIdx.x;
  int n = idx >> 4, c = idx & 15;
  if (n >= N) return;
  const float* U0 = U;
  const float* U1 = U + 256;
  const float* U2 = U + 512;
  float s = 0.f;
  #pragma unroll
  for (int d = 0; d < 16; d++) s += g0[n*16 + d] * U0[c*16 + d];
  ga0[n*16 + c] = s;
  float v1[3] = {0.f, 0.f, 0.f};
  #pragma unroll
  for (int d = 0; d < 16; d++) {
    float u = U1[c*16 + d];
    #pragma unroll
    for (int m = 0; m < 3; m++) v1[m] += g1[n*48 + d*3 + m] * u;
  }
  #pragma unroll
  for (int m = 0; m < 3; m++) ga1[n*48 + c*3 + m] = v1[m];
  float v2[5] = {0.f, 0.f, 0.f, 0.f, 0.f};
  #pragma unroll
  for (int d = 0; d < 16; d++) {
    float u = U2[c*16 + d];
    #pragma unroll
    for (int m = 0; m < 5; m++) v2[m] += g2[n*80 + d*5 + m] * u;
  }
  #pragma unroll
  for (int m = 0; m < 5; m++) ga2[n*80 + c*5 + m] = v2[m];
}

// ---------------------------------------------------------------------------
// Backward block 1, col-centric — wave per node.
// ---------------------------------------------------------------------------
__global__ void k_bwd_b1_col(const float* __restrict__ Wr, const float* __restrict__ br,
                             const float* __restrict__ h0_in, const float* __restrict__ h1_in,
                             const float* __restrict__ h2_in,
                             const float* __restrict__ ga0, const float4* __restrict__ geoR,
                             const int* __restrict__ rowC, const int* __restrict__ rposC,
                             const int* __restrict__ start_col, const int* __restrict__ deg_col,
                             float* __restrict__ g0, float* __restrict__ g1, float* __restrict__ g2,
                             float* __restrict__ dv_col, int N)
{
  int n = (blockIdx.x * blockDim.x + threadIdx.x) >> 6;
  int lane = threadIdx.x & 63;
  int g = lane >> 4, c = lane & 15;
  if (n >= N) return;
  float wr0[8], wr3[8], wr4[8];
  #pragma unroll
  for (int k = 0; k < 8; k++) {
    wr0[k] = Wr[k*80 + c];
    wr3[k] = Wr[k*80 + 48 + c];
    wr4[k] = Wr[k*80 + 64 + c];
  }
  float b0v = br[c], b3v = br[48 + c], b4v = br[64 + c];

  float h0c = h0_in[n*16 + c];
  float h1c[3], h2c[5];
  #pragma unroll
  for (int m = 0; m < 3; m++) h1c[m] = h1_in[n*48 + c*3 + m];
  #pragma unroll
  for (int m = 0; m < 5; m++) h2c[m] = h2_in[n*80 + c*5 + m];

  float accg0 = 0.f, accg1[3] = {0.f,0.f,0.f}, accg2[5] = {0.f,0.f,0.f,0.f,0.f};

  int i0 = start_col[n] + g, i1 = start_col[n] + deg_col[n];
  float4 G0n = {0,0,0,0}, G1n = {0,0,0,0}, G2n = {0,0,0,0}, G3n = {0,0,0,0}, G4n = {0,0,0,0};
  float dm0n = 0.f;
  if (i0 < i1) {
    int rp = rposC[i0];
    G0n = geoR[rp*5+0]; G1n = geoR[rp*5+1]; G2n = geoR[rp*5+2];
    G3n = geoR[rp*5+3]; G4n = geoR[rp*5+4];
    dm0n = ga0[rowC[i0]*16 + c];
  }
  for (int i = i0; i < i1; i += 4) {
    float4 G0 = G0n, G1 = G1n, G2 = G2n, G3 = G3n, G4 = G4n;
    float dm0 = dm0n;
    if (i+4 < i1) {
      int rp = rposC[i+4];
      G0n = geoR[rp*5+0]; G1n = geoR[rp*5+1]; G2n = geoR[rp*5+2];
      G3n = geoR[rp*5+3]; G4n = geoR[rp*5+4];
      dm0n = ga0[rowC[i+4]*16 + c];
    }
    float rad[8]    = {G0.x,G0.y,G0.z,G0.w,G1.x,G1.y,G1.z,G1.w};
    float draddr[8] = {G2.x,G2.y,G2.z,G2.w,G3.x,G3.y,G3.z,G3.w};
    float ux = G4.x, uy = G4.y, uz = G4.z, inv_r = G4.w;
    float sh1[3], sh2[5];
    sh_from_u(ux, uy, uz, sh1, sh2);

    float w0 = b0v, w3 = b3v, w4 = b4v;
    #pragma unroll
    for (int k = 0; k < 8; k++) {
      w0 += rad[k]*wr0[k]; w3 += rad[k]*wr3[k]; w4 += rad[k]*wr4[k];
    }

    float S1 = 0.f, S2 = 0.f;
    #pragma unroll
    for (int m = 0; m < 3; m++) S1 += h1c[m]*sh1[m];
    #pragma unroll
    for (int m = 0; m < 5; m++) S2 += h2c[m]*sh2[m];

    float dw0 = dm0 * h0c;
    float dw3 = dm0 * S1;
    float dw4 = dm0 * S2;
    float t3 = dm0 * w3, t4 = dm0 * w4;

    accg0 += dm0 * w0;
    #pragma unroll
    for (int m = 0; m < 3; m++) accg1[m] += t3 * sh1[m];
    #pragma unroll
    for (int m = 0; m < 5; m++) accg2[m] += t4 * sh2[m];

    float q1x = t3*h1c[0], q1y = t3*h1c[1], q1z = t3*h1c[2];
    float q0 = t4*h2c[0], q1 = t4*h2c[1], q2 = t4*h2c[2], q3 = t4*h2c[3], q4 = t4*h2c[4];
    float gr = 0.f;
    #pragma unroll
    for (int k = 0; k < 8; k++)
      gr += (dw0*wr0[k] + dw3*wr3[k] + dw4*wr4[k]) * draddr[k];
    float gux = SQRT3f*q1x + SQRT15f*(uy*q0 + uz*q3 + ux*q4);
    float guy = SQRT3f*q1y + SQRT15f*(ux*q0 + uz*q1 - uy*q4);
    float guz = SQRT3f*q1z + SQRT15f*uy*q1 + 3.f*SQRT5f*uz*q2 + SQRT15f*ux*q3;

    gr  = grp16_sum(gr);
    gux = grp16_sum(gux);
    guy = grp16_sum(guy);
    guz = grp16_sum(guz);

    if (c == 0) {
      float gdotu = gux*ux + guy*uy + guz*uz;
      dv_col[i*3+0] = gr*ux + (gux - gdotu*ux)*inv_r;
      dv_col[i*3+1] = gr*uy + (guy - gdotu*uy)*inv_r;
      dv_col[i*3+2] = gr*uz + (guz - gdotu*uz)*inv_r;
    }
  }
  accg0 = xgrp_sum(accg0);
  #pragma unroll
  for (int m = 0; m < 3; m++) accg1[m] = xgrp_sum(accg1[m]);
  #pragma unroll
  for (int m = 0; m < 5; m++) accg2[m] = xgrp_sum(accg2[m]);
  if (g == 0) {
    g0[n*16 + c] += accg0;
    #pragma unroll
    for (int m = 0; m < 3; m++) g1[n*48 + c*3 + m] = accg1[m];
    #pragma unroll
    for (int m = 0; m < 5; m++) g2[n*80 + c*5 + m] = accg2[m];
  }
}

// ---------------------------------------------------------------------------
// Backward block 0, row-centric — wave per node; dv added at col position
// (unique writer per edge).
// ---------------------------------------------------------------------------
__global__ void k_bwd_b0_row(const float* __restrict__ Wr, const float* __restrict__ br,
                             const float* __restrict__ h0_in,
                             const float* __restrict__ ga0, const float* __restrict__ ga1,
                             const float* __restrict__ ga2, const float4* __restrict__ geoR,
                             const int* __restrict__ colR, const int* __restrict__ cposR,
                             const int* __restrict__ start_row, const int* __restrict__ deg_row,
                             float* __restrict__ dv_col, int N)
{
  int n = (blockIdx.x * blockDim.x + threadIdx.x) >> 6;
  int lane = threadIdx.x & 63;
  int g = lane >> 4, c = lane & 15;
  if (n >= N) return;
  float wr0[8], wr1[8], wr2[8];
  #pragma unroll
  for (int k = 0; k < 8; k++) {
    wr0[k] = Wr[k*80 + c];
    wr1[k] = Wr[k*80 + 16 + c];
    wr2[k] = Wr[k*80 + 32 + c];
  }
  float b1v = br[16 + c], b2v = br[32 + c];

  float dm0 = ga0[n*16 + c];
  float dm1[3], dm2[5];
  #pragma unroll
  for (int m = 0; m < 3; m++) dm1[m] = ga1[n*48 + c*3 + m];
  #pragma unroll
  for (int m = 0; m < 5; m++) dm2[m] = ga2[n*80 + c*5 + m];

  int i0 = start_row[n] + g, i1 = start_row[n] + deg_row[n];
  float4 G0n = {0,0,0,0}, G1n = {0,0,0,0}, G2n = {0,0,0,0}, G3n = {0,0,0,0}, G4n = {0,0,0,0};
  float h0n = 0.f;
  if (i0 < i1) {
    G0n = geoR[i0*5+0]; G1n = geoR[i0*5+1]; G2n = geoR[i0*5+2];
    G3n = geoR[i0*5+3]; G4n = geoR[i0*5+4];
    h0n = h0_in[colR[i0]*16 + c];
  }
  for (int i = i0; i < i1; i += 4) {
    float4 G0 = G0n, G1 = G1n, G2 = G2n, G3 = G3n, G4 = G4n;
    float h0c = h0n;
    if (i+4 < i1) {
      G0n = geoR[(i+4)*5+0]; G1n = geoR[(i+4)*5+1]; G2n = geoR[(i+4)*5+2];
      G3n = geoR[(i+4)*5+3]; G4n = geoR[(i+4)*5+4];
      h0n = h0_in[colR[i+4]*16 + c];
    }
    float rad[8]    = {G0.x,G0.y,G0.z,G0.w,G1.x,G1.y,G1.z,G1.w};
    float draddr[8] = {G2.x,G2.y,G2.z,G2.w,G3.x,G3.y,G3.z,G3.w};
    float ux = G4.x, uy = G4.y, uz = G4.z, inv_r = G4.w;
    float sh1[3], sh2[5];
    sh_from_u(ux, uy, uz, sh1, sh2);

    float w1 = b1v, w2v = b2v;
    #pragma unroll
    for (int k = 0; k < 8; k++) { w1 += rad[k]*wr1[k]; w2v += rad[k]*wr2[k]; }

    float T1 = 0.f, T2 = 0.f;
    #pragma unroll
    for (int m = 0; m < 3; m++) T1 += dm1[m]*sh1[m];
    #pragma unroll
    for (int m = 0; m < 5; m++) T2 += dm2[m]*sh2[m];

    float dw0 = dm0 * h0c;
    float dw1 = h0c * T1;
    float dw2 = h0c * T2;

    float w1h = w1*h0c, w2h = w2v*h0c;
    float q1x = dm1[0]*w1h, q1y = dm1[1]*w1h, q1z = dm1[2]*w1h;
    float q0 = dm2[0]*w2h, q1 = dm2[1]*w2h, q2 = dm2[2]*w2h, q3 = dm2[3]*w2h, q4 = dm2[4]*w2h;

    float gr = 0.f;
    #pragma unroll
    for (int k = 0; k < 8; k++)
      gr += (dw0*wr0[k] + dw1*wr1[k] + dw2*wr2[k]) * draddr[k];
    float gux = SQRT3f*q1x + SQRT15f*(uy*q0 + uz*q3 + ux*q4);
    float guy = SQRT3f*q1y + SQRT15f*(ux*q0 + uz*q1 - uy*q4);
    float guz = SQRT3f*q1z + SQRT15f*uy*q1 + 3.f*SQRT5f*uz*q2 + SQRT15f*ux*q3;

    gr  = grp16_sum(gr);
    gux = grp16_sum(gux);
    guy = grp16_sum(guy);
    guz = grp16_sum(guz);

    if (c == 0) {
      int cp = cposR[i];
      float gdotu = gux*ux + guy*uy + guz*uz;
      dv_col[cp*3+0] += gr*ux + (gux - gdotu*ux)*inv_r;
      dv_col[cp*3+1] += gr*uy + (guy - gdotu*uy)*inv_r;
      dv_col[cp*3+2] += gr*uz + (guz - gdotu*uz)*inv_r;
    }
  }
}

// ---------------------------------------------------------------------------
// Force assembly: force[n] = sum_{col==n} dv - sum_{row==n} dv
// ---------------------------------------------------------------------------
__global__ void k_force(const int* __restrict__ start_row, const int* __restrict__ deg_row,
                        const int* __restrict__ cposR,
                        const int* __restrict__ start_col, const int* __restrict__ deg_col,
                        const float* __restrict__ dv_col, float* __restrict__ force, int N)
{
  int n = blockIdx.x * blockDim.x + threadIdx.x;
  if (n >= N) return;
  float fx = 0.f, fy = 0.f, fz = 0.f;
  int c0 = start_col[n], c1 = c0 + deg_col[n];
  for (int i = c0; i < c1; i++) {
    fx += dv_col[i*3+0]; fy += dv_col[i*3+1]; fz += dv_col[i*3+2];
  }
  int r0 = start_row[n], r1 = r0 + deg_row[n];
  for (int i = r0; i < r1; i++) {
    int cp = cposR[i];
    fx -= dv_col[cp*3+0]; fy -= dv_col[cp*3+1]; fz -= dv_col[cp*3+2];
  }
  force[n*3+0] = fx; force[n*3+1] = fy; force[n*3+2] = fz;
}

// ---------------------------------------------------------------------------
extern "C" void kernel_launch(void* const* d_in, const int* in_sizes, int n_in,
                              void* d_out, int out_size, void* d_ws, size_t ws_size,
                              hipStream_t stream)
{
  const float* pos    = (const float*)d_in[0];
  const int*   z      = (const int*)  d_in[1];
  const int*   ei     = (const int*)  d_in[2];
  const float* emb    = (const float*)d_in[3];
  const float* W_init = (const float*)d_in[4];
  const float* Wr     = (const float*)d_in[5];   // (2, 8, 80)
  const float* br     = (const float*)d_in[6];   // (2, 80)
  const float* W_out  = (const float*)d_in[7];   // (2, 3, 16, 16)
  const float* W_read = (const float*)d_in[8];
  const float* W1     = (const float*)d_in[9];
  const float* b1     = (const float*)d_in[10];
  const float* W2     = (const float*)d_in[11];
  const float* b2     = (const float*)d_in[12];

  const int N = in_sizes[0] / 3;
  const int E = in_sizes[2] / 2;

  float* f = (float*)d_ws;
  float* geo_f = f; f += (size_t)E*20;   // float4-aligned (d_ws base is aligned)
  float* h0_s0 = f; f += (size_t)N*16;
  float* h0_s1 = f; f += (size_t)N*16;
  float* h0_s2 = f; f += (size_t)N*16;
  float* h1_s1 = f; f += (size_t)N*48;
  float* h2_s1 = f; f += (size_t)N*80;
  float* a0    = f; f += (size_t)N*16;   // also ga0
  float* a1    = f; f += (size_t)N*48;   // also ga1
  float* a2    = f; f += (size_t)N*80;   // also ga2
  float* g0    = f; f += (size_t)N*16;
  float* g1    = f; f += (size_t)N*48;
  float* g2    = f; f += (size_t)N*80;
  float* dv    = f; f += (size_t)E*3;    // dv_col, positional in col order
  int* ip = (int*)f;
  int* cursors   = ip; ip += 2;          // cursors+deg contiguous -> one memset
  int* deg_row   = ip; ip += N;
  int* deg_col   = ip; ip += N;
  int* start_row = ip; ip += N;
  int* start_col = ip; ip += N;
  int* cur_row   = ip; ip += N;
  int* cur_col   = ip; ip += N;
  int* colR      = ip; ip += E;
  int* cposR     = ip; ip += E;
  int* rowC      = ip; ip += E;
  int* rposC     = ip; ip += E;

  float4* geoR = (float4*)geo_f;

  float* out    = (float*)d_out;
  float* energy = out;
  float* force  = out + 1;

  const int BLK = 256;
  const int NPB = BLK / 64;  // nodes per block (wave-per-node kernels)
  const int GPB = BLK / 16;

  (void)hipMemsetAsync(energy, 0, sizeof(float), stream);
  (void)hipMemsetAsync(cursors, 0, (size_t)(2 + 2*N) * sizeof(int), stream);

  // ---- CSR build (scan-free) + geometry in CSR order ----
  k_hist<<<cdiv(E, BLK), BLK, 0, stream>>>(ei, E, deg_row, deg_col);
  k_alloc<<<cdiv(N, BLK), BLK, 0, stream>>>(deg_row, deg_col, start_row, cur_row,
                                            start_col, cur_col, cursors, N);
  k_scatter_geom<<<cdiv(E, BLK), BLK, 0, stream>>>(pos, ei, E, cur_row, cur_col,
                                                   geoR, colR, cposR, rowC, rposC);

  k_node_init<<<cdiv(N, BLK), BLK, 0, stream>>>(emb, z, W_init, h0_s0, N);

  // ---- forward block 0 ----
  k_fwd_b0<<<cdiv(N, NPB), BLK, 0, stream>>>(Wr, br, h0_s0, geoR, colR,
                                             start_row, deg_row, a0, a1, a2, N);
  k_node_update<<<cdiv(N*16, BLK), BLK, 0, stream>>>(h0_s0, a0, a1, a2,
                                                     W_out, h0_s1, h1_s1, h2_s1, N, 1);

  // ---- forward block 1 (only h0 path live) ----
  k_fwd_b1<<<cdiv(N, NPB), BLK, 0, stream>>>(Wr + 640, br + 80,
                                             h0_s1, h1_s1, h2_s1, geoR, colR,
                                             start_row, deg_row, a0, N);
  k_node_update<<<cdiv(N*16, BLK), BLK, 0, stream>>>(h0_s1, a0, nullptr, nullptr,
                                                     W_out + 768, h0_s2, nullptr, nullptr, N, 0);

  // ---- readout fwd + bwd (also emits ga0 for block-1 backward) ----
  k_readout_bwd<<<cdiv(N, BLK), BLK, 0, stream>>>(h0_s2, W_read, W1, b1, W2, b2,
                                                  W_out + 768, g0, a0, energy, N);

  // ---- backward block 1 ----
  k_bwd_b1_col<<<cdiv(N, NPB), BLK, 0, stream>>>(Wr + 640, br + 80,
                                                 h0_s1, h1_s1, h2_s1, a0, geoR,
                                                 rowC, rposC, start_col, deg_col,
                                                 g0, g1, g2, dv, N);

  // ---- backward block 0 ----
  k_ga<<<cdiv(N*16, BLK), BLK, 0, stream>>>(g0, g1, g2, W_out, a0, a1, a2, N);
  k_bwd_b0_row<<<cdiv(N, NPB), BLK, 0, stream>>>(Wr, br, h0_s0,
                                                 a0, a1, a2, geoR, colR, cposR,
                                                 start_row, deg_row, dv, N);

  // ---- force assembly ----
  k_force<<<cdiv(N, BLK), BLK, 0, stream>>>(start_row, deg_row, cposR,
                                            start_col, deg_col, dv, force, N);
}

// Round 10
// 514.170 us; speedup vs baseline: 4.5843x; 1.0295x over previous
//
#include <hip/hip_runtime.h>
#include <math.h>

#ifndef M_PI
#define M_PI 3.14159265358979323846
#endif

static inline int cdiv(int a, int b){ return (a + b - 1) / b; }

#define SQRT3f  1.7320508075688772f
#define SQRT5f  2.23606797749979f
#define SQRT15f 3.872983346207417f
#define KRADf   0.6324555320336759f      /* sqrt(2/R_MAX), R_MAX=5 */
#define PI5f    0.6283185307179586f      /* pi/5 */

// sum over the 16-lane channel group (within-group, xor 1..8)
__device__ __forceinline__ float grp16_sum(float v){
  v += __shfl_xor(v, 1, 64);
  v += __shfl_xor(v, 2, 64);
  v += __shfl_xor(v, 4, 64);
  v += __shfl_xor(v, 8, 64);
  return v;
}
// sum across the 4 groups of a wave (same channel lane in each group)
__device__ __forceinline__ float xgrp_sum(float v){
  v += __shfl_xor(v, 16, 64);
  v += __shfl_xor(v, 32, 64);
  return v;
}

// sh from unit vector (8 ops)
__device__ __forceinline__ void sh_from_u(float ux, float uy, float uz,
                                          float* sh1, float* sh2)
{
  sh1[0] = SQRT3f*ux; sh1[1] = SQRT3f*uy; sh1[2] = SQRT3f*uz;
  sh2[0] = SQRT15f*ux*uy;
  sh2[1] = SQRT15f*uy*uz;
  sh2[2] = 0.5f*SQRT5f*(3.f*uz*uz - 1.f);
  sh2[3] = SQRT15f*ux*uz;
  sh2[4] = 0.5f*SQRT15f*(ux*ux - uy*uy);
}

// Chebyshev recurrences from (s1,c1)=sincos(pi*r/5): rad only (fwd)
__device__ __forceinline__ void rad_from_sc(float s1, float c1, float inv_r, float* rad)
{
  float tc = 2.f * c1;
  float sprev = 0.f, s = s1;
  float Ki = KRADf * inv_r;
  #pragma unroll
  for (int k = 0; k < 8; k++) {
    rad[k] = Ki * s;
    float sn = tc*s - sprev; sprev = s; s = sn;
  }
}
// rad + draddr (bwd)
__device__ __forceinline__ void rad_drad_from_sc(float s1, float c1, float inv_r,
                                                 float* rad, float* draddr)
{
  float tc = 2.f * c1;
  float sprev = 0.f, s = s1, cprev = 1.f, cc = c1;
  float Ki = KRADf * inv_r;
  const float KPI5 = KRADf * PI5f;
  #pragma unroll
  for (int k = 0; k < 8; k++) {
    rad[k] = Ki * s;
    draddr[k] = (KPI5 * (float)(k+1) * cc - rad[k]) * inv_r;
    float sn = tc*s - sprev; sprev = s; s = sn;
    float cn = tc*cc - cprev; cprev = cc; cc = cn;
  }
}

// ---------------------------------------------------------------------------
// Degree histogram (E-parallel)
// ---------------------------------------------------------------------------
__global__ void k_hist(const int* __restrict__ ei, int E,
                       int* __restrict__ deg_row, int* __restrict__ deg_col)
{
  int e = blockIdx.x * blockDim.x + threadIdx.x;
  if (e >= E) return;
  atomicAdd(&deg_row[ei[e]], 1);
  atomicAdd(&deg_col[ei[E + e]], 1);
}

// ---------------------------------------------------------------------------
// Scan-free segment allocation: wave-aggregated atomicAdd on global cursors.
// ---------------------------------------------------------------------------
__global__ void k_alloc(const int* __restrict__ deg_row, const int* __restrict__ deg_col,
                        int* __restrict__ start_row, int* __restrict__ cur_row,
                        int* __restrict__ start_col, int* __restrict__ cur_col,
                        int* __restrict__ cursors, int N)
{
  int idx = blockIdx.x * blockDim.x + threadIdx.x;
  int lane = threadIdx.x & 63;
  #pragma unroll
  for (int which = 0; which < 2; which++) {
    const int* deg = which ? deg_col : deg_row;
    int* start = which ? start_col : start_row;
    int* cur   = which ? cur_col   : cur_row;
    int v = (idx < N) ? deg[idx] : 0;
    int incl = v;
    #pragma unroll
    for (int d = 1; d < 64; d <<= 1) {
      int y = __shfl_up(incl, d, 64);
      if (lane >= d) incl += y;
    }
    int wtot = __shfl(incl, 63, 64);
    int base = 0;
    if (lane == 63) base = atomicAdd(&cursors[which], wtot);
    base = __shfl(base, 63, 64);
    if (idx < N) { int st = base + incl - v; start[idx] = st; cur[idx] = st; }
  }
}

// ---------------------------------------------------------------------------
// Scatter + compact geometry in BOTH CSR orders.
// Per edge: u4=(ux,uy,uz,inv_r), sc2=(sin(pi r/5), cos(pi r/5)).
// Row order: uR/scR + colR (col idx) + cposR (edge's col position).
// Col order: uC/scC + rowC (row idx) + rposC (edge's row position).
// rad/draddr are rebuilt in-register by consumers (cheap recurrence).
// ---------------------------------------------------------------------------
__global__ void k_scatter_geom(const float* __restrict__ pos, const int* __restrict__ ei, int E,
                               int* __restrict__ cur_row, int* __restrict__ cur_col,
                               float4* __restrict__ uR, float2* __restrict__ scR,
                               float4* __restrict__ uC, float2* __restrict__ scC,
                               int* __restrict__ colR, int* __restrict__ cposR,
                               int* __restrict__ rowC, int* __restrict__ rposC)
{
  int e = blockIdx.x * blockDim.x + threadIdx.x;
  if (e >= E) return;
  int row = ei[e], col = ei[E + e];
  int pr = atomicAdd(&cur_row[row], 1);
  int pc = atomicAdd(&cur_col[col], 1);
  colR[pr] = col; cposR[pr] = pc;
  rowC[pc] = row; rposC[pc] = pr;

  float px = pos[row*3+0] - pos[col*3+0];
  float py = pos[row*3+1] - pos[col*3+1];
  float pz = pos[row*3+2] - pos[col*3+2];
  float r2 = px*px + py*py + pz*pz + 1e-12f;
  float r = sqrtf(r2);
  float inv_r = 1.0f / r;
  float ux = px*inv_r, uy = py*inv_r, uz = pz*inv_r;
  float s1, c1;
  sincosf(r * PI5f, &s1, &c1);
  float4 u4 = make_float4(ux, uy, uz, inv_r);
  float2 sc = make_float2(s1, c1);
  uR[pr] = u4; scR[pr] = sc;
  uC[pc] = u4; scC[pc] = sc;
}

// ---------------------------------------------------------------------------
// h0_init[n,:] = emb[z[n],:] @ W_init
// ---------------------------------------------------------------------------
__global__ void k_node_init(const float* __restrict__ emb, const int* __restrict__ z,
                            const float* __restrict__ W_init, float* __restrict__ h0, int N)
{
  __shared__ float sW[256];
  if (threadIdx.x < 256) sW[threadIdx.x] = W_init[threadIdx.x];
  __syncthreads();
  int n = blockIdx.x * blockDim.x + threadIdx.x;
  if (n >= N) return;
  const float* e = emb + z[n]*16;
  float ev[16];
  #pragma unroll
  for (int k = 0; k < 16; k++) ev[k] = e[k];
  #pragma unroll
  for (int c = 0; c < 16; c++) {
    float s = 0.f;
    #pragma unroll
    for (int k = 0; k < 16; k++) s += ev[k] * sW[k*16+c];
    h0[n*16+c] = s;
  }
}

// ---------------------------------------------------------------------------
// Forward block 0 — wave per node (4 groups x 16 channels, stride-4 edges).
// Streams uR/scR/colR; gathers h0[col].
// ---------------------------------------------------------------------------
__global__ void k_fwd_b0(const float* __restrict__ Wr, const float* __restrict__ br,
                         const float* __restrict__ h0_in,
                         const float4* __restrict__ uR, const float2* __restrict__ scR,
                         const int* __restrict__ colR,
                         const int* __restrict__ start_row, const int* __restrict__ deg_row,
                         float* __restrict__ a0, float* __restrict__ a1, float* __restrict__ a2,
                         int N)
{
  int n = (blockIdx.x * blockDim.x + threadIdx.x) >> 6;
  int lane = threadIdx.x & 63;
  int g = lane >> 4, c = lane & 15;
  if (n >= N) return;
  float wr0[8], wr1[8], wr2[8];
  #pragma unroll
  for (int k = 0; k < 8; k++) {
    wr0[k] = Wr[k*80 + c];
    wr1[k] = Wr[k*80 + 16 + c];
    wr2[k] = Wr[k*80 + 32 + c];
  }
  float b0v = br[c], b1v = br[16 + c], b2v = br[32 + c];

  float acc0 = 0.f, acc1[3] = {0.f,0.f,0.f}, acc2[5] = {0.f,0.f,0.f,0.f,0.f};

  int i0 = start_row[n] + g, i1 = start_row[n] + deg_row[n];
  float4 Un = {0,0,0,0}; float2 SCn = {0,0};
  float h0n = 0.f;
  if (i0 < i1) {
    Un = uR[i0]; SCn = scR[i0];
    h0n = h0_in[colR[i0]*16 + c];
  }
  for (int i = i0; i < i1; i += 4) {
    float4 U = Un; float2 SC = SCn;
    float h0c = h0n;
    if (i+4 < i1) {
      Un = uR[i+4]; SCn = scR[i+4];
      h0n = h0_in[colR[i+4]*16 + c];
    }
    float rad[8];
    rad_from_sc(SC.x, SC.y, U.w, rad);
    float sh1[3], sh2[5];
    sh_from_u(U.x, U.y, U.z, sh1, sh2);
    float w0 = b0v, w1 = b1v, w2 = b2v;
    #pragma unroll
    for (int k = 0; k < 8; k++) {
      w0 += rad[k]*wr0[k]; w1 += rad[k]*wr1[k]; w2 += rad[k]*wr2[k];
    }
    acc0 += w0*h0c;
    float wh1 = w1*h0c, wh2 = w2*h0c;
    #pragma unroll
    for (int m = 0; m < 3; m++) acc1[m] += wh1*sh1[m];
    #pragma unroll
    for (int m = 0; m < 5; m++) acc2[m] += wh2*sh2[m];
  }
  acc0 = xgrp_sum(acc0);
  #pragma unroll
  for (int m = 0; m < 3; m++) acc1[m] = xgrp_sum(acc1[m]);
  #pragma unroll
  for (int m = 0; m < 5; m++) acc2[m] = xgrp_sum(acc2[m]);
  if (g == 0) {
    a0[n*16 + c] = acc0;
    #pragma unroll
    for (int m = 0; m < 3; m++) a1[n*48 + c*3 + m] = acc1[m];
    #pragma unroll
    for (int m = 0; m < 5; m++) a2[n*80 + c*5 + m] = acc2[m];
  }
}

// ---------------------------------------------------------------------------
// Forward block 1 (last) — wave per node.
// ---------------------------------------------------------------------------
__global__ void k_fwd_b1(const float* __restrict__ Wr, const float* __restrict__ br,
                         const float* __restrict__ h0_in, const float* __restrict__ h1_in,
                         const float* __restrict__ h2_in,
                         const float4* __restrict__ uR, const float2* __restrict__ scR,
                         const int* __restrict__ colR,
                         const int* __restrict__ start_row, const int* __restrict__ deg_row,
                         float* __restrict__ a0, int N)
{
  int n = (blockIdx.x * blockDim.x + threadIdx.x) >> 6;
  int lane = threadIdx.x & 63;
  int g = lane >> 4, c = lane & 15;
  if (n >= N) return;
  float wr0[8], wr3[8], wr4[8];
  #pragma unroll
  for (int k = 0; k < 8; k++) {
    wr0[k] = Wr[k*80 + c];
    wr3[k] = Wr[k*80 + 48 + c];
    wr4[k] = Wr[k*80 + 64 + c];
  }
  float b0v = br[c], b3v = br[48 + c], b4v = br[64 + c];

  float acc0 = 0.f;
  int i0 = start_row[n] + g, i1 = start_row[n] + deg_row[n];
  float4 Un = {0,0,0,0}; float2 SCn = {0,0};
  float h0n = 0.f, h1n[3] = {0,0,0}, h2n[5] = {0,0,0,0,0};
  if (i0 < i1) {
    int col = colR[i0];
    Un = uR[i0]; SCn = scR[i0];
    h0n = h0_in[col*16 + c];
    #pragma unroll
    for (int m = 0; m < 3; m++) h1n[m] = h1_in[col*48 + c*3 + m];
    #pragma unroll
    for (int m = 0; m < 5; m++) h2n[m] = h2_in[col*80 + c*5 + m];
  }
  for (int i = i0; i < i1; i += 4) {
    float4 U = Un; float2 SC = SCn;
    float h0c = h0n;
    float h1c[3], h2c[5];
    #pragma unroll
    for (int m = 0; m < 3; m++) h1c[m] = h1n[m];
    #pragma unroll
    for (int m = 0; m < 5; m++) h2c[m] = h2n[m];
    if (i+4 < i1) {
      int col = colR[i+4];
      Un = uR[i+4]; SCn = scR[i+4];
      h0n = h0_in[col*16 + c];
      #pragma unroll
      for (int m = 0; m < 3; m++) h1n[m] = h1_in[col*48 + c*3 + m];
      #pragma unroll
      for (int m = 0; m < 5; m++) h2n[m] = h2_in[col*80 + c*5 + m];
    }
    float rad[8];
    rad_from_sc(SC.x, SC.y, U.w, rad);
    float sh1[3], sh2[5];
    sh_from_u(U.x, U.y, U.z, sh1, sh2);
    float w0 = b0v, w3 = b3v, w4 = b4v;
    #pragma unroll
    for (int k = 0; k < 8; k++) {
      w0 += rad[k]*wr0[k]; w3 += rad[k]*wr3[k]; w4 += rad[k]*wr4[k];
    }
    float S1 = 0.f, S2 = 0.f;
    #pragma unroll
    for (int m = 0; m < 3; m++) S1 += h1c[m]*sh1[m];
    #pragma unroll
    for (int m = 0; m < 5; m++) S2 += h2c[m]*sh2[m];
    acc0 += w0*h0c + w3*S1 + w4*S2;
  }
  acc0 = xgrp_sum(acc0);
  if (g == 0) a0[n*16 + c] = acc0;
}

// ---------------------------------------------------------------------------
// Node update: h_out = h_in + a @ U
// ---------------------------------------------------------------------------
__global__ void k_node_update(const float* __restrict__ h0_in,
                              const float* __restrict__ a0, const float* __restrict__ a1,
                              const float* __restrict__ a2,
                              const float* __restrict__ U,
                              float* __restrict__ h0_out, float* __restrict__ h1_out,
                              float* __restrict__ h2_out, int N, int full)
{
  int idx = blockIdx.x * blockDim.x + threadIdx.x;
  int n = idx >> 4, d = idx & 15;
  if (n >= N) return;
  const float* U0 = U;
  const float* U1 = U + 256;
  const float* U2 = U + 512;
  float s = h0_in[n*16 + d];
  #pragma unroll
  for (int c = 0; c < 16; c++) s += a0[n*16 + c] * U0[c*16 + d];
  h0_out[n*16 + d] = s;
  if (full) {
    float v1[3] = {0.f, 0.f, 0.f};
    #pragma unroll
    for (int c = 0; c < 16; c++) {
      float u = U1[c*16 + d];
      #pragma unroll
      for (int m = 0; m < 3; m++) v1[m] += a1[n*48 + c*3 + m] * u;
    }
    #pragma unroll
    for (int m = 0; m < 3; m++) h1_out[n*48 + d*3 + m] = v1[m];
    float v2[5] = {0.f, 0.f, 0.f, 0.f, 0.f};
    #pragma unroll
    for (int c = 0; c < 16; c++) {
      float u = U2[c*16 + d];
      #pragma unroll
      for (int m = 0; m < 5; m++) v2[m] += a2[n*80 + c*5 + m] * u;
    }
    #pragma unroll
    for (int m = 0; m < 5; m++) h2_out[n*80 + d*5 + m] = v2[m];
  }
}

// ---------------------------------------------------------------------------
// Readout fwd + bwd fused; epilogue also computes ga0_b1 = g0 @ U0(block1)^T.
// ---------------------------------------------------------------------------
__global__ void k_readout_bwd(const float* __restrict__ h0, const float* __restrict__ W_read,
                              const float* __restrict__ W1, const float* __restrict__ b1,
                              const float* __restrict__ W2, const float* __restrict__ b2,
                              const float* __restrict__ U0b1,
                              float* __restrict__ g0, float* __restrict__ ga0,
                              float* __restrict__ energy, int N)
{
  int n = blockIdx.x * blockDim.x + threadIdx.x;
  float site = 0.f;
  if (n < N) {
    float h[16], inv[16], dt[16], g0v[16];
    #pragma unroll
    for (int d = 0; d < 16; d++) h[d] = h0[n*16 + d];
    #pragma unroll
    for (int j = 0; j < 16; j++) {
      float s = 0.f;
      #pragma unroll
      for (int d = 0; d < 16; d++) s += h[d] * W_read[d*16 + j];
      inv[j] = s;
    }
    site = b2[0];
    #pragma unroll
    for (int c = 0; c < 16; c++) {
      float t = b1[c];
      #pragma unroll
      for (int j = 0; j < 16; j++) t += inv[j] * W1[j*16 + c];
      float sg = 1.f / (1.f + expf(-t));
      float w2v = W2[c];
      site += t * sg * w2v;
      dt[c] = w2v * sg * (1.f + t * (1.f - sg));
    }
    float dinv[16];
    #pragma unroll
    for (int j = 0; j < 16; j++) {
      float s = 0.f;
      #pragma unroll
      for (int c = 0; c < 16; c++) s += dt[c] * W1[j*16 + c];
      dinv[j] = s;
    }
    #pragma unroll
    for (int d = 0; d < 16; d++) {
      float s = 0.f;
      #pragma unroll
      for (int j = 0; j < 16; j++) s += dinv[j] * W_read[d*16 + j];
      g0v[d] = s;
      g0[n*16 + d] = s;
    }
    #pragma unroll
    for (int c = 0; c < 16; c++) {
      float s = 0.f;
      #pragma unroll
      for (int d = 0; d < 16; d++) s += g0v[d] * U0b1[c*16 + d];
      ga0[n*16 + c] = s;
    }
  }
  #pragma unroll
  for (int off = 32; off; off >>= 1) site += __shfl_down(site, off, 64);
  if ((threadIdx.x & 63) == 0) atomicAdd(energy, site);
}

// ---------------------------------------------------------------------------
// ga = g @ U^T (full, for block 0 backward)
// ---------------------------------------------------------------------------
__global__ void k_ga(const float* __restrict__ g0, const float* __restrict__ g1,
                     const float* __restrict__ g2, const float* __restrict__ U,
                     float* __restrict__ ga0, float* __restrict__ ga1, float* __restrict__ ga2,
                     int N)
{
  int idx = blockIdx.x * blockDim.x + threadIdx.x;
  int n = idx >> 4, c = idx & 15;
  if (n >= N) return;
  const float* U0 = U;
  const float* U1 = U + 256;
  const float* U2 = U + 512;
  float s = 0.f;
  #pragma unroll
  for (int d = 0; d < 16; d++) s += g0[n*16 + d] * U0[c*16 + d];
  ga0[n*16 + c] = s;
  float v1[3] = {0.f, 0.f, 0.f};
  #pragma unroll
  for (int d = 0; d < 16; d++) {
    float u = U1[c*16 + d];
    #pragma unroll
    for (int m = 0; m < 3; m++) v1[m] += g1[n*48 + d*3 + m] * u;
  }
  #pragma unroll
  for (int m = 0; m < 3; m++) ga1[n*48 + c*3 + m] = v1[m];
  float v2[5] = {0.f, 0.f, 0.f, 0.f, 0.f};
  #pragma unroll
  for (int d = 0; d < 16; d++) {
    float u = U2[c*16 + d];
    #pragma unroll
    for (int m = 0; m < 5; m++) v2[m] += g2[n*80 + d*5 + m] * u;
  }
  #pragma unroll
  for (int m = 0; m < 5; m++) ga2[n*80 + c*5 + m] = v2[m];
}

// ---------------------------------------------------------------------------
// Backward block 1, col-centric — wave per node. Streams uC/scC/rowC;
// gathers ga0[row]; dv_b1 written positionally into dv_col (stream).
// ---------------------------------------------------------------------------
__global__ void k_bwd_b1_col(const float* __restrict__ Wr, const float* __restrict__ br,
                             const float* __restrict__ h0_in, const float* __restrict__ h1_in,
                             const float* __restrict__ h2_in,
                             const float* __restrict__ ga0,
                             const float4* __restrict__ uC, const float2* __restrict__ scC,
                             const int* __restrict__ rowC,
                             const int* __restrict__ start_col, const int* __restrict__ deg_col,
                             float* __restrict__ g0, float* __restrict__ g1, float* __restrict__ g2,
                             float* __restrict__ dv_col, int N)
{
  int n = (blockIdx.x * blockDim.x + threadIdx.x) >> 6;
  int lane = threadIdx.x & 63;
  int g = lane >> 4, c = lane & 15;
  if (n >= N) return;
  float wr0[8], wr3[8], wr4[8];
  #pragma unroll
  for (int k = 0; k < 8; k++) {
    wr0[k] = Wr[k*80 + c];
    wr3[k] = Wr[k*80 + 48 + c];
    wr4[k] = Wr[k*80 + 64 + c];
  }
  float b0v = br[c], b3v = br[48 + c], b4v = br[64 + c];

  float h0c = h0_in[n*16 + c];
  float h1c[3], h2c[5];
  #pragma unroll
  for (int m = 0; m < 3; m++) h1c[m] = h1_in[n*48 + c*3 + m];
  #pragma unroll
  for (int m = 0; m < 5; m++) h2c[m] = h2_in[n*80 + c*5 + m];

  float accg0 = 0.f, accg1[3] = {0.f,0.f,0.f}, accg2[5] = {0.f,0.f,0.f,0.f,0.f};

  int i0 = start_col[n] + g, i1 = start_col[n] + deg_col[n];
  float4 Un = {0,0,0,0}; float2 SCn = {0,0};
  float dm0n = 0.f;
  if (i0 < i1) {
    Un = uC[i0]; SCn = scC[i0];
    dm0n = ga0[rowC[i0]*16 + c];
  }
  for (int i = i0; i < i1; i += 4) {
    float4 U = Un; float2 SC = SCn;
    float dm0 = dm0n;
    if (i+4 < i1) {
      Un = uC[i+4]; SCn = scC[i+4];
      dm0n = ga0[rowC[i+4]*16 + c];
    }
    float rad[8], draddr[8];
    rad_drad_from_sc(SC.x, SC.y, U.w, rad, draddr);
    float ux = U.x, uy = U.y, uz = U.z, inv_r = U.w;
    float sh1[3], sh2[5];
    sh_from_u(ux, uy, uz, sh1, sh2);

    float w0 = b0v, w3 = b3v, w4 = b4v;
    #pragma unroll
    for (int k = 0; k < 8; k++) {
      w0 += rad[k]*wr0[k]; w3 += rad[k]*wr3[k]; w4 += rad[k]*wr4[k];
    }

    float S1 = 0.f, S2 = 0.f;
    #pragma unroll
    for (int m = 0; m < 3; m++) S1 += h1c[m]*sh1[m];
    #pragma unroll
    for (int m = 0; m < 5; m++) S2 += h2c[m]*sh2[m];

    float dw0 = dm0 * h0c;
    float dw3 = dm0 * S1;
    float dw4 = dm0 * S2;
    float t3 = dm0 * w3, t4 = dm0 * w4;

    accg0 += dm0 * w0;
    #pragma unroll
    for (int m = 0; m < 3; m++) accg1[m] += t3 * sh1[m];
    #pragma unroll
    for (int m = 0; m < 5; m++) accg2[m] += t4 * sh2[m];

    float q1x = t3*h1c[0], q1y = t3*h1c[1], q1z = t3*h1c[2];
    float q0 = t4*h2c[0], q1 = t4*h2c[1], q2 = t4*h2c[2], q3 = t4*h2c[3], q4 = t4*h2c[4];
    float gr = 0.f;
    #pragma unroll
    for (int k = 0; k < 8; k++)
      gr += (dw0*wr0[k] + dw3*wr3[k] + dw4*wr4[k]) * draddr[k];
    float gux = SQRT3f*q1x + SQRT15f*(uy*q0 + uz*q3 + ux*q4);
    float guy = SQRT3f*q1y + SQRT15f*(ux*q0 + uz*q1 - uy*q4);
    float guz = SQRT3f*q1z + SQRT15f*uy*q1 + 3.f*SQRT5f*uz*q2 + SQRT15f*ux*q3;

    gr  = grp16_sum(gr);
    gux = grp16_sum(gux);
    guy = grp16_sum(guy);
    guz = grp16_sum(guz);

    if (c == 0) {
      float gdotu = gux*ux + guy*uy + guz*uz;
      dv_col[i*3+0] = gr*ux + (gux - gdotu*ux)*inv_r;
      dv_col[i*3+1] = gr*uy + (guy - gdotu*uy)*inv_r;
      dv_col[i*3+2] = gr*uz + (guz - gdotu*uz)*inv_r;
    }
  }
  accg0 = xgrp_sum(accg0);
  #pragma unroll
  for (int m = 0; m < 3; m++) accg1[m] = xgrp_sum(accg1[m]);
  #pragma unroll
  for (int m = 0; m < 5; m++) accg2[m] = xgrp_sum(accg2[m]);
  if (g == 0) {
    g0[n*16 + c] += accg0;
    #pragma unroll
    for (int m = 0; m < 3; m++) g1[n*48 + c*3 + m] = accg1[m];
    #pragma unroll
    for (int m = 0; m < 5; m++) g2[n*80 + c*5 + m] = accg2[m];
  }
}

// ---------------------------------------------------------------------------
// Backward block 0, row-centric — wave per node. Streams uR/scR/colR;
// gathers h0[col]; dv_b0 written positionally into dv_row (pure stream, no RMW).
// ---------------------------------------------------------------------------
__global__ void k_bwd_b0_row(const float* __restrict__ Wr, const float* __restrict__ br,
                             const float* __restrict__ h0_in,
                             const float* __restrict__ ga0, const float* __restrict__ ga1,
                             const float* __restrict__ ga2,
                             const float4* __restrict__ uR, const float2* __restrict__ scR,
                             const int* __restrict__ colR,
                             const int* __restrict__ start_row, const int* __restrict__ deg_row,
                             float* __restrict__ dv_row, int N)
{
  int n = (blockIdx.x * blockDim.x + threadIdx.x) >> 6;
  int lane = threadIdx.x & 63;
  int g = lane >> 4, c = lane & 15;
  if (n >= N) return;
  float wr0[8], wr1[8], wr2[8];
  #pragma unroll
  for (int k = 0; k < 8; k++) {
    wr0[k] = Wr[k*80 + c];
    wr1[k] = Wr[k*80 + 16 + c];
    wr2[k] = Wr[k*80 + 32 + c];
  }
  float b1v = br[16 + c], b2v = br[32 + c];

  float dm0 = ga0[n*16 + c];
  float dm1[3], dm2[5];
  #pragma unroll
  for (int m = 0; m < 3; m++) dm1[m] = ga1[n*48 + c*3 + m];
  #pragma unroll
  for (int m = 0; m < 5; m++) dm2[m] = ga2[n*80 + c*5 + m];

  int i0 = start_row[n] + g, i1 = start_row[n] + deg_row[n];
  float4 Un = {0,0,0,0}; float2 SCn = {0,0};
  float h0n = 0.f;
  if (i0 < i1) {
    Un = uR[i0]; SCn = scR[i0];
    h0n = h0_in[colR[i0]*16 + c];
  }
  for (int i = i0; i < i1; i += 4) {
    float4 U = Un; float2 SC = SCn;
    float h0c = h0n;
    if (i+4 < i1) {
      Un = uR[i+4]; SCn = scR[i+4];
      h0n = h0_in[colR[i+4]*16 + c];
    }
    float rad[8], draddr[8];
    rad_drad_from_sc(SC.x, SC.y, U.w, rad, draddr);
    float ux = U.x, uy = U.y, uz = U.z, inv_r = U.w;
    float sh1[3], sh2[5];
    sh_from_u(ux, uy, uz, sh1, sh2);

    float w1 = b1v, w2v = b2v;
    #pragma unroll
    for (int k = 0; k < 8; k++) { w1 += rad[k]*wr1[k]; w2v += rad[k]*wr2[k]; }

    float T1 = 0.f, T2 = 0.f;
    #pragma unroll
    for (int m = 0; m < 3; m++) T1 += dm1[m]*sh1[m];
    #pragma unroll
    for (int m = 0; m < 5; m++) T2 += dm2[m]*sh2[m];

    float dw0 = dm0 * h0c;
    float dw1 = h0c * T1;
    float dw2 = h0c * T2;

    float w1h = w1*h0c, w2h = w2v*h0c;
    float q1x = dm1[0]*w1h, q1y = dm1[1]*w1h, q1z = dm1[2]*w1h;
    float q0 = dm2[0]*w2h, q1 = dm2[1]*w2h, q2 = dm2[2]*w2h, q3 = dm2[3]*w2h, q4 = dm2[4]*w2h;

    float gr = 0.f;
    #pragma unroll
    for (int k = 0; k < 8; k++)
      gr += (dw0*wr0[k] + dw1*wr1[k] + dw2*wr2[k]) * draddr[k];
    float gux = SQRT3f*q1x + SQRT15f*(uy*q0 + uz*q3 + ux*q4);
    float guy = SQRT3f*q1y + SQRT15f*(ux*q0 + uz*q1 - uy*q4);
    float guz = SQRT3f*q1z + SQRT15f*uy*q1 + 3.f*SQRT5f*uz*q2 + SQRT15f*ux*q3;

    gr  = grp16_sum(gr);
    gux = grp16_sum(gux);
    guy = grp16_sum(guy);
    guz = grp16_sum(guz);

    if (c == 0) {
      float gdotu = gux*ux + guy*uy + guz*uz;
      dv_row[i*3+0] = gr*ux + (gux - gdotu*ux)*inv_r;
      dv_row[i*3+1] = gr*uy + (guy - gdotu*uy)*inv_r;
      dv_row[i*3+2] = gr*uz + (guz - gdotu*uz)*inv_r;
    }
  }
}

// ---------------------------------------------------------------------------
// Force assembly: dv_e = dv_col[colpos(e)] + dv_row[rowpos(e)].
// force[n] = sum_{col==n} dv_e - sum_{row==n} dv_e
// Col side: dv_col streams, dv_row gathered via rposC.
// Row side: dv_row streams, dv_col gathered via cposR.
// ---------------------------------------------------------------------------
__global__ void k_force(const int* __restrict__ start_row, const int* __restrict__ deg_row,
                        const int* __restrict__ cposR,
                        const int* __restrict__ start_col, const int* __restrict__ deg_col,
                        const int* __restrict__ rposC,
                        const float* __restrict__ dv_col, const float* __restrict__ dv_row,
                        float* __restrict__ force, int N)
{
  int n = blockIdx.x * blockDim.x + threadIdx.x;
  if (n >= N) return;
  float fx = 0.f, fy = 0.f, fz = 0.f;
  int c0 = start_col[n], c1 = c0 + deg_col[n];
  for (int i = c0; i < c1; i++) {
    int rp = rposC[i];
    fx += dv_col[i*3+0] + dv_row[rp*3+0];
    fy += dv_col[i*3+1] + dv_row[rp*3+1];
    fz += dv_col[i*3+2] + dv_row[rp*3+2];
  }
  int r0 = start_row[n], r1 = r0 + deg_row[n];
  for (int i = r0; i < r1; i++) {
    int cp = cposR[i];
    fx -= dv_row[i*3+0] + dv_col[cp*3+0];
    fy -= dv_row[i*3+1] + dv_col[cp*3+1];
    fz -= dv_row[i*3+2] + dv_col[cp*3+2];
  }
  force[n*3+0] = fx; force[n*3+1] = fy; force[n*3+2] = fz;
}

// ---------------------------------------------------------------------------
extern "C" void kernel_launch(void* const* d_in, const int* in_sizes, int n_in,
                              void* d_out, int out_size, void* d_ws, size_t ws_size,
                              hipStream_t stream)
{
  const float* pos    = (const float*)d_in[0];
  const int*   z      = (const int*)  d_in[1];
  const int*   ei     = (const int*)  d_in[2];
  const float* emb    = (const float*)d_in[3];
  const float* W_init = (const float*)d_in[4];
  const float* Wr     = (const float*)d_in[5];   // (2, 8, 80)
  const float* br     = (const float*)d_in[6];   // (2, 80)
  const float* W_out  = (const float*)d_in[7];   // (2, 3, 16, 16)
  const float* W_read = (const float*)d_in[8];
  const float* W1     = (const float*)d_in[9];
  const float* b1     = (const float*)d_in[10];
  const float* W2     = (const float*)d_in[11];
  const float* b2     = (const float*)d_in[12];

  const int N = in_sizes[0] / 3;
  const int E = in_sizes[2] / 2;

  float* f = (float*)d_ws;
  float4* uR  = (float4*)f; f += (size_t)E*4;
  float4* uC  = (float4*)f; f += (size_t)E*4;
  float2* scR = (float2*)f; f += (size_t)E*2;
  float2* scC = (float2*)f; f += (size_t)E*2;
  float* h0_s0 = f; f += (size_t)N*16;
  float* h0_s1 = f; f += (size_t)N*16;
  float* h0_s2 = f; f += (size_t)N*16;
  float* h1_s1 = f; f += (size_t)N*48;
  float* h2_s1 = f; f += (size_t)N*80;
  float* a0    = f; f += (size_t)N*16;   // also ga0
  float* a1    = f; f += (size_t)N*48;   // also ga1
  float* a2    = f; f += (size_t)N*80;   // also ga2
  float* g0    = f; f += (size_t)N*16;
  float* g1    = f; f += (size_t)N*48;
  float* g2    = f; f += (size_t)N*80;
  float* dv_c  = f; f += (size_t)E*3;    // dv from bwd b1, col order
  float* dv_r  = f; f += (size_t)E*3;    // dv from bwd b0, row order
  int* ip = (int*)f;
  int* cursors   = ip; ip += 2;          // cursors+deg contiguous -> one memset
  int* deg_row   = ip; ip += N;
  int* deg_col   = ip; ip += N;
  int* start_row = ip; ip += N;
  int* start_col = ip; ip += N;
  int* cur_row   = ip; ip += N;
  int* cur_col   = ip; ip += N;
  int* colR      = ip; ip += E;
  int* cposR     = ip; ip += E;
  int* rowC      = ip; ip += E;
  int* rposC     = ip; ip += E;

  float* out    = (float*)d_out;
  float* energy = out;
  float* force  = out + 1;

  const int BLK = 256;
  const int NPB = BLK / 64;  // nodes per block (wave-per-node kernels)

  (void)hipMemsetAsync(energy, 0, sizeof(float), stream);
  (void)hipMemsetAsync(cursors, 0, (size_t)(2 + 2*N) * sizeof(int), stream);

  // ---- CSR build (scan-free) + compact geometry in both orders ----
  k_hist<<<cdiv(E, BLK), BLK, 0, stream>>>(ei, E, deg_row, deg_col);
  k_alloc<<<cdiv(N, BLK), BLK, 0, stream>>>(deg_row, deg_col, start_row, cur_row,
                                            start_col, cur_col, cursors, N);
  k_scatter_geom<<<cdiv(E, BLK), BLK, 0, stream>>>(pos, ei, E, cur_row, cur_col,
                                                   uR, scR, uC, scC,
                                                   colR, cposR, rowC, rposC);

  k_node_init<<<cdiv(N, BLK), BLK, 0, stream>>>(emb, z, W_init, h0_s0, N);

  // ---- forward block 0 ----
  k_fwd_b0<<<cdiv(N, NPB), BLK, 0, stream>>>(Wr, br, h0_s0, uR, scR, colR,
                                             start_row, deg_row, a0, a1, a2, N);
  k_node_update<<<cdiv(N*16, BLK), BLK, 0, stream>>>(h0_s0, a0, a1, a2,
                                                     W_out, h0_s1, h1_s1, h2_s1, N, 1);

  // ---- forward block 1 (only h0 path live) ----
  k_fwd_b1<<<cdiv(N, NPB), BLK, 0, stream>>>(Wr + 640, br + 80,
                                             h0_s1, h1_s1, h2_s1, uR, scR, colR,
                                             start_row, deg_row, a0, N);
  k_node_update<<<cdiv(N*16, BLK), BLK, 0, stream>>>(h0_s1, a0, nullptr, nullptr,
                                                     W_out + 768, h0_s2, nullptr, nullptr, N, 0);

  // ---- readout fwd + bwd (also emits ga0 for block-1 backward) ----
  k_readout_bwd<<<cdiv(N, BLK), BLK, 0, stream>>>(h0_s2, W_read, W1, b1, W2, b2,
                                                  W_out + 768, g0, a0, energy, N);

  // ---- backward block 1 ----
  k_bwd_b1_col<<<cdiv(N, NPB), BLK, 0, stream>>>(Wr + 640, br + 80,
                                                 h0_s1, h1_s1, h2_s1, a0,
                                                 uC, scC, rowC, start_col, deg_col,
                                                 g0, g1, g2, dv_c, N);

  // ---- backward block 0 ----
  k_ga<<<cdiv(N*16, BLK), BLK, 0, stream>>>(g0, g1, g2, W_out, a0, a1, a2, N);
  k_bwd_b0_row<<<cdiv(N, NPB), BLK, 0, stream>>>(Wr, br, h0_s0,
                                                 a0, a1, a2, uR, scR, colR,
                                                 start_row, deg_row, dv_r, N);

  // ---- force assembly ----
  k_force<<<cdiv(N, BLK), BLK, 0, stream>>>(start_row, deg_row, cposR,
                                            start_col, deg_col, rposC,
                                            dv_c, dv_r, force, N);
}